// Round 2
// baseline (1423.650 us; speedup 1.0000x reference)
//
#include <hip/hip_runtime.h>
#include <hip/hip_bf16.h>

#define B_    2
#define H_    90
#define W_    180
#define C_    768
#define WFK   46          // kept W-frequency modes (of 91)
#define NBK   8
#define BSK   96
#define HID   3072
#define NTOK  (B_*H_*W_)  // 32400
#define MPAD  32512       // 254*128
#define NPOS  (B_*H_*WFK) // 8280
#define LAM   0.01f
#define CHROWS 8192       // gemm M-chunk rows (64 tiles of 128)

typedef __attribute__((ext_vector_type(8))) short short8;
typedef __attribute__((ext_vector_type(4))) short short4v;
typedef __attribute__((ext_vector_type(4))) float f32x4;

__device__ __forceinline__ float bf2f(short u) {
    union { unsigned int i; float f; } z;
    z.i = ((unsigned int)(unsigned short)u) << 16;
    return z.f;
}

// ---------------- DFT twiddle tables ----------------
__global__ __launch_bounds__(256) void init_tables_kernel(float* fwc, float* fws, float* hc, float* hs) {
    int i = blockIdx.x * 256 + threadIdx.x;
    if (i < WFK * W_) {
        int wf = i / W_, w = i % W_;
        int p = (w * wf) % W_;
        float th = (float)p * (float)(6.283185307179586476925286766559 / 180.0);
        fwc[i] = cosf(th); fws[i] = sinf(th);
    }
    if (i < H_ * H_) {
        int k = i / H_, h = i % H_;
        int p = (h * k) % H_;
        float th = (float)p * (float)(6.283185307179586476925286766559 / 90.0);
        hc[i] = cosf(th); hs[i] = sinf(th);
    }
}

// ---------------- LayerNorm: f32 in -> bf16 out, zero-pads rows >= ntok_valid ----------------
__global__ __launch_bounds__(256) void ln_kernel(const float* __restrict__ in,
        const float* __restrict__ w, const float* __restrict__ b,
        __hip_bfloat16* __restrict__ outb, int ntok_valid)
{
    int tok = blockIdx.x;
    int tid = threadIdx.x;
    size_t base = (size_t)tok * C_;
    if (tok >= ntok_valid) {
        __hip_bfloat16 z = __float2bfloat16(0.f);
        outb[base + tid] = z; outb[base + tid + 256] = z; outb[base + tid + 512] = z;
        return;
    }
    float x0 = in[base + tid], x1 = in[base + tid + 256], x2 = in[base + tid + 512];
    float s = x0 + x1 + x2;
    float q = x0*x0 + x1*x1 + x2*x2;
#pragma unroll
    for (int off = 32; off > 0; off >>= 1) { s += __shfl_down(s, off); q += __shfl_down(q, off); }
    __shared__ float rs[4], rq[4];
    int wid = tid >> 6, lane = tid & 63;
    if (lane == 0) { rs[wid] = s; rq[wid] = q; }
    __syncthreads();
    float ts = rs[0] + rs[1] + rs[2] + rs[3];
    float tq = rq[0] + rq[1] + rq[2] + rq[3];
    float mu = ts * (1.f / C_);
    float var = tq * (1.f / C_) - mu * mu;
    float rstd = rsqrtf(var + 1e-5f);
#pragma unroll
    for (int k = 0; k < 3; ++k) {
        int c = tid + k * 256;
        float xv = (k == 0 ? x0 : (k == 1 ? x1 : x2));
        outb[base + c] = __float2bfloat16((xv - mu) * rstd * w[c] + b[c]);
    }
}

// ---------------- forward rfft along W (only wf<46), scaled by 1/sqrt(16200) ----------------
__global__ __launch_bounds__(256) void wfft_kernel(const __hip_bfloat16* __restrict__ h1,
        float* __restrict__ f1r, float* __restrict__ f1i,
        const float* __restrict__ fwc, const float* __restrict__ fws)
{
    __shared__ float xs[W_ * 64];
    int slab = blockIdx.x;           // b*90+h
    int c0 = blockIdx.y * 64;
    int tid = threadIdx.x;
    const short* src = (const short*)h1 + (size_t)slab * W_ * C_ + c0;
    for (int i = tid; i < W_ * 8; i += 256) {
        int w = i >> 3, c8 = (i & 7) * 8;
        short8 v = *(const short8*)&src[(size_t)w * C_ + c8];
        float* dst = &xs[w * 64 + c8];
#pragma unroll
        for (int j = 0; j < 8; ++j) dst[j] = bf2f(v[j]);
    }
    __syncthreads();
    const float S = 0.00785674201318386f; // 1/sqrt(90*180)
    for (int t = tid; t < WFK * 16; t += 256) {
        int wf = t >> 4, cg = (t & 15) << 2;
        const float* cw = fwc + wf * W_;
        const float* sw = fws + wf * W_;
        float ar0 = 0, ar1 = 0, ar2 = 0, ar3 = 0, ai0 = 0, ai1 = 0, ai2 = 0, ai3 = 0;
        for (int w = 0; w < W_; ++w) {
            float c = cw[w], sn = sw[w];
            float4 x = *(const float4*)&xs[w * 64 + cg];
            ar0 = fmaf(x.x, c, ar0); ai0 = fmaf(-x.x, sn, ai0);
            ar1 = fmaf(x.y, c, ar1); ai1 = fmaf(-x.y, sn, ai1);
            ar2 = fmaf(x.z, c, ar2); ai2 = fmaf(-x.z, sn, ai2);
            ar3 = fmaf(x.w, c, ar3); ai3 = fmaf(-x.w, sn, ai3);
        }
        size_t o = ((size_t)slab * WFK + wf) * C_ + c0 + cg;
        *(float4*)&f1r[o] = make_float4(S*ar0, S*ar1, S*ar2, S*ar3);
        *(float4*)&f1i[o] = make_float4(S*ai0, S*ai1, S*ai2, S*ai3);
    }
}

// ---------------- complex DFT along H (90-pt), IN-PLACE; sg=+1 fwd e^{-i}, sg=-1 inv e^{+i} ----------------
__global__ __launch_bounds__(256) void hdft_kernel(float* __restrict__ dr, float* __restrict__ di,
        const float* __restrict__ hc, const float* __restrict__ hs, float sg)
{
    __shared__ float xr[H_ * 64], xi[H_ * 64];
    int bwf = blockIdx.x;            // b*46+wf
    int b = bwf / WFK, wf = bwf % WFK;
    int c0 = blockIdx.y * 64;
    int tid = threadIdx.x;
    size_t base = ((size_t)(b * H_) * WFK + wf) * C_ + c0;
    for (int i = tid; i < H_ * 16; i += 256) {
        int h = i >> 4, c4 = (i & 15) << 2;
        size_t a = base + (size_t)h * WFK * C_ + c4;
        *(float4*)&xr[h * 64 + c4] = *(const float4*)&dr[a];
        *(float4*)&xi[h * 64 + c4] = *(const float4*)&di[a];
    }
    __syncthreads();
    for (int t = tid; t < H_ * 16; t += 256) {
        int k = t >> 4, cg = (t & 15) << 2;
        const float* cc = hc + k * H_;
        const float* ss = hs + k * H_;
        float or0=0,or1=0,or2=0,or3=0, oi0=0,oi1=0,oi2=0,oi3=0;
        for (int h = 0; h < H_; ++h) {
            float c = cc[h], s = sg * ss[h];
            float4 vr = *(const float4*)&xr[h * 64 + cg];
            float4 vi = *(const float4*)&xi[h * 64 + cg];
            or0 = fmaf(vr.x, c, fmaf(vi.x, s, or0)); oi0 = fmaf(vi.x, c, fmaf(-vr.x, s, oi0));
            or1 = fmaf(vr.y, c, fmaf(vi.y, s, or1)); oi1 = fmaf(vi.y, c, fmaf(-vr.y, s, oi1));
            or2 = fmaf(vr.z, c, fmaf(vi.z, s, or2)); oi2 = fmaf(vi.z, c, fmaf(-vr.z, s, oi2));
            or3 = fmaf(vr.w, c, fmaf(vi.w, s, or3)); oi3 = fmaf(vi.w, c, fmaf(-vr.w, s, oi3));
        }
        size_t o = base + (size_t)k * WFK * C_ + cg;
        *(float4*)&dr[o] = make_float4(or0, or1, or2, or3);
        *(float4*)&di[o] = make_float4(oi0, oi1, oi2, oi3);
    }
}

// ---------------- block-diagonal complex 2-layer MLP + softshrink, IN-PLACE ----------------
__global__ __launch_bounds__(256) void blockmlp_kernel(
        float* __restrict__ vr, float* __restrict__ vi,
        const float* __restrict__ w1, const float* __restrict__ b1,
        const float* __restrict__ w2, const float* __restrict__ b2)
{
    __shared__ float X[64 * 192];    // per pos: [xr(96) xi(96)]
    int chunk = blockIdx.x;          // 130 chunks of 64 positions
    int nb = blockIdx.y;
    int tid = threadIdx.x;
    int p0 = chunk * 64;
    for (int i = tid; i < 64 * 24; i += 256) {
        int p = i / 24, q = i % 24;
        int pg = p0 + p;
        float4 r4 = make_float4(0,0,0,0), i4 = make_float4(0,0,0,0);
        if (pg < NPOS) {
            size_t a = (size_t)pg * C_ + nb * BSK + q * 4;
            r4 = *(const float4*)&vr[a];
            i4 = *(const float4*)&vi[a];
        }
        *(float4*)&X[p * 192 + q * 4] = r4;
        *(float4*)&X[p * 192 + 96 + q * 4] = i4;
    }
    __syncthreads();
    const float* w1r = w1 + (size_t)nb * BSK * BSK;
    const float* w1i = w1 + (size_t)(NBK + nb) * BSK * BSK;
    const float* b1r = b1 + nb * BSK;
    const float* b1i = b1 + (NBK + nb) * BSK;
    float o1r[6][4], o1i[6][4];
#pragma unroll
    for (int it = 0; it < 6; ++it) {
        int t = tid + it * 256;
        int p = t / 24, og = (t % 24) * 4;
        float r0 = b1r[og], r1 = b1r[og+1], r2 = b1r[og+2], r3 = b1r[og+3];
        float i0 = b1i[og], i1 = b1i[og+1], i2 = b1i[og+2], i3 = b1i[og+3];
        for (int k = 0; k < BSK; ++k) {
            float xr = X[p * 192 + k];
            float xi = X[p * 192 + 96 + k];
            float4 wr = *(const float4*)&w1r[k * BSK + og];
            float4 wi = *(const float4*)&w1i[k * BSK + og];
            r0 = fmaf(xr, wr.x, fmaf(-xi, wi.x, r0)); i0 = fmaf(xi, wr.x, fmaf(xr, wi.x, i0));
            r1 = fmaf(xr, wr.y, fmaf(-xi, wi.y, r1)); i1 = fmaf(xi, wr.y, fmaf(xr, wi.y, i1));
            r2 = fmaf(xr, wr.z, fmaf(-xi, wi.z, r2)); i2 = fmaf(xi, wr.z, fmaf(xr, wi.z, i2));
            r3 = fmaf(xr, wr.w, fmaf(-xi, wi.w, r3)); i3 = fmaf(xi, wr.w, fmaf(xr, wi.w, i3));
        }
        o1r[it][0] = fmaxf(r0, 0.f); o1r[it][1] = fmaxf(r1, 0.f); o1r[it][2] = fmaxf(r2, 0.f); o1r[it][3] = fmaxf(r3, 0.f);
        o1i[it][0] = fmaxf(i0, 0.f); o1i[it][1] = fmaxf(i1, 0.f); o1i[it][2] = fmaxf(i2, 0.f); o1i[it][3] = fmaxf(i3, 0.f);
    }
    __syncthreads();
#pragma unroll
    for (int it = 0; it < 6; ++it) {
        int t = tid + it * 256;
        int p = t / 24, og = (t % 24) * 4;
        *(float4*)&X[p * 192 + og]      = make_float4(o1r[it][0], o1r[it][1], o1r[it][2], o1r[it][3]);
        *(float4*)&X[p * 192 + 96 + og] = make_float4(o1i[it][0], o1i[it][1], o1i[it][2], o1i[it][3]);
    }
    __syncthreads();
    const float* w2r = w2 + (size_t)nb * BSK * BSK;
    const float* w2i = w2 + (size_t)(NBK + nb) * BSK * BSK;
    const float* b2r = b2 + nb * BSK;
    const float* b2i = b2 + (NBK + nb) * BSK;
#pragma unroll
    for (int it = 0; it < 6; ++it) {
        int t = tid + it * 256;
        int p = t / 24, ig = (t % 24) * 4;
        int pg = p0 + p;
        float r0 = b2r[ig], r1 = b2r[ig+1], r2 = b2r[ig+2], r3 = b2r[ig+3];
        float i0 = b2i[ig], i1 = b2i[ig+1], i2 = b2i[ig+2], i3 = b2i[ig+3];
        for (int o = 0; o < BSK; ++o) {
            float xr = X[p * 192 + o];
            float xi = X[p * 192 + 96 + o];
            float4 wr = *(const float4*)&w2r[o * BSK + ig];
            float4 wi = *(const float4*)&w2i[o * BSK + ig];
            r0 = fmaf(xr, wr.x, fmaf(-xi, wi.x, r0)); i0 = fmaf(xi, wr.x, fmaf(xr, wi.x, i0));
            r1 = fmaf(xr, wr.y, fmaf(-xi, wi.y, r1)); i1 = fmaf(xi, wr.y, fmaf(xr, wi.y, i1));
            r2 = fmaf(xr, wr.z, fmaf(-xi, wi.z, r2)); i2 = fmaf(xi, wr.z, fmaf(xr, wi.z, i2));
            r3 = fmaf(xr, wr.w, fmaf(-xi, wi.w, r3)); i3 = fmaf(xi, wr.w, fmaf(xr, wi.w, i3));
        }
        if (pg < NPOS) {
            auto ss = [](float v) { return v > LAM ? v - LAM : (v < -LAM ? v + LAM : 0.f); };
            size_t a = (size_t)pg * C_ + nb * BSK + ig;
            *(float4*)&vr[a] = make_float4(ss(r0), ss(r1), ss(r2), ss(r3));
            *(float4*)&vi[a] = make_float4(ss(i0), ss(i1), ss(i2), ss(i3));
        }
    }
}

// ---------------- inverse rfft along W (wf>=46 zero; imag of DC ignored) + residuals ----------------
__global__ __launch_bounds__(256) void iwfft_kernel(
        const float* __restrict__ inr, const float* __restrict__ ini,
        const __hip_bfloat16* __restrict__ h1, const float* __restrict__ x,
        float* __restrict__ out, const float* __restrict__ fwc, const float* __restrict__ fws)
{
    __shared__ float yr[WFK * 64], yi[WFK * 64];
    int slab = blockIdx.x; int c0 = blockIdx.y * 64; int tid = threadIdx.x;
    size_t sb = (size_t)slab * WFK * C_ + c0;
    for (int i = tid; i < WFK * 16; i += 256) {
        int wf = i >> 4, c4 = (i & 15) << 2;
        size_t a = sb + (size_t)wf * C_ + c4;
        *(float4*)&yr[wf * 64 + c4] = *(const float4*)&inr[a];
        *(float4*)&yi[wf * 64 + c4] = *(const float4*)&ini[a];
    }
    __syncthreads();
    const float S = 0.00785674201318386f;
    const short* hp = (const short*)h1;
    for (int t = tid; t < W_ * 16; t += 256) {
        int w = t >> 4, cg = (t & 15) << 2;
        float4 y0 = *(const float4*)&yr[cg];  // wf=0: real part only
        float a0 = y0.x, a1 = y0.y, a2 = y0.z, a3 = y0.w;
        for (int wf = 1; wf < WFK; ++wf) {
            float c2 = 2.f * fwc[wf * W_ + w], s2 = 2.f * fws[wf * W_ + w];
            float4 vr = *(const float4*)&yr[wf * 64 + cg];
            float4 vi = *(const float4*)&yi[wf * 64 + cg];
            a0 = fmaf(vr.x, c2, fmaf(-vi.x, s2, a0));
            a1 = fmaf(vr.y, c2, fmaf(-vi.y, s2, a1));
            a2 = fmaf(vr.z, c2, fmaf(-vi.z, s2, a2));
            a3 = fmaf(vr.w, c2, fmaf(-vi.w, s2, a3));
        }
        size_t o = ((size_t)slab * W_ + w) * C_ + c0 + cg;
        short4v hv = *(const short4v*)&hp[o];
        float4 xv = *(const float4*)&x[o];
        float4 r;
        r.x = fmaf(S, a0, bf2f(hv[0]) + xv.x);
        r.y = fmaf(S, a1, bf2f(hv[1]) + xv.y);
        r.z = fmaf(S, a2, bf2f(hv[2]) + xv.z);
        r.w = fmaf(S, a3, bf2f(hv[3]) + xv.w);
        *(float4*)&out[o] = r;
    }
}

// ---------------- transpose + f32->bf16 (weights) ----------------
__global__ __launch_bounds__(256) void transpose_cvt_kernel(const float* __restrict__ Wm,
        __hip_bfloat16* __restrict__ Wt, int R, int Ccol)
{
    __shared__ float tile[32][33];
    int c0 = blockIdx.x * 32, r0 = blockIdx.y * 32;
    int tid = threadIdx.x;
    int tc = tid & 31, tr = tid >> 5;
#pragma unroll
    for (int k = 0; k < 4; ++k)
        tile[tr + k * 8][tc] = Wm[(size_t)(r0 + tr + k * 8) * Ccol + c0 + tc];
    __syncthreads();
    int rr = tid & 31, cc = tid >> 5;
#pragma unroll
    for (int k = 0; k < 4; ++k)
        Wt[(size_t)(c0 + cc + k * 8) * R + r0 + rr] = __float2bfloat16(tile[rr][cc + k * 8]);
}

// ---------------- bf16 MFMA GEMM: C[M,N] = A[M,K] * Bt[N,K]^T ----------------
// EPI 0: out = bf16( gelu(acc + bias) ) -> obf      (all rows)
// EPI 1: out = f32 ( acc + bias + res )  -> of32    (rows < mvalid only)
template<int EPI>
__global__ __launch_bounds__(256) void gemm_kernel(
        const short* __restrict__ A, const short* __restrict__ Bt,
        const float* __restrict__ bias,
        __hip_bfloat16* __restrict__ obf, float* __restrict__ of32,
        const float* __restrict__ res, int N, int K, int mvalid)
{
    __shared__ short As[128 * 40];
    __shared__ short Bs[128 * 40];
    int tid = threadIdx.x;
    int wid = tid >> 6, lane = tid & 63;
    int wm = (wid >> 1) * 64, wn = (wid & 1) * 64;
    int lrow = lane & 15, lk8 = lane >> 4;
    f32x4 zero = {0.f, 0.f, 0.f, 0.f};
    f32x4 acc[4][4];
#pragma unroll
    for (int i = 0; i < 4; ++i)
#pragma unroll
        for (int j = 0; j < 4; ++j) acc[i][j] = zero;
    size_t m0 = (size_t)blockIdx.x * 128, n0 = (size_t)blockIdx.y * 128;
    int srow = tid >> 2;
    int scol = (tid & 3) * 8;
    const short* Ag = A + (m0 + srow) * K + scol;
    const short* Bg = Bt + (n0 + srow) * K + scol;
    for (int k0 = 0; k0 < K; k0 += 32) {
        int4 a0 = *(const int4*)(Ag + k0);
        int4 a1 = *(const int4*)(Ag + k0 + (size_t)64 * K);
        int4 b0 = *(const int4*)(Bg + k0);
        int4 b1 = *(const int4*)(Bg + k0 + (size_t)64 * K);
        __syncthreads();
        *(int4*)&As[srow * 40 + scol] = a0;
        *(int4*)&As[(srow + 64) * 40 + scol] = a1;
        *(int4*)&Bs[srow * 40 + scol] = b0;
        *(int4*)&Bs[(srow + 64) * 40 + scol] = b1;
        __syncthreads();
        short8 af[4], bfr[4];
#pragma unroll
        for (int mf = 0; mf < 4; ++mf) af[mf] = *(const short8*)&As[(wm + mf * 16 + lrow) * 40 + lk8 * 8];
#pragma unroll
        for (int nf = 0; nf < 4; ++nf) bfr[nf] = *(const short8*)&Bs[(wn + nf * 16 + lrow) * 40 + lk8 * 8];
#pragma unroll
        for (int mf = 0; mf < 4; ++mf)
#pragma unroll
            for (int nf = 0; nf < 4; ++nf)
                acc[mf][nf] = __builtin_amdgcn_mfma_f32_16x16x32_bf16(af[mf], bfr[nf], acc[mf][nf], 0, 0, 0);
    }
    int crow = (lane >> 4) * 4;
    int ccol = lane & 15;
#pragma unroll
    for (int mf = 0; mf < 4; ++mf) {
#pragma unroll
        for (int j = 0; j < 4; ++j) {
            size_t r = m0 + wm + mf * 16 + crow + j;
            if (EPI == 1 && r >= (size_t)mvalid) continue;
#pragma unroll
            for (int nf = 0; nf < 4; ++nf) {
                size_t cidx = n0 + wn + nf * 16 + ccol;
                float v = acc[mf][nf][j] + bias[cidx];
                if (EPI == 0) {
                    float g = 0.5f * v * (1.f + erff(v * 0.70710678118654752f));
                    obf[r * N + cidx] = __float2bfloat16(g);
                } else {
                    of32[r * N + cidx] = v + res[r * N + cidx];
                }
            }
        }
    }
}

extern "C" void kernel_launch(void* const* d_in, const int* in_sizes, int n_in,
                              void* d_out, int out_size, void* d_ws, size_t ws_size,
                              hipStream_t stream) {
    (void)in_sizes; (void)n_in; (void)out_size; (void)ws_size;
    const float* x    = (const float*)d_in[0];
    const float* n1w  = (const float*)d_in[1];
    const float* n1b  = (const float*)d_in[2];
    const float* w1   = (const float*)d_in[3];
    const float* b1   = (const float*)d_in[4];
    const float* w2   = (const float*)d_in[5];
    const float* b2   = (const float*)d_in[6];
    const float* n2w  = (const float*)d_in[7];
    const float* n2b  = (const float*)d_in[8];
    const float* fc1w = (const float*)d_in[9];
    const float* fc1b = (const float*)d_in[10];
    const float* fc2w = (const float*)d_in[11];
    const float* fc2b = (const float*)d_in[12];
    float* out = (float*)d_out;

    // ---- workspace layout (~110.4 MB total) with region aliasing ----
    float* wsf = (float*)d_ws;
    size_t off = 0;
    auto alloc = [&](size_t nfloats) { float* p = wsf + off; off += (nfloats + 63) & ~(size_t)63; return p; };
    // region1: h1 (bf16, NTOK*C) until iwfft; then h3 (bf16, MPAD*C)
    float* region1 = alloc((size_t)MPAD * C_ / 2);
    // region2: f1r,f1i (f32, NPOS*C each) until iwfft; then tb chunk (bf16, CHROWS*HID)
    float* region2 = alloc((size_t)2 * NPOS * C_);
    __hip_bfloat16* w1t = (__hip_bfloat16*)alloc((size_t)HID * C_ / 2);
    __hip_bfloat16* w2t = (__hip_bfloat16*)alloc((size_t)HID * C_ / 2);
    float* fwc  = alloc(WFK * W_);
    float* fws  = alloc(WFK * W_);
    float* hc   = alloc(H_ * H_);
    float* hs   = alloc(H_ * H_);

    __hip_bfloat16* h1b = (__hip_bfloat16*)region1;
    __hip_bfloat16* h3  = (__hip_bfloat16*)region1;
    float* f1r = region2;
    float* f1i = region2 + (size_t)NPOS * C_;
    __hip_bfloat16* tb  = (__hip_bfloat16*)region2;

    init_tables_kernel<<<33, 256, 0, stream>>>(fwc, fws, hc, hs);
    transpose_cvt_kernel<<<dim3(HID / 32, C_ / 32), 256, 0, stream>>>(fc1w, w1t, C_, HID);
    transpose_cvt_kernel<<<dim3(C_ / 32, HID / 32), 256, 0, stream>>>(fc2w, w2t, HID, C_);

    ln_kernel<<<NTOK, 256, 0, stream>>>(x, n1w, n1b, h1b, NTOK);
    wfft_kernel<<<dim3(B_ * H_, 12), 256, 0, stream>>>(h1b, f1r, f1i, fwc, fws);
    hdft_kernel<<<dim3(B_ * WFK, 12), 256, 0, stream>>>(f1r, f1i, hc, hs, 1.f);
    blockmlp_kernel<<<dim3(130, NBK), 256, 0, stream>>>(f1r, f1i, w1, b1, w2, b2);
    hdft_kernel<<<dim3(B_ * WFK, 12), 256, 0, stream>>>(f1r, f1i, hc, hs, -1.f);
    iwfft_kernel<<<dim3(B_ * H_, 12), 256, 0, stream>>>(f1r, f1i, h1b, x, out, fwc, fws);
    // h1b, f1r/f1i dead from here; regions reused by h3 and tb
    ln_kernel<<<MPAD, 256, 0, stream>>>(out, n2w, n2b, h3, NTOK);
    for (int c = 0; c < 4; ++c) {
        int base = c * CHROWS;
        int tiles = (c < 3) ? (CHROWS / 128) : ((MPAD - 3 * CHROWS) / 128); // 64,64,64,62
        gemm_kernel<0><<<dim3(tiles, HID / 128), 256, 0, stream>>>(
            (const short*)(h3 + (size_t)base * C_), (const short*)w1t, fc1b,
            tb, nullptr, nullptr, HID, C_, 0);
        gemm_kernel<1><<<dim3(tiles, C_ / 128), 256, 0, stream>>>(
            (const short*)tb, (const short*)w2t, fc2b,
            nullptr, out + (size_t)base * C_, out + (size_t)base * C_, C_, HID, NTOK - base);
    }
}

// Round 3
// 1163.182 us; speedup vs baseline: 1.2239x; 1.2239x over previous
//
#include <hip/hip_runtime.h>
#include <hip/hip_bf16.h>

#define B_    2
#define H_    90
#define W_    180
#define C_    768
#define WFK   46          // kept W-frequency modes (of 91)
#define NBK   8
#define BSK   96
#define HID   3072
#define NTOK  (B_*H_*W_)  // 32400
#define MPAD  32512       // 254*128
#define NPOS  (B_*H_*WFK) // 8280
#define LAM   0.01f
#define CHROWS 8192       // gemm M-chunk rows (64 tiles of 128)

typedef __attribute__((ext_vector_type(8))) short short8;
typedef __attribute__((ext_vector_type(4))) short short4v;
typedef __attribute__((ext_vector_type(4))) float f32x4;

__device__ __forceinline__ float bf2f(short u) {
    union { unsigned int i; float f; } z;
    z.i = ((unsigned int)(unsigned short)u) << 16;
    return z.f;
}

// ---------------- DFT twiddle tables ----------------
__global__ __launch_bounds__(256) void init_tables_kernel(float* fwc, float* fws, float* hc, float* hs) {
    int i = blockIdx.x * 256 + threadIdx.x;
    if (i < WFK * W_) {
        int wf = i / W_, w = i % W_;
        int p = (w * wf) % W_;
        float th = (float)p * (float)(6.283185307179586476925286766559 / 180.0);
        fwc[i] = cosf(th); fws[i] = sinf(th);
    }
    if (i < H_ * H_) {
        int k = i / H_, h = i % H_;
        int p = (h * k) % H_;
        float th = (float)p * (float)(6.283185307179586476925286766559 / 90.0);
        hc[i] = cosf(th); hs[i] = sinf(th);
    }
}

// ---------------- build expanded real weights for the block-MLP ----------------
// wbig[L][nb][o][k] (bf16), k contiguous:  out[o] = sum_k X[k]*Wbig[k][o]
//   o<96,k<96:  wr[k][o] ; o<96,k>=96: -wi[k'][o] ; o>=96,k<96: wi[k][o'] ; o>=96,k>=96: wr[k'][o']
__global__ __launch_bounds__(256) void wprep_kernel(
        const float* __restrict__ w1, const float* __restrict__ b1,
        const float* __restrict__ w2, const float* __restrict__ b2,
        __hip_bfloat16* __restrict__ wbig, float* __restrict__ bbig)
{
    int idx = blockIdx.x * 256 + threadIdx.x;
    if (idx < 2 * NBK * 192 * 192) {
        int k = idx % 192;
        int o = (idx / 192) % 192;
        int nb = (idx / (192 * 192)) % NBK;
        int L = idx / (192 * 192 * NBK);
        const float* w = L ? w2 : w1;
        const float* wr = w + (size_t)nb * BSK * BSK;
        const float* wi = w + (size_t)(NBK + nb) * BSK * BSK;
        int kk = k % BSK, oo = o % BSK;
        float val;
        if (o < BSK)  val = (k < BSK) ? wr[kk * BSK + oo] : -wi[kk * BSK + oo];
        else          val = (k < BSK) ? wi[kk * BSK + oo] :  wr[kk * BSK + oo];
        wbig[((size_t)(L * NBK + nb) * 192 + o) * 192 + k] = __float2bfloat16(val);
    }
    if (idx < 2 * NBK * 192) {
        int o = idx % 192;
        int nb = (idx / 192) % NBK;
        int L = idx / (192 * NBK);
        const float* b = L ? b2 : b1;
        bbig[idx] = (o < BSK) ? b[nb * BSK + o] : b[(NBK + nb) * BSK + (o - BSK)];
    }
}

// ---------------- LayerNorm: f32 in -> bf16 out, zero-pads rows >= ntok_valid ----------------
__global__ __launch_bounds__(256) void ln_kernel(const float* __restrict__ in,
        const float* __restrict__ w, const float* __restrict__ b,
        __hip_bfloat16* __restrict__ outb, int ntok_valid)
{
    int tok = blockIdx.x;
    int tid = threadIdx.x;
    size_t base = (size_t)tok * C_;
    if (tok >= ntok_valid) {
        __hip_bfloat16 z = __float2bfloat16(0.f);
        outb[base + tid] = z; outb[base + tid + 256] = z; outb[base + tid + 512] = z;
        return;
    }
    float x0 = in[base + tid], x1 = in[base + tid + 256], x2 = in[base + tid + 512];
    float s = x0 + x1 + x2;
    float q = x0*x0 + x1*x1 + x2*x2;
#pragma unroll
    for (int off = 32; off > 0; off >>= 1) { s += __shfl_down(s, off); q += __shfl_down(q, off); }
    __shared__ float rs[4], rq[4];
    int wid = tid >> 6, lane = tid & 63;
    if (lane == 0) { rs[wid] = s; rq[wid] = q; }
    __syncthreads();
    float ts = rs[0] + rs[1] + rs[2] + rs[3];
    float tq = rq[0] + rq[1] + rq[2] + rq[3];
    float mu = ts * (1.f / C_);
    float var = tq * (1.f / C_) - mu * mu;
    float rstd = rsqrtf(var + 1e-5f);
#pragma unroll
    for (int k = 0; k < 3; ++k) {
        int c = tid + k * 256;
        float xv = (k == 0 ? x0 : (k == 1 ? x1 : x2));
        outb[base + c] = __float2bfloat16((xv - mu) * rstd * w[c] + b[c]);
    }
}

// ---------------- forward rfft along W (only wf<46), scaled by 1/sqrt(16200) ----------------
__global__ __launch_bounds__(256) void wfft_kernel(const __hip_bfloat16* __restrict__ h1,
        float* __restrict__ f1r, float* __restrict__ f1i,
        const float* __restrict__ fwc, const float* __restrict__ fws)
{
    __shared__ float xs[W_ * 64];
    int slab = blockIdx.x;           // b*90+h
    int c0 = blockIdx.y * 64;
    int tid = threadIdx.x;
    const short* src = (const short*)h1 + (size_t)slab * W_ * C_ + c0;
    for (int i = tid; i < W_ * 8; i += 256) {
        int w = i >> 3, c8 = (i & 7) * 8;
        short8 v = *(const short8*)&src[(size_t)w * C_ + c8];
        float* dst = &xs[w * 64 + c8];
#pragma unroll
        for (int j = 0; j < 8; ++j) dst[j] = bf2f(v[j]);
    }
    __syncthreads();
    const float S = 0.00785674201318386f; // 1/sqrt(90*180)
    for (int t = tid; t < WFK * 16; t += 256) {
        int wf = t >> 4, cg = (t & 15) << 2;
        const float* cw = fwc + wf * W_;
        const float* sw = fws + wf * W_;
        float ar0 = 0, ar1 = 0, ar2 = 0, ar3 = 0, ai0 = 0, ai1 = 0, ai2 = 0, ai3 = 0;
        for (int w = 0; w < W_; ++w) {
            float c = cw[w], sn = sw[w];
            float4 x = *(const float4*)&xs[w * 64 + cg];
            ar0 = fmaf(x.x, c, ar0); ai0 = fmaf(-x.x, sn, ai0);
            ar1 = fmaf(x.y, c, ar1); ai1 = fmaf(-x.y, sn, ai1);
            ar2 = fmaf(x.z, c, ar2); ai2 = fmaf(-x.z, sn, ai2);
            ar3 = fmaf(x.w, c, ar3); ai3 = fmaf(-x.w, sn, ai3);
        }
        size_t o = ((size_t)slab * WFK + wf) * C_ + c0 + cg;
        *(float4*)&f1r[o] = make_float4(S*ar0, S*ar1, S*ar2, S*ar3);
        *(float4*)&f1i[o] = make_float4(S*ai0, S*ai1, S*ai2, S*ai3);
    }
}

// ---------------- complex DFT along H (90-pt), IN-PLACE; sg=+1 fwd e^{-i}, sg=-1 inv e^{+i} ----------------
__global__ __launch_bounds__(256) void hdft_kernel(float* __restrict__ dr, float* __restrict__ di,
        const float* __restrict__ hc, const float* __restrict__ hs, float sg)
{
    __shared__ float xr[H_ * 64], xi[H_ * 64];
    int bwf = blockIdx.x;            // b*46+wf
    int b = bwf / WFK, wf = bwf % WFK;
    int c0 = blockIdx.y * 64;
    int tid = threadIdx.x;
    size_t base = ((size_t)(b * H_) * WFK + wf) * C_ + c0;
    for (int i = tid; i < H_ * 16; i += 256) {
        int h = i >> 4, c4 = (i & 15) << 2;
        size_t a = base + (size_t)h * WFK * C_ + c4;
        *(float4*)&xr[h * 64 + c4] = *(const float4*)&dr[a];
        *(float4*)&xi[h * 64 + c4] = *(const float4*)&di[a];
    }
    __syncthreads();
    for (int t = tid; t < H_ * 16; t += 256) {
        int k = t >> 4, cg = (t & 15) << 2;
        const float* cc = hc + k * H_;
        const float* ss = hs + k * H_;
        float or0=0,or1=0,or2=0,or3=0, oi0=0,oi1=0,oi2=0,oi3=0;
        for (int h = 0; h < H_; ++h) {
            float c = cc[h], s = sg * ss[h];
            float4 vr = *(const float4*)&xr[h * 64 + cg];
            float4 vi = *(const float4*)&xi[h * 64 + cg];
            or0 = fmaf(vr.x, c, fmaf(vi.x, s, or0)); oi0 = fmaf(vi.x, c, fmaf(-vr.x, s, oi0));
            or1 = fmaf(vr.y, c, fmaf(vi.y, s, or1)); oi1 = fmaf(vi.y, c, fmaf(-vr.y, s, oi1));
            or2 = fmaf(vr.z, c, fmaf(vi.z, s, or2)); oi2 = fmaf(vi.z, c, fmaf(-vr.z, s, oi2));
            or3 = fmaf(vr.w, c, fmaf(vi.w, s, or3)); oi3 = fmaf(vi.w, c, fmaf(-vr.w, s, oi3));
        }
        size_t o = base + (size_t)k * WFK * C_ + cg;
        *(float4*)&dr[o] = make_float4(or0, or1, or2, or3);
        *(float4*)&di[o] = make_float4(oi0, oi1, oi2, oi3);
    }
}

// ---------------- block-diagonal complex 2-layer MLP + softshrink, IN-PLACE, via MFMA ----------------
// Per CTA: 64 positions x one block nb. X row layout: [xr(96) | xi(96)] in bf16 LDS (stride 200).
// Layer l: O = act(X @ Wbig_l + bbig_l) with Wbig in [o][k] order read straight from L2.
__global__ __launch_bounds__(256) void blockmlp_mfma_kernel(
        float* __restrict__ vr, float* __restrict__ vi,
        const __hip_bfloat16* __restrict__ wbig, const float* __restrict__ bbig)
{
    __shared__ __hip_bfloat16 X1[64 * 200];
    __shared__ __hip_bfloat16 X2[64 * 200];
    int chunk = blockIdx.x;          // 130 chunks of 64 positions
    int nb = blockIdx.y;
    int tid = threadIdx.x, wid = tid >> 6, lane = tid & 63;
    int p0 = chunk * 64;
    // ---- load & convert X tile ----
    for (int i = tid; i < 64 * 48; i += 256) {
        int p = i / 48, q = i % 48;
        int pg = p0 + p;
        int c4 = (q % 24) * 4;
        bool isr = q < 24;
        float4 v = make_float4(0, 0, 0, 0);
        if (pg < NPOS) {
            const float* src = isr ? vr : vi;
            v = *(const float4*)&src[(size_t)pg * C_ + nb * BSK + c4];
        }
        __hip_bfloat16* d = &X1[p * 200 + (isr ? 0 : 96) + c4];
        d[0] = __float2bfloat16(v.x); d[1] = __float2bfloat16(v.y);
        d[2] = __float2bfloat16(v.z); d[3] = __float2bfloat16(v.w);
    }
    __syncthreads();
    int n0 = wid * 48;
    int lrow = lane & 15, lk8 = lane >> 4;
    int crow = (lane >> 4) * 4, ccol = lane & 15;
    const short* W1 = (const short*)(wbig + (size_t)nb * 192 * 192);
    const short* W2 = (const short*)(wbig + (size_t)(NBK + nb) * 192 * 192);
    const float* bb1 = bbig + nb * 192;
    const float* bb2 = bbig + (NBK + nb) * 192;
    f32x4 zero = {0.f, 0.f, 0.f, 0.f};
    // ---- layer 1 ----
    {
        f32x4 acc[4][3];
#pragma unroll
        for (int m = 0; m < 4; ++m)
#pragma unroll
            for (int n = 0; n < 3; ++n) acc[m][n] = zero;
#pragma unroll
        for (int k0 = 0; k0 < 192; k0 += 32) {
            short8 af[4], bf[3];
#pragma unroll
            for (int m = 0; m < 4; ++m)
                af[m] = *(const short8*)&X1[(m * 16 + lrow) * 200 + k0 + lk8 * 8];
#pragma unroll
            for (int n = 0; n < 3; ++n)
                bf[n] = *(const short8*)&W1[(size_t)(n0 + n * 16 + lrow) * 192 + k0 + lk8 * 8];
#pragma unroll
            for (int m = 0; m < 4; ++m)
#pragma unroll
                for (int n = 0; n < 3; ++n)
                    acc[m][n] = __builtin_amdgcn_mfma_f32_16x16x32_bf16(af[m], bf[n], acc[m][n], 0, 0, 0);
        }
        __syncthreads();   // X1 reads done before X2 written? (X2 separate buffer; sync for X2 reuse pattern)
#pragma unroll
        for (int m = 0; m < 4; ++m)
#pragma unroll
            for (int j = 0; j < 4; ++j) {
                int row = m * 16 + crow + j;
#pragma unroll
                for (int n = 0; n < 3; ++n) {
                    int col = n0 + n * 16 + ccol;
                    float v = acc[m][n][j] + bb1[col];
                    X2[row * 200 + col] = __float2bfloat16(fmaxf(v, 0.f));
                }
            }
    }
    __syncthreads();
    // ---- layer 2 + softshrink + in-place store ----
    {
        f32x4 acc[4][3];
#pragma unroll
        for (int m = 0; m < 4; ++m)
#pragma unroll
            for (int n = 0; n < 3; ++n) acc[m][n] = zero;
#pragma unroll
        for (int k0 = 0; k0 < 192; k0 += 32) {
            short8 af[4], bf[3];
#pragma unroll
            for (int m = 0; m < 4; ++m)
                af[m] = *(const short8*)&X2[(m * 16 + lrow) * 200 + k0 + lk8 * 8];
#pragma unroll
            for (int n = 0; n < 3; ++n)
                bf[n] = *(const short8*)&W2[(size_t)(n0 + n * 16 + lrow) * 192 + k0 + lk8 * 8];
#pragma unroll
            for (int m = 0; m < 4; ++m)
#pragma unroll
                for (int n = 0; n < 3; ++n)
                    acc[m][n] = __builtin_amdgcn_mfma_f32_16x16x32_bf16(af[m], bf[n], acc[m][n], 0, 0, 0);
        }
#pragma unroll
        for (int m = 0; m < 4; ++m)
#pragma unroll
            for (int j = 0; j < 4; ++j) {
                int row = m * 16 + crow + j;
                int pg = p0 + row;
                if (pg >= NPOS) continue;
#pragma unroll
                for (int n = 0; n < 3; ++n) {
                    int col = n0 + n * 16 + ccol;
                    float v = acc[m][n][j] + bb2[col];
                    v = v > LAM ? v - LAM : (v < -LAM ? v + LAM : 0.f);
                    if (col < BSK) vr[(size_t)pg * C_ + nb * BSK + col] = v;
                    else           vi[(size_t)pg * C_ + nb * BSK + col - BSK] = v;
                }
            }
    }
}

// ---------------- inverse rfft along W (wf>=46 zero; imag of DC ignored) + residuals ----------------
__global__ __launch_bounds__(256) void iwfft_kernel(
        const float* __restrict__ inr, const float* __restrict__ ini,
        const __hip_bfloat16* __restrict__ h1, const float* __restrict__ x,
        float* __restrict__ out, const float* __restrict__ fwc, const float* __restrict__ fws)
{
    __shared__ float yr[WFK * 64], yi[WFK * 64];
    int slab = blockIdx.x; int c0 = blockIdx.y * 64; int tid = threadIdx.x;
    size_t sb = (size_t)slab * WFK * C_ + c0;
    for (int i = tid; i < WFK * 16; i += 256) {
        int wf = i >> 4, c4 = (i & 15) << 2;
        size_t a = sb + (size_t)wf * C_ + c4;
        *(float4*)&yr[wf * 64 + c4] = *(const float4*)&inr[a];
        *(float4*)&yi[wf * 64 + c4] = *(const float4*)&ini[a];
    }
    __syncthreads();
    const float S = 0.00785674201318386f;
    const short* hp = (const short*)h1;
    for (int t = tid; t < W_ * 16; t += 256) {
        int w = t >> 4, cg = (t & 15) << 2;
        float4 y0 = *(const float4*)&yr[cg];  // wf=0: real part only
        float a0 = y0.x, a1 = y0.y, a2 = y0.z, a3 = y0.w;
        for (int wf = 1; wf < WFK; ++wf) {
            float c2 = 2.f * fwc[wf * W_ + w], s2 = 2.f * fws[wf * W_ + w];
            float4 vr = *(const float4*)&yr[wf * 64 + cg];
            float4 vi = *(const float4*)&yi[wf * 64 + cg];
            a0 = fmaf(vr.x, c2, fmaf(-vi.x, s2, a0));
            a1 = fmaf(vr.y, c2, fmaf(-vi.y, s2, a1));
            a2 = fmaf(vr.z, c2, fmaf(-vi.z, s2, a2));
            a3 = fmaf(vr.w, c2, fmaf(-vi.w, s2, a3));
        }
        size_t o = ((size_t)slab * W_ + w) * C_ + c0 + cg;
        short4v hv = *(const short4v*)&hp[o];
        float4 xv = *(const float4*)&x[o];
        float4 r;
        r.x = fmaf(S, a0, bf2f(hv[0]) + xv.x);
        r.y = fmaf(S, a1, bf2f(hv[1]) + xv.y);
        r.z = fmaf(S, a2, bf2f(hv[2]) + xv.z);
        r.w = fmaf(S, a3, bf2f(hv[3]) + xv.w);
        *(float4*)&out[o] = r;
    }
}

// ---------------- transpose + f32->bf16 (weights) ----------------
__global__ __launch_bounds__(256) void transpose_cvt_kernel(const float* __restrict__ Wm,
        __hip_bfloat16* __restrict__ Wt, int R, int Ccol)
{
    __shared__ float tile[32][33];
    int c0 = blockIdx.x * 32, r0 = blockIdx.y * 32;
    int tid = threadIdx.x;
    int tc = tid & 31, tr = tid >> 5;
#pragma unroll
    for (int k = 0; k < 4; ++k)
        tile[tr + k * 8][tc] = Wm[(size_t)(r0 + tr + k * 8) * Ccol + c0 + tc];
    __syncthreads();
    int rr = tid & 31, cc = tid >> 5;
#pragma unroll
    for (int k = 0; k < 4; ++k)
        Wt[(size_t)(c0 + cc + k * 8) * R + r0 + rr] = __float2bfloat16(tile[rr][cc + k * 8]);
}

// ---------------- bf16 MFMA GEMM: C[M,N] = A[M,K] * Bt[N,K]^T ----------------
// EPI 0: out = bf16( gelu(acc + bias) ) -> obf      (all rows)
// EPI 1: out = f32 ( acc + bias + res )  -> of32    (rows < mvalid only)
template<int EPI>
__global__ __launch_bounds__(256) void gemm_kernel(
        const short* __restrict__ A, const short* __restrict__ Bt,
        const float* __restrict__ bias,
        __hip_bfloat16* __restrict__ obf, float* __restrict__ of32,
        const float* __restrict__ res, int N, int K, int mvalid)
{
    __shared__ short As[128 * 40];
    __shared__ short Bs[128 * 40];
    int tid = threadIdx.x;
    int wid = tid >> 6, lane = tid & 63;
    int wm = (wid >> 1) * 64, wn = (wid & 1) * 64;
    int lrow = lane & 15, lk8 = lane >> 4;
    f32x4 zero = {0.f, 0.f, 0.f, 0.f};
    f32x4 acc[4][4];
#pragma unroll
    for (int i = 0; i < 4; ++i)
#pragma unroll
        for (int j = 0; j < 4; ++j) acc[i][j] = zero;
    size_t m0 = (size_t)blockIdx.x * 128, n0 = (size_t)blockIdx.y * 128;
    int srow = tid >> 2;
    int scol = (tid & 3) * 8;
    const short* Ag = A + (m0 + srow) * K + scol;
    const short* Bg = Bt + (n0 + srow) * K + scol;
    for (int k0 = 0; k0 < K; k0 += 32) {
        int4 a0 = *(const int4*)(Ag + k0);
        int4 a1 = *(const int4*)(Ag + k0 + (size_t)64 * K);
        int4 b0 = *(const int4*)(Bg + k0);
        int4 b1 = *(const int4*)(Bg + k0 + (size_t)64 * K);
        __syncthreads();
        *(int4*)&As[srow * 40 + scol] = a0;
        *(int4*)&As[(srow + 64) * 40 + scol] = a1;
        *(int4*)&Bs[srow * 40 + scol] = b0;
        *(int4*)&Bs[(srow + 64) * 40 + scol] = b1;
        __syncthreads();
        short8 af[4], bfr[4];
#pragma unroll
        for (int mf = 0; mf < 4; ++mf) af[mf] = *(const short8*)&As[(wm + mf * 16 + lrow) * 40 + lk8 * 8];
#pragma unroll
        for (int nf = 0; nf < 4; ++nf) bfr[nf] = *(const short8*)&Bs[(wn + nf * 16 + lrow) * 40 + lk8 * 8];
#pragma unroll
        for (int mf = 0; mf < 4; ++mf)
#pragma unroll
            for (int nf = 0; nf < 4; ++nf)
                acc[mf][nf] = __builtin_amdgcn_mfma_f32_16x16x32_bf16(af[mf], bfr[nf], acc[mf][nf], 0, 0, 0);
    }
    int crow = (lane >> 4) * 4;
    int ccol = lane & 15;
#pragma unroll
    for (int mf = 0; mf < 4; ++mf) {
#pragma unroll
        for (int j = 0; j < 4; ++j) {
            size_t r = m0 + wm + mf * 16 + crow + j;
            if (EPI == 1 && r >= (size_t)mvalid) continue;
#pragma unroll
            for (int nf = 0; nf < 4; ++nf) {
                size_t cidx = n0 + wn + nf * 16 + ccol;
                float v = acc[mf][nf][j] + bias[cidx];
                if (EPI == 0) {
                    float g = 0.5f * v * (1.f + erff(v * 0.70710678118654752f));
                    obf[r * N + cidx] = __float2bfloat16(g);
                } else {
                    of32[r * N + cidx] = v + res[r * N + cidx];
                }
            }
        }
    }
}

extern "C" void kernel_launch(void* const* d_in, const int* in_sizes, int n_in,
                              void* d_out, int out_size, void* d_ws, size_t ws_size,
                              hipStream_t stream) {
    (void)in_sizes; (void)n_in; (void)out_size; (void)ws_size;
    const float* x    = (const float*)d_in[0];
    const float* n1w  = (const float*)d_in[1];
    const float* n1b  = (const float*)d_in[2];
    const float* w1   = (const float*)d_in[3];
    const float* b1   = (const float*)d_in[4];
    const float* w2   = (const float*)d_in[5];
    const float* b2   = (const float*)d_in[6];
    const float* n2w  = (const float*)d_in[7];
    const float* n2b  = (const float*)d_in[8];
    const float* fc1w = (const float*)d_in[9];
    const float* fc1b = (const float*)d_in[10];
    const float* fc2w = (const float*)d_in[11];
    const float* fc2b = (const float*)d_in[12];
    float* out = (float*)d_out;

    // ---- workspace layout (~111.6 MB total) with region aliasing ----
    float* wsf = (float*)d_ws;
    size_t off = 0;
    auto alloc = [&](size_t nfloats) { float* p = wsf + off; off += (nfloats + 63) & ~(size_t)63; return p; };
    // region1: h1 (bf16, NTOK*C) until iwfft; then h3 (bf16, MPAD*C)
    float* region1 = alloc((size_t)MPAD * C_ / 2);
    // region2: f1r,f1i (f32, NPOS*C each) until iwfft; then tb chunk (bf16, CHROWS*HID)
    float* region2 = alloc((size_t)2 * NPOS * C_);
    __hip_bfloat16* w1t = (__hip_bfloat16*)alloc((size_t)HID * C_ / 2);
    __hip_bfloat16* w2t = (__hip_bfloat16*)alloc((size_t)HID * C_ / 2);
    __hip_bfloat16* wbig = (__hip_bfloat16*)alloc((size_t)2 * NBK * 192 * 192 / 2);
    float* bbig = alloc(2 * NBK * 192);
    float* fwc  = alloc(WFK * W_);
    float* fws  = alloc(WFK * W_);
    float* hc   = alloc(H_ * H_);
    float* hs   = alloc(H_ * H_);

    __hip_bfloat16* h1b = (__hip_bfloat16*)region1;
    __hip_bfloat16* h3  = (__hip_bfloat16*)region1;
    float* f1r = region2;
    float* f1i = region2 + (size_t)NPOS * C_;
    __hip_bfloat16* tb  = (__hip_bfloat16*)region2;

    init_tables_kernel<<<33, 256, 0, stream>>>(fwc, fws, hc, hs);
    wprep_kernel<<<(2 * NBK * 192 * 192 + 255) / 256, 256, 0, stream>>>(w1, b1, w2, b2, wbig, bbig);
    transpose_cvt_kernel<<<dim3(HID / 32, C_ / 32), 256, 0, stream>>>(fc1w, w1t, C_, HID);
    transpose_cvt_kernel<<<dim3(C_ / 32, HID / 32), 256, 0, stream>>>(fc2w, w2t, HID, C_);

    ln_kernel<<<NTOK, 256, 0, stream>>>(x, n1w, n1b, h1b, NTOK);
    wfft_kernel<<<dim3(B_ * H_, 12), 256, 0, stream>>>(h1b, f1r, f1i, fwc, fws);
    hdft_kernel<<<dim3(B_ * WFK, 12), 256, 0, stream>>>(f1r, f1i, hc, hs, 1.f);
    blockmlp_mfma_kernel<<<dim3(130, NBK), 256, 0, stream>>>(f1r, f1i, wbig, bbig);
    hdft_kernel<<<dim3(B_ * WFK, 12), 256, 0, stream>>>(f1r, f1i, hc, hs, -1.f);
    iwfft_kernel<<<dim3(B_ * H_, 12), 256, 0, stream>>>(f1r, f1i, h1b, x, out, fwc, fws);
    // h1b, f1r/f1i dead from here; regions reused by h3 and tb
    ln_kernel<<<MPAD, 256, 0, stream>>>(out, n2w, n2b, h3, NTOK);
    for (int c = 0; c < 4; ++c) {
        int base = c * CHROWS;
        int tiles = (c < 3) ? (CHROWS / 128) : ((MPAD - 3 * CHROWS) / 128); // 64,64,64,62
        gemm_kernel<0><<<dim3(tiles, HID / 128), 256, 0, stream>>>(
            (const short*)(h3 + (size_t)base * C_), (const short*)w1t, fc1b,
            tb, nullptr, nullptr, HID, C_, 0);
        gemm_kernel<1><<<dim3(tiles, C_ / 128), 256, 0, stream>>>(
            (const short*)tb, (const short*)w2t, fc2b,
            nullptr, out + (size_t)base * C_, out + (size_t)base * C_, C_, HID, NTOK - base);
    }
}

// Round 4
// 1083.738 us; speedup vs baseline: 1.3136x; 1.0733x over previous
//
#include <hip/hip_runtime.h>
#include <hip/hip_bf16.h>

#define B_    2
#define H_    90
#define W_    180
#define C_    768
#define WFK   46          // kept W-frequency modes (of 91)
#define NBK   8
#define BSK   96
#define HID   3072
#define NTOK  (B_*H_*W_)  // 32400
#define MPAD  32512       // 254*128
#define NPOS  (B_*H_*WFK) // 8280
#define LAM   0.01f
#define CHROWS 8192       // gemm M-chunk rows (64 tiles of 128)

typedef __attribute__((ext_vector_type(8))) short short8;
typedef __attribute__((ext_vector_type(4))) float f32x4;

__device__ __forceinline__ float bf2f(short u) {
    union { unsigned int i; float f; } z;
    z.i = ((unsigned int)(unsigned short)u) << 16;
    return z.f;
}

__device__ __forceinline__ void gload_lds16(const void* g, void* l) {
    __builtin_amdgcn_global_load_lds((const __attribute__((address_space(1))) void*)g,
                                     (__attribute__((address_space(3))) void*)l, 16, 0, 0);
}

// ---------------- tables: W-fwd twiddles, H twiddles, and iwfft bf16 T-matrix ----------------
// Tw[w][k], w<192 (pad from 180), k<96 (pad from 92): k=2j -> S*(j==0?1:2cos), k=2j+1 -> (j==0?0:-2S*sin)
__global__ __launch_bounds__(256) void init_tables_kernel(float* fwc, float* fws, float* hc, float* hs,
                                                          __hip_bfloat16* Tw) {
    int i = blockIdx.x * 256 + threadIdx.x;
    if (i < WFK * W_) {
        int wf = i / W_, w = i % W_;
        int p = (w * wf) % W_;
        float th = (float)p * (float)(6.283185307179586476925286766559 / 180.0);
        fwc[i] = cosf(th); fws[i] = sinf(th);
    }
    if (i < H_ * H_) {
        int k = i / H_, h = i % H_;
        int p = (h * k) % H_;
        float th = (float)p * (float)(6.283185307179586476925286766559 / 90.0);
        hc[i] = cosf(th); hs[i] = sinf(th);
    }
    if (i < 192 * 96) {
        int w = i / 96, k = i % 96;
        int j = k >> 1, odd = k & 1;
        const float S = 0.00785674201318386f;
        float val = 0.f;
        if (w < W_ && j < WFK) {
            float th = (float)((w * j) % W_) * (float)(6.283185307179586476925286766559 / 180.0);
            if (odd) val = (j == 0) ? 0.f : -2.f * S * sinf(th);
            else     val = (j == 0) ? S : 2.f * S * cosf(th);
        }
        Tw[i] = __float2bfloat16(val);
    }
}

// ---------------- build expanded real weights for the block-MLP ----------------
__global__ __launch_bounds__(256) void wprep_kernel(
        const float* __restrict__ w1, const float* __restrict__ b1,
        const float* __restrict__ w2, const float* __restrict__ b2,
        __hip_bfloat16* __restrict__ wbig, float* __restrict__ bbig)
{
    int idx = blockIdx.x * 256 + threadIdx.x;
    if (idx < 2 * NBK * 192 * 192) {
        int k = idx % 192;
        int o = (idx / 192) % 192;
        int nb = (idx / (192 * 192)) % NBK;
        int L = idx / (192 * 192 * NBK);
        const float* w = L ? w2 : w1;
        const float* wr = w + (size_t)nb * BSK * BSK;
        const float* wi = w + (size_t)(NBK + nb) * BSK * BSK;
        int kk = k % BSK, oo = o % BSK;
        float val;
        if (o < BSK)  val = (k < BSK) ? wr[kk * BSK + oo] : -wi[kk * BSK + oo];
        else          val = (k < BSK) ? wi[kk * BSK + oo] :  wr[kk * BSK + oo];
        wbig[((size_t)(L * NBK + nb) * 192 + o) * 192 + k] = __float2bfloat16(val);
    }
    if (idx < 2 * NBK * 192) {
        int o = idx % 192;
        int nb = (idx / 192) % NBK;
        int L = idx / (192 * NBK);
        const float* b = L ? b2 : b1;
        bbig[idx] = (o < BSK) ? b[nb * BSK + o] : b[(NBK + nb) * BSK + (o - BSK)];
    }
}

// ---------------- LayerNorm: f32 in -> bf16 out, zero-pads rows >= ntok_valid ----------------
__global__ __launch_bounds__(256) void ln_kernel(const float* __restrict__ in,
        const float* __restrict__ w, const float* __restrict__ b,
        __hip_bfloat16* __restrict__ outb, int ntok_valid)
{
    int tok = blockIdx.x;
    int tid = threadIdx.x;
    size_t base = (size_t)tok * C_;
    if (tok >= ntok_valid) {
        __hip_bfloat16 z = __float2bfloat16(0.f);
        outb[base + tid] = z; outb[base + tid + 256] = z; outb[base + tid + 512] = z;
        return;
    }
    float x0 = in[base + tid], x1 = in[base + tid + 256], x2 = in[base + tid + 512];
    float s = x0 + x1 + x2;
    float q = x0*x0 + x1*x1 + x2*x2;
#pragma unroll
    for (int off = 32; off > 0; off >>= 1) { s += __shfl_down(s, off); q += __shfl_down(q, off); }
    __shared__ float rs[4], rq[4];
    int wid = tid >> 6, lane = tid & 63;
    if (lane == 0) { rs[wid] = s; rq[wid] = q; }
    __syncthreads();
    float ts = rs[0] + rs[1] + rs[2] + rs[3];
    float tq = rq[0] + rq[1] + rq[2] + rq[3];
    float mu = ts * (1.f / C_);
    float var = tq * (1.f / C_) - mu * mu;
    float rstd = rsqrtf(var + 1e-5f);
#pragma unroll
    for (int k = 0; k < 3; ++k) {
        int c = tid + k * 256;
        float xv = (k == 0 ? x0 : (k == 1 ? x1 : x2));
        outb[base + c] = __float2bfloat16((xv - mu) * rstd * w[c] + b[c]);
    }
}

// ---------------- forward rfft along W (only wf<46), scaled by 1/sqrt(16200) ----------------
__global__ __launch_bounds__(256) void wfft_kernel(const __hip_bfloat16* __restrict__ h1,
        float* __restrict__ f1r, float* __restrict__ f1i,
        const float* __restrict__ fwc, const float* __restrict__ fws)
{
    __shared__ float xs[W_ * 64];
    int slab = blockIdx.x;           // b*90+h
    int c0 = blockIdx.y * 64;
    int tid = threadIdx.x;
    const short* src = (const short*)h1 + (size_t)slab * W_ * C_ + c0;
    for (int i = tid; i < W_ * 8; i += 256) {
        int w = i >> 3, c8 = (i & 7) * 8;
        short8 v = *(const short8*)&src[(size_t)w * C_ + c8];
        float* dst = &xs[w * 64 + c8];
#pragma unroll
        for (int j = 0; j < 8; ++j) dst[j] = bf2f(v[j]);
    }
    __syncthreads();
    const float S = 0.00785674201318386f; // 1/sqrt(90*180)
    for (int t = tid; t < WFK * 16; t += 256) {
        int wf = t >> 4, cg = (t & 15) << 2;
        const float* cw = fwc + wf * W_;
        const float* sw = fws + wf * W_;
        float ar0 = 0, ar1 = 0, ar2 = 0, ar3 = 0, ai0 = 0, ai1 = 0, ai2 = 0, ai3 = 0;
        for (int w = 0; w < W_; ++w) {
            float c = cw[w], sn = sw[w];
            float4 x = *(const float4*)&xs[w * 64 + cg];
            ar0 = fmaf(x.x, c, ar0); ai0 = fmaf(-x.x, sn, ai0);
            ar1 = fmaf(x.y, c, ar1); ai1 = fmaf(-x.y, sn, ai1);
            ar2 = fmaf(x.z, c, ar2); ai2 = fmaf(-x.z, sn, ai2);
            ar3 = fmaf(x.w, c, ar3); ai3 = fmaf(-x.w, sn, ai3);
        }
        size_t o = ((size_t)slab * WFK + wf) * C_ + c0 + cg;
        *(float4*)&f1r[o] = make_float4(S*ar0, S*ar1, S*ar2, S*ar3);
        *(float4*)&f1i[o] = make_float4(S*ai0, S*ai1, S*ai2, S*ai3);
    }
}

// ---------------- complex DFT along H (90-pt), IN-PLACE; sg=+1 fwd e^{-i}, sg=-1 inv e^{+i} ----------------
__global__ __launch_bounds__(256) void hdft_kernel(float* __restrict__ dr, float* __restrict__ di,
        const float* __restrict__ hc, const float* __restrict__ hs, float sg)
{
    __shared__ float xr[H_ * 64], xi[H_ * 64];
    int bwf = blockIdx.x;            // b*46+wf
    int b = bwf / WFK, wf = bwf % WFK;
    int c0 = blockIdx.y * 64;
    int tid = threadIdx.x;
    size_t base = ((size_t)(b * H_) * WFK + wf) * C_ + c0;
    for (int i = tid; i < H_ * 16; i += 256) {
        int h = i >> 4, c4 = (i & 15) << 2;
        size_t a = base + (size_t)h * WFK * C_ + c4;
        *(float4*)&xr[h * 64 + c4] = *(const float4*)&dr[a];
        *(float4*)&xi[h * 64 + c4] = *(const float4*)&di[a];
    }
    __syncthreads();
    for (int t = tid; t < H_ * 16; t += 256) {
        int k = t >> 4, cg = (t & 15) << 2;
        const float* cc = hc + k * H_;
        const float* ss = hs + k * H_;
        float or0=0,or1=0,or2=0,or3=0, oi0=0,oi1=0,oi2=0,oi3=0;
        for (int h = 0; h < H_; ++h) {
            float c = cc[h], s = sg * ss[h];
            float4 vr = *(const float4*)&xr[h * 64 + cg];
            float4 vi = *(const float4*)&xi[h * 64 + cg];
            or0 = fmaf(vr.x, c, fmaf(vi.x, s, or0)); oi0 = fmaf(vi.x, c, fmaf(-vr.x, s, oi0));
            or1 = fmaf(vr.y, c, fmaf(vi.y, s, or1)); oi1 = fmaf(vi.y, c, fmaf(-vr.y, s, oi1));
            or2 = fmaf(vr.z, c, fmaf(vi.z, s, or2)); oi2 = fmaf(vi.z, c, fmaf(-vr.z, s, oi2));
            or3 = fmaf(vr.w, c, fmaf(vi.w, s, or3)); oi3 = fmaf(vi.w, c, fmaf(-vr.w, s, oi3));
        }
        size_t o = base + (size_t)k * WFK * C_ + cg;
        *(float4*)&dr[o] = make_float4(or0, or1, or2, or3);
        *(float4*)&di[o] = make_float4(oi0, oi1, oi2, oi3);
    }
}

// ---------------- block-diagonal complex 2-layer MLP + softshrink, IN-PLACE, via MFMA ----------------
__global__ __launch_bounds__(256) void blockmlp_mfma_kernel(
        float* __restrict__ vr, float* __restrict__ vi,
        const __hip_bfloat16* __restrict__ wbig, const float* __restrict__ bbig)
{
    __shared__ __hip_bfloat16 X1[64 * 200];
    __shared__ __hip_bfloat16 X2[64 * 200];
    int chunk = blockIdx.x;          // 130 chunks of 64 positions
    int nb = blockIdx.y;
    int tid = threadIdx.x, wid = tid >> 6, lane = tid & 63;
    int p0 = chunk * 64;
    for (int i = tid; i < 64 * 48; i += 256) {
        int p = i / 48, q = i % 48;
        int pg = p0 + p;
        int c4 = (q % 24) * 4;
        bool isr = q < 24;
        float4 v = make_float4(0, 0, 0, 0);
        if (pg < NPOS) {
            const float* src = isr ? vr : vi;
            v = *(const float4*)&src[(size_t)pg * C_ + nb * BSK + c4];
        }
        __hip_bfloat16* d = &X1[p * 200 + (isr ? 0 : 96) + c4];
        d[0] = __float2bfloat16(v.x); d[1] = __float2bfloat16(v.y);
        d[2] = __float2bfloat16(v.z); d[3] = __float2bfloat16(v.w);
    }
    __syncthreads();
    int n0 = wid * 48;
    int lrow = lane & 15, lk8 = lane >> 4;
    int crow = (lane >> 4) * 4, ccol = lane & 15;
    const short* W1 = (const short*)(wbig + (size_t)nb * 192 * 192);
    const short* W2 = (const short*)(wbig + (size_t)(NBK + nb) * 192 * 192);
    const float* bb1 = bbig + nb * 192;
    const float* bb2 = bbig + (NBK + nb) * 192;
    f32x4 zero = {0.f, 0.f, 0.f, 0.f};
    {
        f32x4 acc[4][3];
#pragma unroll
        for (int m = 0; m < 4; ++m)
#pragma unroll
            for (int n = 0; n < 3; ++n) acc[m][n] = zero;
#pragma unroll
        for (int k0 = 0; k0 < 192; k0 += 32) {
            short8 af[4], bf[3];
#pragma unroll
            for (int m = 0; m < 4; ++m)
                af[m] = *(const short8*)&X1[(m * 16 + lrow) * 200 + k0 + lk8 * 8];
#pragma unroll
            for (int n = 0; n < 3; ++n)
                bf[n] = *(const short8*)&W1[(size_t)(n0 + n * 16 + lrow) * 192 + k0 + lk8 * 8];
#pragma unroll
            for (int m = 0; m < 4; ++m)
#pragma unroll
                for (int n = 0; n < 3; ++n)
                    acc[m][n] = __builtin_amdgcn_mfma_f32_16x16x32_bf16(af[m], bf[n], acc[m][n], 0, 0, 0);
        }
        __syncthreads();
#pragma unroll
        for (int m = 0; m < 4; ++m)
#pragma unroll
            for (int j = 0; j < 4; ++j) {
                int row = m * 16 + crow + j;
#pragma unroll
                for (int n = 0; n < 3; ++n) {
                    int col = n0 + n * 16 + ccol;
                    float v = acc[m][n][j] + bb1[col];
                    X2[row * 200 + col] = __float2bfloat16(fmaxf(v, 0.f));
                }
            }
    }
    __syncthreads();
    {
        f32x4 acc[4][3];
#pragma unroll
        for (int m = 0; m < 4; ++m)
#pragma unroll
            for (int n = 0; n < 3; ++n) acc[m][n] = zero;
#pragma unroll
        for (int k0 = 0; k0 < 192; k0 += 32) {
            short8 af[4], bf[3];
#pragma unroll
            for (int m = 0; m < 4; ++m)
                af[m] = *(const short8*)&X2[(m * 16 + lrow) * 200 + k0 + lk8 * 8];
#pragma unroll
            for (int n = 0; n < 3; ++n)
                bf[n] = *(const short8*)&W2[(size_t)(n0 + n * 16 + lrow) * 192 + k0 + lk8 * 8];
#pragma unroll
            for (int m = 0; m < 4; ++m)
#pragma unroll
                for (int n = 0; n < 3; ++n)
                    acc[m][n] = __builtin_amdgcn_mfma_f32_16x16x32_bf16(af[m], bf[n], acc[m][n], 0, 0, 0);
        }
#pragma unroll
        for (int m = 0; m < 4; ++m)
#pragma unroll
            for (int j = 0; j < 4; ++j) {
                int row = m * 16 + crow + j;
                int pg = p0 + row;
                if (pg >= NPOS) continue;
#pragma unroll
                for (int n = 0; n < 3; ++n) {
                    int col = n0 + n * 16 + ccol;
                    float v = acc[m][n][j] + bb2[col];
                    v = v > LAM ? v - LAM : (v < -LAM ? v + LAM : 0.f);
                    if (col < BSK) vr[(size_t)pg * C_ + nb * BSK + col] = v;
                    else           vi[(size_t)pg * C_ + nb * BSK + col - BSK] = v;
                }
            }
    }
}

// ---------------- inverse rfft along W via MFMA: OUT[180][64] = T[192][96] @ Yt^T, + residuals ----------------
__global__ __launch_bounds__(256) void iwfft_kernel(
        const float* __restrict__ inr, const float* __restrict__ ini,
        const __hip_bfloat16* __restrict__ h1, const float* __restrict__ x,
        float* __restrict__ out, const __hip_bfloat16* __restrict__ Tw)
{
    __shared__ __hip_bfloat16 Yt[64 * 104];   // [channel][k], k: 2j=re,2j+1=im, pad 92..95
    int slab = blockIdx.x;        // 180
    int c0 = blockIdx.y * 64;     // 12 groups
    int tid = threadIdx.x, wid = tid >> 6, lane = tid & 63;
    int lrow = lane & 15, lk8 = lane >> 4;
    size_t sb = (size_t)slab * WFK * C_ + c0;
    for (int i = tid; i < WFK * 16; i += 256) {
        int wf = i >> 4, cq = (i & 15) * 4;
        size_t a = sb + (size_t)wf * C_ + cq;
        float4 vrv = *(const float4*)&inr[a];
        float4 viv = *(const float4*)&ini[a];
        Yt[(cq + 0) * 104 + 2 * wf]     = __float2bfloat16(vrv.x);
        Yt[(cq + 0) * 104 + 2 * wf + 1] = __float2bfloat16(viv.x);
        Yt[(cq + 1) * 104 + 2 * wf]     = __float2bfloat16(vrv.y);
        Yt[(cq + 1) * 104 + 2 * wf + 1] = __float2bfloat16(viv.y);
        Yt[(cq + 2) * 104 + 2 * wf]     = __float2bfloat16(vrv.z);
        Yt[(cq + 2) * 104 + 2 * wf + 1] = __float2bfloat16(viv.z);
        Yt[(cq + 3) * 104 + 2 * wf]     = __float2bfloat16(vrv.w);
        Yt[(cq + 3) * 104 + 2 * wf + 1] = __float2bfloat16(viv.w);
    }
    {   // zero K-pad 92..95 for all 64 channels (256 threads exactly)
        int c = tid >> 2, kk = 92 + (tid & 3);
        Yt[c * 104 + kk] = __float2bfloat16(0.f);
    }
    __syncthreads();
    const short* Tp = (const short*)Tw;
    f32x4 zero = {0.f, 0.f, 0.f, 0.f};
    f32x4 acc[3][4];
#pragma unroll
    for (int m = 0; m < 3; ++m)
#pragma unroll
        for (int n = 0; n < 4; ++n) acc[m][n] = zero;
#pragma unroll
    for (int ks = 0; ks < 3; ++ks) {
        short8 af[3], bf[4];
#pragma unroll
        for (int m = 0; m < 3; ++m)
            af[m] = *(const short8*)&Tp[(wid * 48 + m * 16 + lrow) * 96 + ks * 32 + lk8 * 8];
#pragma unroll
        for (int n = 0; n < 4; ++n)
            bf[n] = *(const short8*)&Yt[(n * 16 + lrow) * 104 + ks * 32 + lk8 * 8];
#pragma unroll
        for (int m = 0; m < 3; ++m)
#pragma unroll
            for (int n = 0; n < 4; ++n)
                acc[m][n] = __builtin_amdgcn_mfma_f32_16x16x32_bf16(af[m], bf[n], acc[m][n], 0, 0, 0);
    }
    int crow = (lane >> 4) * 4, ccol = lane & 15;
    const short* hp = (const short*)h1;
#pragma unroll
    for (int m = 0; m < 3; ++m)
#pragma unroll
        for (int j = 0; j < 4; ++j) {
            int w = wid * 48 + m * 16 + crow + j;
            if (w >= W_) continue;
            size_t o = ((size_t)slab * W_ + w) * C_ + c0;
#pragma unroll
            for (int n = 0; n < 4; ++n) {
                int col = n * 16 + ccol;
                out[o + col] = acc[m][n][j] + bf2f(hp[o + col]) + x[o + col];
            }
        }
}

// ---------------- transpose + f32->bf16 (weights) ----------------
__global__ __launch_bounds__(256) void transpose_cvt_kernel(const float* __restrict__ Wm,
        __hip_bfloat16* __restrict__ Wt, int R, int Ccol)
{
    __shared__ float tile[32][33];
    int c0 = blockIdx.x * 32, r0 = blockIdx.y * 32;
    int tid = threadIdx.x;
    int tc = tid & 31, tr = tid >> 5;
#pragma unroll
    for (int k = 0; k < 4; ++k)
        tile[tr + k * 8][tc] = Wm[(size_t)(r0 + tr + k * 8) * Ccol + c0 + tc];
    __syncthreads();
    int rr = tid & 31, cc = tid >> 5;
#pragma unroll
    for (int k = 0; k < 4; ++k)
        Wt[(size_t)(c0 + cc + k * 8) * R + r0 + rr] = __float2bfloat16(tile[rr][cc + k * 8]);
}

// ---------------- bf16 MFMA GEMM (m97 structure): C[M,N] = A[M,K] * Bt[N,K]^T ----------------
// global_load_lds width-16 staging into linear [128][32] LDS, 2-barrier K-loop.
// EPI 0: out = bf16( gelu(acc + bias) ) -> obf      (all rows)
// EPI 1: out = f32 ( acc + bias + res )  -> of32    (rows < mvalid only)
template<int EPI>
__global__ __launch_bounds__(256) void gemm_kernel(
        const short* __restrict__ A, const short* __restrict__ Bt,
        const float* __restrict__ bias,
        __hip_bfloat16* __restrict__ obf, float* __restrict__ of32,
        const float* __restrict__ res, int N, int K, int mvalid)
{
    __shared__ short As[128 * 32];
    __shared__ short Bs[128 * 32];
    int tid = threadIdx.x;
    int wid = tid >> 6, lane = tid & 63;
    int wm = (wid >> 1) * 64, wn = (wid & 1) * 64;
    int lrow = lane & 15, lk8 = lane >> 4;
    f32x4 zero = {0.f, 0.f, 0.f, 0.f};
    f32x4 acc[4][4];
#pragma unroll
    for (int i = 0; i < 4; ++i)
#pragma unroll
        for (int j = 0; j < 4; ++j) acc[i][j] = zero;
    size_t m0 = (size_t)blockIdx.x * 128, n0 = (size_t)blockIdx.y * 128;
    int srow = tid >> 2;            // 0..63
    int scol = (tid & 3) * 8;       // k-octet
    const short* Ag = A + (m0 + srow) * K + scol;
    const short* Bg = Bt + (n0 + srow) * K + scol;
    char* Asb = (char*)As + (size_t)tid * 16;
    char* Bsb = (char*)Bs + (size_t)tid * 16;
    for (int k0 = 0; k0 < K; k0 += 32) {
        __syncthreads();            // prior reads done before overwrite
        gload_lds16(Ag + k0, Asb);
        gload_lds16(Ag + k0 + (size_t)64 * K, Asb + 4096);
        gload_lds16(Bg + k0, Bsb);
        gload_lds16(Bg + k0 + (size_t)64 * K, Bsb + 4096);
        __syncthreads();            // implicit vmcnt(0) drain
        short8 af[4], bfr[4];
#pragma unroll
        for (int mf = 0; mf < 4; ++mf) af[mf] = *(const short8*)&As[(wm + mf * 16 + lrow) * 32 + lk8 * 8];
#pragma unroll
        for (int nf = 0; nf < 4; ++nf) bfr[nf] = *(const short8*)&Bs[(wn + nf * 16 + lrow) * 32 + lk8 * 8];
#pragma unroll
        for (int mf = 0; mf < 4; ++mf)
#pragma unroll
            for (int nf = 0; nf < 4; ++nf)
                acc[mf][nf] = __builtin_amdgcn_mfma_f32_16x16x32_bf16(af[mf], bfr[nf], acc[mf][nf], 0, 0, 0);
    }
    int crow = (lane >> 4) * 4;
    int ccol = lane & 15;
#pragma unroll
    for (int mf = 0; mf < 4; ++mf) {
#pragma unroll
        for (int j = 0; j < 4; ++j) {
            size_t r = m0 + wm + mf * 16 + crow + j;
            if (EPI == 1 && r >= (size_t)mvalid) continue;
#pragma unroll
            for (int nf = 0; nf < 4; ++nf) {
                size_t cidx = n0 + wn + nf * 16 + ccol;
                float v = acc[mf][nf][j] + bias[cidx];
                if (EPI == 0) {
                    float g = 0.5f * v * (1.f + erff(v * 0.70710678118654752f));
                    obf[r * N + cidx] = __float2bfloat16(g);
                } else {
                    of32[r * N + cidx] = v + res[r * N + cidx];
                }
            }
        }
    }
}

extern "C" void kernel_launch(void* const* d_in, const int* in_sizes, int n_in,
                              void* d_out, int out_size, void* d_ws, size_t ws_size,
                              hipStream_t stream) {
    (void)in_sizes; (void)n_in; (void)out_size; (void)ws_size;
    const float* x    = (const float*)d_in[0];
    const float* n1w  = (const float*)d_in[1];
    const float* n1b  = (const float*)d_in[2];
    const float* w1   = (const float*)d_in[3];
    const float* b1   = (const float*)d_in[4];
    const float* w2   = (const float*)d_in[5];
    const float* b2   = (const float*)d_in[6];
    const float* n2w  = (const float*)d_in[7];
    const float* n2b  = (const float*)d_in[8];
    const float* fc1w = (const float*)d_in[9];
    const float* fc1b = (const float*)d_in[10];
    const float* fc2w = (const float*)d_in[11];
    const float* fc2b = (const float*)d_in[12];
    float* out = (float*)d_out;

    // ---- workspace layout (~112 MB) with region aliasing ----
    float* wsf = (float*)d_ws;
    size_t off = 0;
    auto alloc = [&](size_t nfloats) { float* p = wsf + off; off += (nfloats + 63) & ~(size_t)63; return p; };
    float* region1 = alloc((size_t)MPAD * C_ / 2);          // h1 (bf16) then h3 (bf16)
    float* region2 = alloc((size_t)2 * NPOS * C_);          // f1r,f1i (f32) then tb (bf16 chunk)
    __hip_bfloat16* w1t = (__hip_bfloat16*)alloc((size_t)HID * C_ / 2);
    __hip_bfloat16* w2t = (__hip_bfloat16*)alloc((size_t)HID * C_ / 2);
    __hip_bfloat16* wbig = (__hip_bfloat16*)alloc((size_t)2 * NBK * 192 * 192 / 2);
    float* bbig = alloc(2 * NBK * 192);
    __hip_bfloat16* Tw = (__hip_bfloat16*)alloc(192 * 96 / 2);
    float* fwc  = alloc(WFK * W_);
    float* fws  = alloc(WFK * W_);
    float* hc   = alloc(H_ * H_);
    float* hs   = alloc(H_ * H_);

    __hip_bfloat16* h1b = (__hip_bfloat16*)region1;
    __hip_bfloat16* h3  = (__hip_bfloat16*)region1;
    float* f1r = region2;
    float* f1i = region2 + (size_t)NPOS * C_;
    __hip_bfloat16* tb  = (__hip_bfloat16*)region2;

    init_tables_kernel<<<72, 256, 0, stream>>>(fwc, fws, hc, hs, Tw);
    wprep_kernel<<<(2 * NBK * 192 * 192 + 255) / 256, 256, 0, stream>>>(w1, b1, w2, b2, wbig, bbig);
    transpose_cvt_kernel<<<dim3(HID / 32, C_ / 32), 256, 0, stream>>>(fc1w, w1t, C_, HID);
    transpose_cvt_kernel<<<dim3(C_ / 32, HID / 32), 256, 0, stream>>>(fc2w, w2t, HID, C_);

    ln_kernel<<<NTOK, 256, 0, stream>>>(x, n1w, n1b, h1b, NTOK);
    wfft_kernel<<<dim3(B_ * H_, 12), 256, 0, stream>>>(h1b, f1r, f1i, fwc, fws);
    hdft_kernel<<<dim3(B_ * WFK, 12), 256, 0, stream>>>(f1r, f1i, hc, hs, 1.f);
    blockmlp_mfma_kernel<<<dim3(130, NBK), 256, 0, stream>>>(f1r, f1i, wbig, bbig);
    hdft_kernel<<<dim3(B_ * WFK, 12), 256, 0, stream>>>(f1r, f1i, hc, hs, -1.f);
    iwfft_kernel<<<dim3(B_ * H_, 12), 256, 0, stream>>>(f1r, f1i, h1b, x, out, Tw);
    // h1b, f1r/f1i dead from here; regions reused by h3 and tb
    ln_kernel<<<MPAD, 256, 0, stream>>>(out, n2w, n2b, h3, NTOK);
    for (int c = 0; c < 4; ++c) {
        int base = c * CHROWS;
        int tiles = (c < 3) ? (CHROWS / 128) : ((MPAD - 3 * CHROWS) / 128); // 64,64,64,62
        gemm_kernel<0><<<dim3(tiles, HID / 128), 256, 0, stream>>>(
            (const short*)(h3 + (size_t)base * C_), (const short*)w1t, fc1b,
            tb, nullptr, nullptr, HID, C_, 0);
        gemm_kernel<1><<<dim3(tiles, C_ / 128), 256, 0, stream>>>(
            (const short*)tb, (const short*)w2t, fc2b,
            nullptr, out + (size_t)base * C_, out + (size_t)base * C_, C_, HID, NTOK - base);
    }
}

// Round 5
// 922.717 us; speedup vs baseline: 1.5429x; 1.1745x over previous
//
#include <hip/hip_runtime.h>
#include <hip/hip_bf16.h>

#define B_    2
#define H_    90
#define W_    180
#define C_    768
#define WFK   46          // kept W-frequency modes (of 91)
#define NBK   8
#define BSK   96
#define HID   3072
#define NTOK  (B_*H_*W_)  // 32400
#define MPAD  32512       // 254*128
#define NPOS  (B_*H_*WFK) // 8280
#define LAM   0.01f
#define CHROWS 8192       // gemm M-chunk rows (64 tiles of 128)

typedef __attribute__((ext_vector_type(8))) short short8;
typedef __attribute__((ext_vector_type(4))) float f32x4;

__device__ __forceinline__ float bf2f(short u) {
    union { unsigned int i; float f; } z;
    z.i = ((unsigned int)(unsigned short)u) << 16;
    return z.f;
}

__device__ __forceinline__ void gload_lds16(const void* g, void* l) {
    __builtin_amdgcn_global_load_lds((const __attribute__((address_space(1))) void*)g,
                                     (__attribute__((address_space(3))) void*)l, 16, 0, 0);
}

// ---------------- bf16 twiddle tables for all MFMA DFT stages ----------------
// Tw  [192 w][96 k]   : iwfft  (k=2j re, 2j+1 im; S & Hermitian 2x folded)
// Twf [96 r][192 w]   : wfft   (r=2wf -> S*cos, 2wf+1 -> -S*sin)
// Thf/Thi [192 r][192 j]: hdft fwd/inv (interleaved re/im both sides)
__global__ __launch_bounds__(256) void init_tables_kernel(__hip_bfloat16* Tw, __hip_bfloat16* Twf,
                                                          __hip_bfloat16* Thf, __hip_bfloat16* Thi) {
    int i = blockIdx.x * 256 + threadIdx.x;
    const float S = 0.00785674201318386f; // 1/sqrt(90*180)
    if (i < 192 * 96) {
        int w = i / 96, k = i % 96;
        int j = k >> 1, odd = k & 1;
        float val = 0.f;
        if (w < W_ && j < WFK) {
            float th = (float)((w * j) % W_) * (float)(6.283185307179586476925286766559 / 180.0);
            if (odd) val = (j == 0) ? 0.f : -2.f * S * sinf(th);
            else     val = (j == 0) ? S : 2.f * S * cosf(th);
        }
        Tw[i] = __float2bfloat16(val);
    }
    if (i < 96 * 192) {
        int r = i / 192, w = i % 192;
        int wf = r >> 1, odd = r & 1;
        float val = 0.f;
        if (w < W_ && wf < WFK) {
            float th = (float)((w * wf) % W_) * (float)(6.283185307179586476925286766559 / 180.0);
            val = odd ? -S * sinf(th) : S * cosf(th);
        }
        Twf[i] = __float2bfloat16(val);
    }
    if (i < 192 * 192) {
        int r = i / 192, j = i % 192;
        float vf = 0.f, vi = 0.f;
        if (r < 180 && j < 180) {
            int k = r >> 1, ro = r & 1, h = j >> 1, jo = j & 1;
            float th = (float)((k * h) % H_) * (float)(6.283185307179586476925286766559 / 90.0);
            float c = cosf(th), s = sinf(th);
            // fwd (sg=+1): re' = re*c + im*s ; im' = im*c - re*s
            vf = ro ? (jo ? c : -s) : (jo ? s : c);
            // inv (sg=-1): re' = re*c - im*s ; im' = im*c + re*s
            vi = ro ? (jo ? c : s) : (jo ? -s : c);
        }
        Thf[i] = __float2bfloat16(vf);
        Thi[i] = __float2bfloat16(vi);
    }
}

// ---------------- build expanded real weights for the block-MLP ----------------
__global__ __launch_bounds__(256) void wprep_kernel(
        const float* __restrict__ w1, const float* __restrict__ b1,
        const float* __restrict__ w2, const float* __restrict__ b2,
        __hip_bfloat16* __restrict__ wbig, float* __restrict__ bbig)
{
    int idx = blockIdx.x * 256 + threadIdx.x;
    if (idx < 2 * NBK * 192 * 192) {
        int k = idx % 192;
        int o = (idx / 192) % 192;
        int nb = (idx / (192 * 192)) % NBK;
        int L = idx / (192 * 192 * NBK);
        const float* w = L ? w2 : w1;
        const float* wr = w + (size_t)nb * BSK * BSK;
        const float* wi = w + (size_t)(NBK + nb) * BSK * BSK;
        int kk = k % BSK, oo = o % BSK;
        float val;
        if (o < BSK)  val = (k < BSK) ? wr[kk * BSK + oo] : -wi[kk * BSK + oo];
        else          val = (k < BSK) ? wi[kk * BSK + oo] :  wr[kk * BSK + oo];
        wbig[((size_t)(L * NBK + nb) * 192 + o) * 192 + k] = __float2bfloat16(val);
    }
    if (idx < 2 * NBK * 192) {
        int o = idx % 192;
        int nb = (idx / 192) % NBK;
        int L = idx / (192 * NBK);
        const float* b = L ? b2 : b1;
        bbig[idx] = (o < BSK) ? b[nb * BSK + o] : b[(NBK + nb) * BSK + (o - BSK)];
    }
}

// ---------------- LayerNorm: f32 in -> bf16 out, zero-pads rows >= ntok_valid ----------------
__global__ __launch_bounds__(256) void ln_kernel(const float* __restrict__ in,
        const float* __restrict__ w, const float* __restrict__ b,
        __hip_bfloat16* __restrict__ outb, int ntok_valid)
{
    int tok = blockIdx.x;
    int tid = threadIdx.x;
    size_t base = (size_t)tok * C_;
    if (tok >= ntok_valid) {
        __hip_bfloat16 z = __float2bfloat16(0.f);
        outb[base + tid] = z; outb[base + tid + 256] = z; outb[base + tid + 512] = z;
        return;
    }
    float x0 = in[base + tid], x1 = in[base + tid + 256], x2 = in[base + tid + 512];
    float s = x0 + x1 + x2;
    float q = x0*x0 + x1*x1 + x2*x2;
#pragma unroll
    for (int off = 32; off > 0; off >>= 1) { s += __shfl_down(s, off); q += __shfl_down(q, off); }
    __shared__ float rs[4], rq[4];
    int wid = tid >> 6, lane = tid & 63;
    if (lane == 0) { rs[wid] = s; rq[wid] = q; }
    __syncthreads();
    float ts = rs[0] + rs[1] + rs[2] + rs[3];
    float tq = rq[0] + rq[1] + rq[2] + rq[3];
    float mu = ts * (1.f / C_);
    float var = tq * (1.f / C_) - mu * mu;
    float rstd = rsqrtf(var + 1e-5f);
#pragma unroll
    for (int k = 0; k < 3; ++k) {
        int c = tid + k * 256;
        float xv = (k == 0 ? x0 : (k == 1 ? x1 : x2));
        outb[base + c] = __float2bfloat16((xv - mu) * rstd * w[c] + b[c]);
    }
}

// ---------------- forward rfft along W via MFMA: OUT[96][64] = Twf @ Xt^T ----------------
__global__ __launch_bounds__(256) void wfft_kernel(const __hip_bfloat16* __restrict__ h1,
        float* __restrict__ f1r, float* __restrict__ f1i,
        const __hip_bfloat16* __restrict__ Twf)
{
    __shared__ __hip_bfloat16 Xt[64 * 200];  // [c][w], w pad 180..191 = 0
    int slab = blockIdx.x;           // b*90+h
    int c0 = blockIdx.y * 64;
    int tid = threadIdx.x, wid = tid >> 6, lane = tid & 63;
    int lrow = lane & 15, lk8 = lane >> 4;
    const short* src = (const short*)h1 + (size_t)slab * W_ * C_ + c0;
    short* X = (short*)Xt;
    for (int i = tid; i < W_ * 8; i += 256) {
        int w = i >> 3, c8 = (i & 7) * 8;
        short8 v = *(const short8*)&src[(size_t)w * C_ + c8];
#pragma unroll
        for (int j = 0; j < 8; ++j) X[(c8 + j) * 200 + w] = v[j];
    }
    for (int z = tid; z < 64 * 12; z += 256) {
        int c = z / 12, w = 180 + z % 12;
        Xt[c * 200 + w] = __float2bfloat16(0.f);
    }
    __syncthreads();
    const short* Tp = (const short*)Twf;
    f32x4 zero = {0.f, 0.f, 0.f, 0.f};
    f32x4 acc[6];
#pragma unroll
    for (int m = 0; m < 6; ++m) acc[m] = zero;
#pragma unroll
    for (int ks = 0; ks < 6; ++ks) {
        short8 bf = *(const short8*)&X[(wid * 16 + lrow) * 200 + ks * 32 + lk8 * 8];
#pragma unroll
        for (int m = 0; m < 6; ++m) {
            short8 af = *(const short8*)&Tp[(m * 16 + lrow) * 192 + ks * 32 + lk8 * 8];
            acc[m] = __builtin_amdgcn_mfma_f32_16x16x32_bf16(af, bf, acc[m], 0, 0, 0);
        }
    }
    int crow = (lane >> 4) * 4, ccol = lane & 15;
#pragma unroll
    for (int m = 0; m < 6; ++m)
#pragma unroll
        for (int j = 0; j < 4; ++j) {
            int r = m * 16 + crow + j;
            int wf = r >> 1;
            if (wf >= WFK) continue;
            size_t o = ((size_t)slab * WFK + wf) * C_ + c0 + wid * 16 + ccol;
            if (r & 1) f1i[o] = acc[m][j];
            else       f1r[o] = acc[m][j];
        }
}

// ---------------- complex DFT along H via MFMA, IN-PLACE: OUT[192][64] = Th @ Xt^T ----------------
__global__ __launch_bounds__(256) void hdft_kernel(float* __restrict__ dr, float* __restrict__ di,
        const __hip_bfloat16* __restrict__ Th)
{
    __shared__ __hip_bfloat16 Xt[64 * 200];  // [c][j], j=2h re / 2h+1 im, pad 180..191 = 0
    int bwf = blockIdx.x;            // b*46+wf
    int b = bwf / WFK, wf = bwf % WFK;
    int c0 = blockIdx.y * 64;
    int tid = threadIdx.x, wid = tid >> 6, lane = tid & 63;
    int lrow = lane & 15, lk8 = lane >> 4;
    size_t base = ((size_t)(b * H_) * WFK + wf) * C_ + c0;
    short* X = (short*)Xt;
    for (int i = tid; i < H_ * 16; i += 256) {
        int h = i >> 4, cq = (i & 15) * 4;
        size_t a = base + (size_t)h * WFK * C_ + cq;
        float4 re = *(const float4*)&dr[a];
        float4 im = *(const float4*)&di[a];
        X[(cq + 0) * 200 + 2 * h] = ((short*)&re)[0 * 2 + 1] & 0 ? 0 : (short)(__bfloat16_as_ushort(__float2bfloat16(re.x)));
        X[(cq + 0) * 200 + 2 * h]     = (short)__bfloat16_as_ushort(__float2bfloat16(re.x));
        X[(cq + 0) * 200 + 2 * h + 1] = (short)__bfloat16_as_ushort(__float2bfloat16(im.x));
        X[(cq + 1) * 200 + 2 * h]     = (short)__bfloat16_as_ushort(__float2bfloat16(re.y));
        X[(cq + 1) * 200 + 2 * h + 1] = (short)__bfloat16_as_ushort(__float2bfloat16(im.y));
        X[(cq + 2) * 200 + 2 * h]     = (short)__bfloat16_as_ushort(__float2bfloat16(re.z));
        X[(cq + 2) * 200 + 2 * h + 1] = (short)__bfloat16_as_ushort(__float2bfloat16(im.z));
        X[(cq + 3) * 200 + 2 * h]     = (short)__bfloat16_as_ushort(__float2bfloat16(re.w));
        X[(cq + 3) * 200 + 2 * h + 1] = (short)__bfloat16_as_ushort(__float2bfloat16(im.w));
    }
    for (int z = tid; z < 64 * 12; z += 256) {
        int c = z / 12, j = 180 + z % 12;
        Xt[c * 200 + j] = __float2bfloat16(0.f);
    }
    __syncthreads();
    const short* Tp = (const short*)Th;
    f32x4 zero = {0.f, 0.f, 0.f, 0.f};
    f32x4 acc[3][4];
#pragma unroll
    for (int m = 0; m < 3; ++m)
#pragma unroll
        for (int n = 0; n < 4; ++n) acc[m][n] = zero;
#pragma unroll
    for (int ks = 0; ks < 6; ++ks) {
        short8 af[3], bf[4];
#pragma unroll
        for (int m = 0; m < 3; ++m)
            af[m] = *(const short8*)&Tp[(wid * 48 + m * 16 + lrow) * 192 + ks * 32 + lk8 * 8];
#pragma unroll
        for (int n = 0; n < 4; ++n)
            bf[n] = *(const short8*)&X[(n * 16 + lrow) * 200 + ks * 32 + lk8 * 8];
#pragma unroll
        for (int m = 0; m < 3; ++m)
#pragma unroll
            for (int n = 0; n < 4; ++n)
                acc[m][n] = __builtin_amdgcn_mfma_f32_16x16x32_bf16(af[m], bf[n], acc[m][n], 0, 0, 0);
    }
    int crow = (lane >> 4) * 4, ccol = lane & 15;
#pragma unroll
    for (int m = 0; m < 3; ++m)
#pragma unroll
        for (int j = 0; j < 4; ++j) {
            int r = wid * 48 + m * 16 + crow + j;
            int kh = r >> 1;
            if (kh >= H_) continue;
#pragma unroll
            for (int n = 0; n < 4; ++n) {
                size_t o = base + (size_t)kh * WFK * C_ + n * 16 + ccol;
                if (r & 1) di[o] = acc[m][n][j];
                else       dr[o] = acc[m][n][j];
            }
        }
}

// ---------------- block-diagonal complex 2-layer MLP + softshrink, IN-PLACE, via MFMA ----------------
__global__ __launch_bounds__(256) void blockmlp_mfma_kernel(
        float* __restrict__ vr, float* __restrict__ vi,
        const __hip_bfloat16* __restrict__ wbig, const float* __restrict__ bbig)
{
    __shared__ __hip_bfloat16 X1[64 * 200];
    __shared__ __hip_bfloat16 X2[64 * 200];
    int chunk = blockIdx.x;          // 130 chunks of 64 positions
    int nb = blockIdx.y;
    int tid = threadIdx.x, wid = tid >> 6, lane = tid & 63;
    int p0 = chunk * 64;
    for (int i = tid; i < 64 * 48; i += 256) {
        int p = i / 48, q = i % 48;
        int pg = p0 + p;
        int c4 = (q % 24) * 4;
        bool isr = q < 24;
        float4 v = make_float4(0, 0, 0, 0);
        if (pg < NPOS) {
            const float* src = isr ? vr : vi;
            v = *(const float4*)&src[(size_t)pg * C_ + nb * BSK + c4];
        }
        __hip_bfloat16* d = &X1[p * 200 + (isr ? 0 : 96) + c4];
        d[0] = __float2bfloat16(v.x); d[1] = __float2bfloat16(v.y);
        d[2] = __float2bfloat16(v.z); d[3] = __float2bfloat16(v.w);
    }
    {   // zero K-pad 192..199 not needed (K stops at 192); nothing else to pad
    }
    __syncthreads();
    int n0 = wid * 48;
    int lrow = lane & 15, lk8 = lane >> 4;
    int crow = (lane >> 4) * 4, ccol = lane & 15;
    const short* W1 = (const short*)(wbig + (size_t)nb * 192 * 192);
    const short* W2 = (const short*)(wbig + (size_t)(NBK + nb) * 192 * 192);
    const float* bb1 = bbig + nb * 192;
    const float* bb2 = bbig + (NBK + nb) * 192;
    f32x4 zero = {0.f, 0.f, 0.f, 0.f};
    {
        f32x4 acc[4][3];
#pragma unroll
        for (int m = 0; m < 4; ++m)
#pragma unroll
            for (int n = 0; n < 3; ++n) acc[m][n] = zero;
#pragma unroll
        for (int k0 = 0; k0 < 192; k0 += 32) {
            short8 af[4], bf[3];
#pragma unroll
            for (int m = 0; m < 4; ++m)
                af[m] = *(const short8*)&X1[(m * 16 + lrow) * 200 + k0 + lk8 * 8];
#pragma unroll
            for (int n = 0; n < 3; ++n)
                bf[n] = *(const short8*)&W1[(size_t)(n0 + n * 16 + lrow) * 192 + k0 + lk8 * 8];
#pragma unroll
            for (int m = 0; m < 4; ++m)
#pragma unroll
                for (int n = 0; n < 3; ++n)
                    acc[m][n] = __builtin_amdgcn_mfma_f32_16x16x32_bf16(af[m], bf[n], acc[m][n], 0, 0, 0);
        }
        __syncthreads();
#pragma unroll
        for (int m = 0; m < 4; ++m)
#pragma unroll
            for (int j = 0; j < 4; ++j) {
                int row = m * 16 + crow + j;
#pragma unroll
                for (int n = 0; n < 3; ++n) {
                    int col = n0 + n * 16 + ccol;
                    float v = acc[m][n][j] + bb1[col];
                    X2[row * 200 + col] = __float2bfloat16(fmaxf(v, 0.f));
                }
            }
    }
    __syncthreads();
    {
        f32x4 acc[4][3];
#pragma unroll
        for (int m = 0; m < 4; ++m)
#pragma unroll
            for (int n = 0; n < 3; ++n) acc[m][n] = zero;
#pragma unroll
        for (int k0 = 0; k0 < 192; k0 += 32) {
            short8 af[4], bf[3];
#pragma unroll
            for (int m = 0; m < 4; ++m)
                af[m] = *(const short8*)&X2[(m * 16 + lrow) * 200 + k0 + lk8 * 8];
#pragma unroll
            for (int n = 0; n < 3; ++n)
                bf[n] = *(const short8*)&W2[(size_t)(n0 + n * 16 + lrow) * 192 + k0 + lk8 * 8];
#pragma unroll
            for (int m = 0; m < 4; ++m)
#pragma unroll
                for (int n = 0; n < 3; ++n)
                    acc[m][n] = __builtin_amdgcn_mfma_f32_16x16x32_bf16(af[m], bf[n], acc[m][n], 0, 0, 0);
        }
#pragma unroll
        for (int m = 0; m < 4; ++m)
#pragma unroll
            for (int j = 0; j < 4; ++j) {
                int row = m * 16 + crow + j;
                int pg = p0 + row;
                if (pg >= NPOS) continue;
#pragma unroll
                for (int n = 0; n < 3; ++n) {
                    int col = n0 + n * 16 + ccol;
                    float v = acc[m][n][j] + bb2[col];
                    v = v > LAM ? v - LAM : (v < -LAM ? v + LAM : 0.f);
                    if (col < BSK) vr[(size_t)pg * C_ + nb * BSK + col] = v;
                    else           vi[(size_t)pg * C_ + nb * BSK + col - BSK] = v;
                }
            }
    }
}

// ---------------- inverse rfft along W via MFMA: OUT[180][64] = Tw[192][96] @ Yt^T, + residuals ----------------
__global__ __launch_bounds__(256) void iwfft_kernel(
        const float* __restrict__ inr, const float* __restrict__ ini,
        const __hip_bfloat16* __restrict__ h1, const float* __restrict__ x,
        float* __restrict__ out, const __hip_bfloat16* __restrict__ Tw)
{
    __shared__ __hip_bfloat16 Yt[64 * 104];   // [channel][k], k: 2j=re,2j+1=im, pad 92..95
    int slab = blockIdx.x;        // 180
    int c0 = blockIdx.y * 64;     // 12 groups
    int tid = threadIdx.x, wid = tid >> 6, lane = tid & 63;
    int lrow = lane & 15, lk8 = lane >> 4;
    size_t sb = (size_t)slab * WFK * C_ + c0;
    for (int i = tid; i < WFK * 16; i += 256) {
        int wf = i >> 4, cq = (i & 15) * 4;
        size_t a = sb + (size_t)wf * C_ + cq;
        float4 vrv = *(const float4*)&inr[a];
        float4 viv = *(const float4*)&ini[a];
        Yt[(cq + 0) * 104 + 2 * wf]     = __float2bfloat16(vrv.x);
        Yt[(cq + 0) * 104 + 2 * wf + 1] = __float2bfloat16(viv.x);
        Yt[(cq + 1) * 104 + 2 * wf]     = __float2bfloat16(vrv.y);
        Yt[(cq + 1) * 104 + 2 * wf + 1] = __float2bfloat16(viv.y);
        Yt[(cq + 2) * 104 + 2 * wf]     = __float2bfloat16(vrv.z);
        Yt[(cq + 2) * 104 + 2 * wf + 1] = __float2bfloat16(viv.z);
        Yt[(cq + 3) * 104 + 2 * wf]     = __float2bfloat16(vrv.w);
        Yt[(cq + 3) * 104 + 2 * wf + 1] = __float2bfloat16(viv.w);
    }
    {   // zero K-pad 92..95 for all 64 channels (256 threads exactly)
        int c = tid >> 2, kk = 92 + (tid & 3);
        Yt[c * 104 + kk] = __float2bfloat16(0.f);
    }
    __syncthreads();
    const short* Tp = (const short*)Tw;
    f32x4 zero = {0.f, 0.f, 0.f, 0.f};
    f32x4 acc[3][4];
#pragma unroll
    for (int m = 0; m < 3; ++m)
#pragma unroll
        for (int n = 0; n < 4; ++n) acc[m][n] = zero;
#pragma unroll
    for (int ks = 0; ks < 3; ++ks) {
        short8 af[3], bf[4];
#pragma unroll
        for (int m = 0; m < 3; ++m)
            af[m] = *(const short8*)&Tp[(wid * 48 + m * 16 + lrow) * 96 + ks * 32 + lk8 * 8];
#pragma unroll
        for (int n = 0; n < 4; ++n)
            bf[n] = *(const short8*)&Yt[(n * 16 + lrow) * 104 + ks * 32 + lk8 * 8];
#pragma unroll
        for (int m = 0; m < 3; ++m)
#pragma unroll
            for (int n = 0; n < 4; ++n)
                acc[m][n] = __builtin_amdgcn_mfma_f32_16x16x32_bf16(af[m], bf[n], acc[m][n], 0, 0, 0);
    }
    int crow = (lane >> 4) * 4, ccol = lane & 15;
    const short* hp = (const short*)h1;
#pragma unroll
    for (int m = 0; m < 3; ++m)
#pragma unroll
        for (int j = 0; j < 4; ++j) {
            int w = wid * 48 + m * 16 + crow + j;
            if (w >= W_) continue;
            size_t o = ((size_t)slab * W_ + w) * C_ + c0;
#pragma unroll
            for (int n = 0; n < 4; ++n) {
                int col = n * 16 + ccol;
                out[o + col] = acc[m][n][j] + bf2f(hp[o + col]) + x[o + col];
            }
        }
}

// ---------------- transpose + f32->bf16 (weights) ----------------
__global__ __launch_bounds__(256) void transpose_cvt_kernel(const float* __restrict__ Wm,
        __hip_bfloat16* __restrict__ Wt, int R, int Ccol)
{
    __shared__ float tile[32][33];
    int c0 = blockIdx.x * 32, r0 = blockIdx.y * 32;
    int tid = threadIdx.x;
    int tc = tid & 31, tr = tid >> 5;
#pragma unroll
    for (int k = 0; k < 4; ++k)
        tile[tr + k * 8][tc] = Wm[(size_t)(r0 + tr + k * 8) * Ccol + c0 + tc];
    __syncthreads();
    int rr = tid & 31, cc = tid >> 5;
#pragma unroll
    for (int k = 0; k < 4; ++k)
        Wt[(size_t)(c0 + cc + k * 8) * R + r0 + rr] = __float2bfloat16(tile[rr][cc + k * 8]);
}

// ---------------- bf16 MFMA GEMM (m97 structure): C[M,N] = A[M,K] * Bt[N,K]^T ----------------
template<int EPI>
__global__ __launch_bounds__(256) void gemm_kernel(
        const short* __restrict__ A, const short* __restrict__ Bt,
        const float* __restrict__ bias,
        __hip_bfloat16* __restrict__ obf, float* __restrict__ of32,
        const float* __restrict__ res, int N, int K, int mvalid)
{
    __shared__ short As[128 * 32];
    __shared__ short Bs[128 * 32];
    int tid = threadIdx.x;
    int wid = tid >> 6, lane = tid & 63;
    int wm = (wid >> 1) * 64, wn = (wid & 1) * 64;
    int lrow = lane & 15, lk8 = lane >> 4;
    f32x4 zero = {0.f, 0.f, 0.f, 0.f};
    f32x4 acc[4][4];
#pragma unroll
    for (int i = 0; i < 4; ++i)
#pragma unroll
        for (int j = 0; j < 4; ++j) acc[i][j] = zero;
    size_t m0 = (size_t)blockIdx.x * 128, n0 = (size_t)blockIdx.y * 128;
    int srow = tid >> 2;            // 0..63
    int scol = (tid & 3) * 8;       // k-octet
    const short* Ag = A + (m0 + srow) * K + scol;
    const short* Bg = Bt + (n0 + srow) * K + scol;
    char* Asb = (char*)As + (size_t)tid * 16;
    char* Bsb = (char*)Bs + (size_t)tid * 16;
    for (int k0 = 0; k0 < K; k0 += 32) {
        __syncthreads();            // prior reads done before overwrite
        gload_lds16(Ag + k0, Asb);
        gload_lds16(Ag + k0 + (size_t)64 * K, Asb + 4096);
        gload_lds16(Bg + k0, Bsb);
        gload_lds16(Bg + k0 + (size_t)64 * K, Bsb + 4096);
        __syncthreads();            // implicit vmcnt(0) drain
        short8 af[4], bfr[4];
#pragma unroll
        for (int mf = 0; mf < 4; ++mf) af[mf] = *(const short8*)&As[(wm + mf * 16 + lrow) * 32 + lk8 * 8];
#pragma unroll
        for (int nf = 0; nf < 4; ++nf) bfr[nf] = *(const short8*)&Bs[(wn + nf * 16 + lrow) * 32 + lk8 * 8];
#pragma unroll
        for (int mf = 0; mf < 4; ++mf)
#pragma unroll
            for (int nf = 0; nf < 4; ++nf)
                acc[mf][nf] = __builtin_amdgcn_mfma_f32_16x16x32_bf16(af[mf], bfr[nf], acc[mf][nf], 0, 0, 0);
    }
    int crow = (lane >> 4) * 4;
    int ccol = lane & 15;
#pragma unroll
    for (int mf = 0; mf < 4; ++mf) {
#pragma unroll
        for (int j = 0; j < 4; ++j) {
            size_t r = m0 + wm + mf * 16 + crow + j;
            if (EPI == 1 && r >= (size_t)mvalid) continue;
#pragma unroll
            for (int nf = 0; nf < 4; ++nf) {
                size_t cidx = n0 + wn + nf * 16 + ccol;
                float v = acc[mf][nf][j] + bias[cidx];
                if (EPI == 0) {
                    float g = 0.5f * v * (1.f + erff(v * 0.70710678118654752f));
                    obf[r * N + cidx] = __float2bfloat16(g);
                } else {
                    of32[r * N + cidx] = v + res[r * N + cidx];
                }
            }
        }
    }
}

extern "C" void kernel_launch(void* const* d_in, const int* in_sizes, int n_in,
                              void* d_out, int out_size, void* d_ws, size_t ws_size,
                              hipStream_t stream) {
    (void)in_sizes; (void)n_in; (void)out_size; (void)ws_size;
    const float* x    = (const float*)d_in[0];
    const float* n1w  = (const float*)d_in[1];
    const float* n1b  = (const float*)d_in[2];
    const float* w1   = (const float*)d_in[3];
    const float* b1   = (const float*)d_in[4];
    const float* w2   = (const float*)d_in[5];
    const float* b2   = (const float*)d_in[6];
    const float* n2w  = (const float*)d_in[7];
    const float* n2b  = (const float*)d_in[8];
    const float* fc1w = (const float*)d_in[9];
    const float* fc1b = (const float*)d_in[10];
    const float* fc2w = (const float*)d_in[11];
    const float* fc2b = (const float*)d_in[12];
    float* out = (float*)d_out;

    // ---- workspace layout (~112 MB) with region aliasing ----
    float* wsf = (float*)d_ws;
    size_t off = 0;
    auto alloc = [&](size_t nfloats) { float* p = wsf + off; off += (nfloats + 63) & ~(size_t)63; return p; };
    float* region1 = alloc((size_t)MPAD * C_ / 2);          // h1 (bf16) then h3 (bf16)
    float* region2 = alloc((size_t)2 * NPOS * C_);          // f1r,f1i (f32) then tb (bf16 chunk)
    __hip_bfloat16* w1t = (__hip_bfloat16*)alloc((size_t)HID * C_ / 2);
    __hip_bfloat16* w2t = (__hip_bfloat16*)alloc((size_t)HID * C_ / 2);
    __hip_bfloat16* wbig = (__hip_bfloat16*)alloc((size_t)2 * NBK * 192 * 192 / 2);
    float* bbig = alloc(2 * NBK * 192);
    __hip_bfloat16* Tw  = (__hip_bfloat16*)alloc(192 * 96 / 2);
    __hip_bfloat16* Twf = (__hip_bfloat16*)alloc(96 * 192 / 2);
    __hip_bfloat16* Thf = (__hip_bfloat16*)alloc(192 * 192 / 2);
    __hip_bfloat16* Thi = (__hip_bfloat16*)alloc(192 * 192 / 2);

    __hip_bfloat16* h1b = (__hip_bfloat16*)region1;
    __hip_bfloat16* h3  = (__hip_bfloat16*)region1;
    float* f1r = region2;
    float* f1i = region2 + (size_t)NPOS * C_;
    __hip_bfloat16* tb  = (__hip_bfloat16*)region2;

    init_tables_kernel<<<144, 256, 0, stream>>>(Tw, Twf, Thf, Thi);
    wprep_kernel<<<(2 * NBK * 192 * 192 + 255) / 256, 256, 0, stream>>>(w1, b1, w2, b2, wbig, bbig);
    transpose_cvt_kernel<<<dim3(HID / 32, C_ / 32), 256, 0, stream>>>(fc1w, w1t, C_, HID);
    transpose_cvt_kernel<<<dim3(C_ / 32, HID / 32), 256, 0, stream>>>(fc2w, w2t, HID, C_);

    ln_kernel<<<NTOK, 256, 0, stream>>>(x, n1w, n1b, h1b, NTOK);
    wfft_kernel<<<dim3(B_ * H_, 12), 256, 0, stream>>>(h1b, f1r, f1i, Twf);
    hdft_kernel<<<dim3(B_ * WFK, 12), 256, 0, stream>>>(f1r, f1i, Thf);
    blockmlp_mfma_kernel<<<dim3(130, NBK), 256, 0, stream>>>(f1r, f1i, wbig, bbig);
    hdft_kernel<<<dim3(B_ * WFK, 12), 256, 0, stream>>>(f1r, f1i, Thi);
    iwfft_kernel<<<dim3(B_ * H_, 12), 256, 0, stream>>>(f1r, f1i, h1b, x, out, Tw);
    // h1b, f1r/f1i dead from here; regions reused by h3 and tb
    ln_kernel<<<MPAD, 256, 0, stream>>>(out, n2w, n2b, h3, NTOK);
    for (int c = 0; c < 4; ++c) {
        int base = c * CHROWS;
        int tiles = (c < 3) ? (CHROWS / 128) : ((MPAD - 3 * CHROWS) / 128); // 64,64,64,62
        gemm_kernel<0><<<dim3(tiles, HID / 128), 256, 0, stream>>>(
            (const short*)(h3 + (size_t)base * C_), (const short*)w1t, fc1b,
            tb, nullptr, nullptr, HID, C_, 0);
        gemm_kernel<1><<<dim3(tiles, C_ / 128), 256, 0, stream>>>(
            (const short*)tb, (const short*)w2t, fc2b,
            nullptr, out + (size_t)base * C_, out + (size_t)base * C_, C_, HID, NTOK - base);
    }
}

// Round 6
// 810.210 us; speedup vs baseline: 1.7571x; 1.1389x over previous
//
#include <hip/hip_runtime.h>
#include <hip/hip_bf16.h>

#define B_    2
#define H_    90
#define W_    180
#define C_    768
#define WFK   46          // kept W-frequency modes (of 91)
#define NBK   8
#define BSK   96
#define HID   3072
#define NTOK  (B_*H_*W_)  // 32400
#define MPAD  32512       // 254*128
#define NPOS  (B_*H_*WFK) // 8280
#define LAM   0.01f

typedef __attribute__((ext_vector_type(8))) short short8;
typedef __attribute__((ext_vector_type(4))) float f32x4;

__device__ __forceinline__ float bf2f(short u) {
    union { unsigned int i; float f; } z;
    z.i = ((unsigned int)(unsigned short)u) << 16;
    return z.f;
}

__device__ __forceinline__ void gload_lds16(const void* g, void* l) {
    __builtin_amdgcn_global_load_lds((const __attribute__((address_space(1))) void*)g,
                                     (__attribute__((address_space(3))) void*)l, 16, 0, 0);
}

// ---------------- bf16 twiddle tables for all MFMA DFT stages ----------------
__global__ __launch_bounds__(256) void init_tables_kernel(__hip_bfloat16* Tw, __hip_bfloat16* Twf,
                                                          __hip_bfloat16* Thf, __hip_bfloat16* Thi) {
    int i = blockIdx.x * 256 + threadIdx.x;
    const float S = 0.00785674201318386f; // 1/sqrt(90*180)
    if (i < 192 * 96) {
        int w = i / 96, k = i % 96;
        int j = k >> 1, odd = k & 1;
        float val = 0.f;
        if (w < W_ && j < WFK) {
            float th = (float)((w * j) % W_) * (float)(6.283185307179586476925286766559 / 180.0);
            if (odd) val = (j == 0) ? 0.f : -2.f * S * sinf(th);
            else     val = (j == 0) ? S : 2.f * S * cosf(th);
        }
        Tw[i] = __float2bfloat16(val);
    }
    if (i < 96 * 192) {
        int r = i / 192, w = i % 192;
        int wf = r >> 1, odd = r & 1;
        float val = 0.f;
        if (w < W_ && wf < WFK) {
            float th = (float)((w * wf) % W_) * (float)(6.283185307179586476925286766559 / 180.0);
            val = odd ? -S * sinf(th) : S * cosf(th);
        }
        Twf[i] = __float2bfloat16(val);
    }
    if (i < 192 * 192) {
        int r = i / 192, j = i % 192;
        float vf = 0.f, vi = 0.f;
        if (r < 180 && j < 180) {
            int k = r >> 1, ro = r & 1, h = j >> 1, jo = j & 1;
            float th = (float)((k * h) % H_) * (float)(6.283185307179586476925286766559 / 90.0);
            float c = cosf(th), s = sinf(th);
            vf = ro ? (jo ? c : -s) : (jo ? s : c);   // fwd
            vi = ro ? (jo ? c : s) : (jo ? -s : c);   // inv
        }
        Thf[i] = __float2bfloat16(vf);
        Thi[i] = __float2bfloat16(vi);
    }
}

// ---------------- build expanded real weights for the block-MLP ----------------
__global__ __launch_bounds__(256) void wprep_kernel(
        const float* __restrict__ w1, const float* __restrict__ b1,
        const float* __restrict__ w2, const float* __restrict__ b2,
        __hip_bfloat16* __restrict__ wbig, float* __restrict__ bbig)
{
    int idx = blockIdx.x * 256 + threadIdx.x;
    if (idx < 2 * NBK * 192 * 192) {
        int k = idx % 192;
        int o = (idx / 192) % 192;
        int nb = (idx / (192 * 192)) % NBK;
        int L = idx / (192 * 192 * NBK);
        const float* w = L ? w2 : w1;
        const float* wr = w + (size_t)nb * BSK * BSK;
        const float* wi = w + (size_t)(NBK + nb) * BSK * BSK;
        int kk = k % BSK, oo = o % BSK;
        float val;
        if (o < BSK)  val = (k < BSK) ? wr[kk * BSK + oo] : -wi[kk * BSK + oo];
        else          val = (k < BSK) ? wi[kk * BSK + oo] :  wr[kk * BSK + oo];
        wbig[((size_t)(L * NBK + nb) * 192 + o) * 192 + k] = __float2bfloat16(val);
    }
    if (idx < 2 * NBK * 192) {
        int o = idx % 192;
        int nb = (idx / 192) % NBK;
        int L = idx / (192 * NBK);
        const float* b = L ? b2 : b1;
        bbig[idx] = (o < BSK) ? b[nb * BSK + o] : b[(NBK + nb) * BSK + (o - BSK)];
    }
}

// ---------------- LayerNorm: f32 in -> bf16 out, zero-pads rows >= ntok_valid ----------------
__global__ __launch_bounds__(256) void ln_kernel(const float* __restrict__ in,
        const float* __restrict__ w, const float* __restrict__ b,
        __hip_bfloat16* __restrict__ outb, int ntok_valid)
{
    int tok = blockIdx.x;
    int tid = threadIdx.x;
    size_t base = (size_t)tok * C_;
    if (tok >= ntok_valid) {
        __hip_bfloat16 z = __float2bfloat16(0.f);
        outb[base + tid] = z; outb[base + tid + 256] = z; outb[base + tid + 512] = z;
        return;
    }
    float x0 = in[base + tid], x1 = in[base + tid + 256], x2 = in[base + tid + 512];
    float s = x0 + x1 + x2;
    float q = x0*x0 + x1*x1 + x2*x2;
#pragma unroll
    for (int off = 32; off > 0; off >>= 1) { s += __shfl_down(s, off); q += __shfl_down(q, off); }
    __shared__ float rs[4], rq[4];
    int wid = tid >> 6, lane = tid & 63;
    if (lane == 0) { rs[wid] = s; rq[wid] = q; }
    __syncthreads();
    float ts = rs[0] + rs[1] + rs[2] + rs[3];
    float tq = rq[0] + rq[1] + rq[2] + rq[3];
    float mu = ts * (1.f / C_);
    float var = tq * (1.f / C_) - mu * mu;
    float rstd = rsqrtf(var + 1e-5f);
#pragma unroll
    for (int k = 0; k < 3; ++k) {
        int c = tid + k * 256;
        float xv = (k == 0 ? x0 : (k == 1 ? x1 : x2));
        outb[base + c] = __float2bfloat16((xv - mu) * rstd * w[c] + b[c]);
    }
}

// ---------------- forward rfft along W via MFMA: OUT[96][64] = Twf @ Xt^T ----------------
__global__ __launch_bounds__(256) void wfft_kernel(const __hip_bfloat16* __restrict__ h1,
        float* __restrict__ f1r, float* __restrict__ f1i,
        const __hip_bfloat16* __restrict__ Twf)
{
    __shared__ __hip_bfloat16 Xt[64 * 200];  // [c][w], w pad 180..191 = 0
    int slab = blockIdx.x;           // b*90+h
    int c0 = blockIdx.y * 64;
    int tid = threadIdx.x, wid = tid >> 6, lane = tid & 63;
    int lrow = lane & 15, lk8 = lane >> 4;
    const short* src = (const short*)h1 + (size_t)slab * W_ * C_ + c0;
    short* X = (short*)Xt;
    for (int i = tid; i < W_ * 8; i += 256) {
        int w = i >> 3, c8 = (i & 7) * 8;
        short8 v = *(const short8*)&src[(size_t)w * C_ + c8];
#pragma unroll
        for (int j = 0; j < 8; ++j) X[(c8 + j) * 200 + w] = v[j];
    }
    for (int z = tid; z < 64 * 12; z += 256) {
        int c = z / 12, w = 180 + z % 12;
        Xt[c * 200 + w] = __float2bfloat16(0.f);
    }
    __syncthreads();
    const short* Tp = (const short*)Twf;
    f32x4 zero = {0.f, 0.f, 0.f, 0.f};
    f32x4 acc[6];
#pragma unroll
    for (int m = 0; m < 6; ++m) acc[m] = zero;
#pragma unroll
    for (int ks = 0; ks < 6; ++ks) {
        short8 bf = *(const short8*)&X[(wid * 16 + lrow) * 200 + ks * 32 + lk8 * 8];
#pragma unroll
        for (int m = 0; m < 6; ++m) {
            short8 af = *(const short8*)&Tp[(m * 16 + lrow) * 192 + ks * 32 + lk8 * 8];
            acc[m] = __builtin_amdgcn_mfma_f32_16x16x32_bf16(af, bf, acc[m], 0, 0, 0);
        }
    }
    int crow = (lane >> 4) * 4, ccol = lane & 15;
#pragma unroll
    for (int m = 0; m < 6; ++m)
#pragma unroll
        for (int j = 0; j < 4; ++j) {
            int r = m * 16 + crow + j;
            int wf = r >> 1;
            if (wf >= WFK) continue;
            size_t o = ((size_t)slab * WFK + wf) * C_ + c0 + wid * 16 + ccol;
            if (r & 1) f1i[o] = acc[m][j];
            else       f1r[o] = acc[m][j];
        }
}

// ---------------- complex DFT along H via MFMA, IN-PLACE: OUT[192][64] = Th @ Xt^T ----------------
__global__ __launch_bounds__(256) void hdft_kernel(float* __restrict__ dr, float* __restrict__ di,
        const __hip_bfloat16* __restrict__ Th)
{
    __shared__ __hip_bfloat16 Xt[64 * 200];  // [c][j], j=2h re / 2h+1 im, pad 180..191 = 0
    int bwf = blockIdx.x;            // b*46+wf
    int b = bwf / WFK, wf = bwf % WFK;
    int c0 = blockIdx.y * 64;
    int tid = threadIdx.x, wid = tid >> 6, lane = tid & 63;
    int lrow = lane & 15, lk8 = lane >> 4;
    size_t base = ((size_t)(b * H_) * WFK + wf) * C_ + c0;
    short* X = (short*)Xt;
    for (int i = tid; i < H_ * 16; i += 256) {
        int h = i >> 4, cq = (i & 15) * 4;
        size_t a = base + (size_t)h * WFK * C_ + cq;
        float4 re = *(const float4*)&dr[a];
        float4 im = *(const float4*)&di[a];
        X[(cq + 0) * 200 + 2 * h]     = (short)__bfloat16_as_ushort(__float2bfloat16(re.x));
        X[(cq + 0) * 200 + 2 * h + 1] = (short)__bfloat16_as_ushort(__float2bfloat16(im.x));
        X[(cq + 1) * 200 + 2 * h]     = (short)__bfloat16_as_ushort(__float2bfloat16(re.y));
        X[(cq + 1) * 200 + 2 * h + 1] = (short)__bfloat16_as_ushort(__float2bfloat16(im.y));
        X[(cq + 2) * 200 + 2 * h]     = (short)__bfloat16_as_ushort(__float2bfloat16(re.z));
        X[(cq + 2) * 200 + 2 * h + 1] = (short)__bfloat16_as_ushort(__float2bfloat16(im.z));
        X[(cq + 3) * 200 + 2 * h]     = (short)__bfloat16_as_ushort(__float2bfloat16(re.w));
        X[(cq + 3) * 200 + 2 * h + 1] = (short)__bfloat16_as_ushort(__float2bfloat16(im.w));
    }
    for (int z = tid; z < 64 * 12; z += 256) {
        int c = z / 12, j = 180 + z % 12;
        Xt[c * 200 + j] = __float2bfloat16(0.f);
    }
    __syncthreads();
    const short* Tp = (const short*)Th;
    f32x4 zero = {0.f, 0.f, 0.f, 0.f};
    f32x4 acc[3][4];
#pragma unroll
    for (int m = 0; m < 3; ++m)
#pragma unroll
        for (int n = 0; n < 4; ++n) acc[m][n] = zero;
#pragma unroll
    for (int ks = 0; ks < 6; ++ks) {
        short8 af[3], bf[4];
#pragma unroll
        for (int m = 0; m < 3; ++m)
            af[m] = *(const short8*)&Tp[(wid * 48 + m * 16 + lrow) * 192 + ks * 32 + lk8 * 8];
#pragma unroll
        for (int n = 0; n < 4; ++n)
            bf[n] = *(const short8*)&X[(n * 16 + lrow) * 200 + ks * 32 + lk8 * 8];
#pragma unroll
        for (int m = 0; m < 3; ++m)
#pragma unroll
            for (int n = 0; n < 4; ++n)
                acc[m][n] = __builtin_amdgcn_mfma_f32_16x16x32_bf16(af[m], bf[n], acc[m][n], 0, 0, 0);
    }
    int crow = (lane >> 4) * 4, ccol = lane & 15;
#pragma unroll
    for (int m = 0; m < 3; ++m)
#pragma unroll
        for (int j = 0; j < 4; ++j) {
            int r = wid * 48 + m * 16 + crow + j;
            int kh = r >> 1;
            if (kh >= H_) continue;
#pragma unroll
            for (int n = 0; n < 4; ++n) {
                size_t o = base + (size_t)kh * WFK * C_ + n * 16 + ccol;
                if (r & 1) di[o] = acc[m][n][j];
                else       dr[o] = acc[m][n][j];
            }
        }
}

// ---------------- block-diagonal complex 2-layer MLP + softshrink, IN-PLACE, via MFMA ----------------
__global__ __launch_bounds__(256) void blockmlp_mfma_kernel(
        float* __restrict__ vr, float* __restrict__ vi,
        const __hip_bfloat16* __restrict__ wbig, const float* __restrict__ bbig)
{
    __shared__ __hip_bfloat16 X1[64 * 200];
    __shared__ __hip_bfloat16 X2[64 * 200];
    int chunk = blockIdx.x;          // 130 chunks of 64 positions
    int nb = blockIdx.y;
    int tid = threadIdx.x, wid = tid >> 6, lane = tid & 63;
    int p0 = chunk * 64;
    for (int i = tid; i < 64 * 48; i += 256) {
        int p = i / 48, q = i % 48;
        int pg = p0 + p;
        int c4 = (q % 24) * 4;
        bool isr = q < 24;
        float4 v = make_float4(0, 0, 0, 0);
        if (pg < NPOS) {
            const float* src = isr ? vr : vi;
            v = *(const float4*)&src[(size_t)pg * C_ + nb * BSK + c4];
        }
        __hip_bfloat16* d = &X1[p * 200 + (isr ? 0 : 96) + c4];
        d[0] = __float2bfloat16(v.x); d[1] = __float2bfloat16(v.y);
        d[2] = __float2bfloat16(v.z); d[3] = __float2bfloat16(v.w);
    }
    __syncthreads();
    int n0 = wid * 48;
    int lrow = lane & 15, lk8 = lane >> 4;
    int crow = (lane >> 4) * 4, ccol = lane & 15;
    const short* W1 = (const short*)(wbig + (size_t)nb * 192 * 192);
    const short* W2 = (const short*)(wbig + (size_t)(NBK + nb) * 192 * 192);
    const float* bb1 = bbig + nb * 192;
    const float* bb2 = bbig + (NBK + nb) * 192;
    f32x4 zero = {0.f, 0.f, 0.f, 0.f};
    {
        f32x4 acc[4][3];
#pragma unroll
        for (int m = 0; m < 4; ++m)
#pragma unroll
            for (int n = 0; n < 3; ++n) acc[m][n] = zero;
#pragma unroll
        for (int k0 = 0; k0 < 192; k0 += 32) {
            short8 af[4], bf[3];
#pragma unroll
            for (int m = 0; m < 4; ++m)
                af[m] = *(const short8*)&X1[(m * 16 + lrow) * 200 + k0 + lk8 * 8];
#pragma unroll
            for (int n = 0; n < 3; ++n)
                bf[n] = *(const short8*)&W1[(size_t)(n0 + n * 16 + lrow) * 192 + k0 + lk8 * 8];
#pragma unroll
            for (int m = 0; m < 4; ++m)
#pragma unroll
                for (int n = 0; n < 3; ++n)
                    acc[m][n] = __builtin_amdgcn_mfma_f32_16x16x32_bf16(af[m], bf[n], acc[m][n], 0, 0, 0);
        }
        __syncthreads();
#pragma unroll
        for (int m = 0; m < 4; ++m)
#pragma unroll
            for (int j = 0; j < 4; ++j) {
                int row = m * 16 + crow + j;
#pragma unroll
                for (int n = 0; n < 3; ++n) {
                    int col = n0 + n * 16 + ccol;
                    float v = acc[m][n][j] + bb1[col];
                    X2[row * 200 + col] = __float2bfloat16(fmaxf(v, 0.f));
                }
            }
    }
    __syncthreads();
    {
        f32x4 acc[4][3];
#pragma unroll
        for (int m = 0; m < 4; ++m)
#pragma unroll
            for (int n = 0; n < 3; ++n) acc[m][n] = zero;
#pragma unroll
        for (int k0 = 0; k0 < 192; k0 += 32) {
            short8 af[4], bf[3];
#pragma unroll
            for (int m = 0; m < 4; ++m)
                af[m] = *(const short8*)&X2[(m * 16 + lrow) * 200 + k0 + lk8 * 8];
#pragma unroll
            for (int n = 0; n < 3; ++n)
                bf[n] = *(const short8*)&W2[(size_t)(n0 + n * 16 + lrow) * 192 + k0 + lk8 * 8];
#pragma unroll
            for (int m = 0; m < 4; ++m)
#pragma unroll
                for (int n = 0; n < 3; ++n)
                    acc[m][n] = __builtin_amdgcn_mfma_f32_16x16x32_bf16(af[m], bf[n], acc[m][n], 0, 0, 0);
        }
#pragma unroll
        for (int m = 0; m < 4; ++m)
#pragma unroll
            for (int j = 0; j < 4; ++j) {
                int row = m * 16 + crow + j;
                int pg = p0 + row;
                if (pg >= NPOS) continue;
#pragma unroll
                for (int n = 0; n < 3; ++n) {
                    int col = n0 + n * 16 + ccol;
                    float v = acc[m][n][j] + bb2[col];
                    v = v > LAM ? v - LAM : (v < -LAM ? v + LAM : 0.f);
                    if (col < BSK) vr[(size_t)pg * C_ + nb * BSK + col] = v;
                    else           vi[(size_t)pg * C_ + nb * BSK + col - BSK] = v;
                }
            }
    }
}

// ---------------- inverse rfft along W via MFMA: OUT[180][64] = Tw[192][96] @ Yt^T, + residuals ----------------
__global__ __launch_bounds__(256) void iwfft_kernel(
        const float* __restrict__ inr, const float* __restrict__ ini,
        const __hip_bfloat16* __restrict__ h1, const float* __restrict__ x,
        float* __restrict__ out, const __hip_bfloat16* __restrict__ Tw)
{
    __shared__ __hip_bfloat16 Yt[64 * 104];   // [channel][k], k: 2j=re,2j+1=im, pad 92..95
    int slab = blockIdx.x;        // 180
    int c0 = blockIdx.y * 64;     // 12 groups
    int tid = threadIdx.x, wid = tid >> 6, lane = tid & 63;
    int lrow = lane & 15, lk8 = lane >> 4;
    size_t sb = (size_t)slab * WFK * C_ + c0;
    for (int i = tid; i < WFK * 16; i += 256) {
        int wf = i >> 4, cq = (i & 15) * 4;
        size_t a = sb + (size_t)wf * C_ + cq;
        float4 vrv = *(const float4*)&inr[a];
        float4 viv = *(const float4*)&ini[a];
        Yt[(cq + 0) * 104 + 2 * wf]     = __float2bfloat16(vrv.x);
        Yt[(cq + 0) * 104 + 2 * wf + 1] = __float2bfloat16(viv.x);
        Yt[(cq + 1) * 104 + 2 * wf]     = __float2bfloat16(vrv.y);
        Yt[(cq + 1) * 104 + 2 * wf + 1] = __float2bfloat16(viv.y);
        Yt[(cq + 2) * 104 + 2 * wf]     = __float2bfloat16(vrv.z);
        Yt[(cq + 2) * 104 + 2 * wf + 1] = __float2bfloat16(viv.z);
        Yt[(cq + 3) * 104 + 2 * wf]     = __float2bfloat16(vrv.w);
        Yt[(cq + 3) * 104 + 2 * wf + 1] = __float2bfloat16(viv.w);
    }
    {
        int c = tid >> 2, kk = 92 + (tid & 3);
        Yt[c * 104 + kk] = __float2bfloat16(0.f);
    }
    __syncthreads();
    const short* Tp = (const short*)Tw;
    f32x4 zero = {0.f, 0.f, 0.f, 0.f};
    f32x4 acc[3][4];
#pragma unroll
    for (int m = 0; m < 3; ++m)
#pragma unroll
        for (int n = 0; n < 4; ++n) acc[m][n] = zero;
#pragma unroll
    for (int ks = 0; ks < 3; ++ks) {
        short8 af[3], bf[4];
#pragma unroll
        for (int m = 0; m < 3; ++m)
            af[m] = *(const short8*)&Tp[(wid * 48 + m * 16 + lrow) * 96 + ks * 32 + lk8 * 8];
#pragma unroll
        for (int n = 0; n < 4; ++n)
            bf[n] = *(const short8*)&Yt[(n * 16 + lrow) * 104 + ks * 32 + lk8 * 8];
#pragma unroll
        for (int m = 0; m < 3; ++m)
#pragma unroll
            for (int n = 0; n < 4; ++n)
                acc[m][n] = __builtin_amdgcn_mfma_f32_16x16x32_bf16(af[m], bf[n], acc[m][n], 0, 0, 0);
    }
    int crow = (lane >> 4) * 4, ccol = lane & 15;
    const short* hp = (const short*)h1;
#pragma unroll
    for (int m = 0; m < 3; ++m)
#pragma unroll
        for (int j = 0; j < 4; ++j) {
            int w = wid * 48 + m * 16 + crow + j;
            if (w >= W_) continue;
            size_t o = ((size_t)slab * W_ + w) * C_ + c0;
#pragma unroll
            for (int n = 0; n < 4; ++n) {
                int col = n * 16 + ccol;
                out[o + col] = acc[m][n][j] + bf2f(hp[o + col]) + x[o + col];
            }
        }
}

// ---------------- transpose + f32->bf16 (weights) ----------------
__global__ __launch_bounds__(256) void transpose_cvt_kernel(const float* __restrict__ Wm,
        __hip_bfloat16* __restrict__ Wt, int R, int Ccol)
{
    __shared__ float tile[32][33];
    int c0 = blockIdx.x * 32, r0 = blockIdx.y * 32;
    int tid = threadIdx.x;
    int tc = tid & 31, tr = tid >> 5;
#pragma unroll
    for (int k = 0; k < 4; ++k)
        tile[tr + k * 8][tc] = Wm[(size_t)(r0 + tr + k * 8) * Ccol + c0 + tc];
    __syncthreads();
    int rr = tid & 31, cc = tid >> 5;
#pragma unroll
    for (int k = 0; k < 4; ++k)
        Wt[(size_t)(c0 + cc + k * 8) * R + r0 + rr] = __float2bfloat16(tile[rr][cc + k * 8]);
}

// ---------------- bf16 MFMA GEMM (m97 structure + M-supertile remap) ----------------
// Flat 1D grid of MT*NT blocks; SUPER=16 m-tiles share an L2-hot A panel across the N sweep.
// EPI 0: out = bf16( gelu(acc + bias) ) -> obf      (all rows)
// EPI 1: out = f32 ( acc + bias + res )  -> of32    (rows < mvalid only)
template<int EPI>
__global__ __launch_bounds__(256) void gemm_kernel(
        const short* __restrict__ A, const short* __restrict__ Bt,
        const float* __restrict__ bias,
        __hip_bfloat16* __restrict__ obf, float* __restrict__ of32,
        const float* __restrict__ res, int N, int K, int mvalid, int MT, int NT)
{
    __shared__ short As[128 * 32];
    __shared__ short Bs[128 * 32];
    // ---- supertile remap (bijective incl. remainder supertile) ----
    int id = blockIdx.x;
    const int SUPER = 16;
    int per = SUPER * NT;
    int sidx = id / per;
    int offs = id % per;
    int rows = MT - sidx * SUPER; if (rows > SUPER) rows = SUPER;
    int mt = sidx * SUPER + offs % rows;
    int nt = offs / rows;
    size_t m0 = (size_t)mt * 128, n0 = (size_t)nt * 128;

    int tid = threadIdx.x;
    int wid = tid >> 6, lane = tid & 63;
    int wm = (wid >> 1) * 64, wn = (wid & 1) * 64;
    int lrow = lane & 15, lk8 = lane >> 4;
    f32x4 zero = {0.f, 0.f, 0.f, 0.f};
    f32x4 acc[4][4];
#pragma unroll
    for (int i = 0; i < 4; ++i)
#pragma unroll
        for (int j = 0; j < 4; ++j) acc[i][j] = zero;
    int srow = tid >> 2;            // 0..63
    int scol = (tid & 3) * 8;       // k-octet
    const short* Ag = A + (m0 + srow) * K + scol;
    const short* Bg = Bt + (n0 + srow) * K + scol;
    char* Asb = (char*)As + (size_t)tid * 16;
    char* Bsb = (char*)Bs + (size_t)tid * 16;
    for (int k0 = 0; k0 < K; k0 += 32) {
        __syncthreads();            // prior reads done before overwrite
        gload_lds16(Ag + k0, Asb);
        gload_lds16(Ag + k0 + (size_t)64 * K, Asb + 4096);
        gload_lds16(Bg + k0, Bsb);
        gload_lds16(Bg + k0 + (size_t)64 * K, Bsb + 4096);
        __syncthreads();            // implicit vmcnt(0) drain
        short8 af[4], bfr[4];
#pragma unroll
        for (int mf = 0; mf < 4; ++mf) af[mf] = *(const short8*)&As[(wm + mf * 16 + lrow) * 32 + lk8 * 8];
#pragma unroll
        for (int nf = 0; nf < 4; ++nf) bfr[nf] = *(const short8*)&Bs[(wn + nf * 16 + lrow) * 32 + lk8 * 8];
#pragma unroll
        for (int mf = 0; mf < 4; ++mf)
#pragma unroll
            for (int nf = 0; nf < 4; ++nf)
                acc[mf][nf] = __builtin_amdgcn_mfma_f32_16x16x32_bf16(af[mf], bfr[nf], acc[mf][nf], 0, 0, 0);
    }
    int crow = (lane >> 4) * 4;
    int ccol = lane & 15;
#pragma unroll
    for (int mf = 0; mf < 4; ++mf) {
#pragma unroll
        for (int j = 0; j < 4; ++j) {
            size_t r = m0 + wm + mf * 16 + crow + j;
            if (EPI == 1 && r >= (size_t)mvalid) continue;
#pragma unroll
            for (int nf = 0; nf < 4; ++nf) {
                size_t cidx = n0 + wn + nf * 16 + ccol;
                float v = acc[mf][nf][j] + bias[cidx];
                if (EPI == 0) {
                    float g = 0.5f * v * (1.f + erff(v * 0.70710678118654752f));
                    obf[r * N + cidx] = __float2bfloat16(g);
                } else {
                    of32[r * N + cidx] = v + res[r * N + cidx];
                }
            }
        }
    }
}

extern "C" void kernel_launch(void* const* d_in, const int* in_sizes, int n_in,
                              void* d_out, int out_size, void* d_ws, size_t ws_size,
                              hipStream_t stream) {
    (void)in_sizes; (void)n_in; (void)out_size;
    const float* x    = (const float*)d_in[0];
    const float* n1w  = (const float*)d_in[1];
    const float* n1b  = (const float*)d_in[2];
    const float* w1   = (const float*)d_in[3];
    const float* b1   = (const float*)d_in[4];
    const float* w2   = (const float*)d_in[5];
    const float* b2   = (const float*)d_in[6];
    const float* n2w  = (const float*)d_in[7];
    const float* n2b  = (const float*)d_in[8];
    const float* fc1w = (const float*)d_in[9];
    const float* fc1b = (const float*)d_in[10];
    const float* fc2w = (const float*)d_in[11];
    const float* fc2b = (const float*)d_in[12];
    float* out = (float*)d_out;

    // ---- tiered chunking: pick largest tb that fits ws_size (deterministic: ws_size fixed) ----
    const size_t fl_region1 = (size_t)MPAD * C_ / 2;            // 12,484,608
    const size_t fl_f1      = (size_t)2 * NPOS * C_;            // 12,718,080
    const size_t fl_tb1     = (size_t)MPAD * HID / 2;           // 49,938,432 (254 tiles)
    const size_t fl_tb2     = (size_t)127 * 128 * HID / 2;      // 24,969,216 (127 tiles)
    const size_t fl_wx      = 2712576 + 4096;                    // weights + tables + align slop
    const size_t need1 = (fl_region1 + fl_tb1 + fl_wx) * 4;
    const size_t need2 = (fl_region1 + ((fl_f1 > fl_tb2) ? fl_f1 : fl_tb2) + fl_wx) * 4;
    int nch = (ws_size >= need1) ? 1 : (ws_size >= need2) ? 2 : 4;
    size_t fl_tb = (nch == 1) ? fl_tb1 : (nch == 2) ? fl_tb2 : 0;
    size_t fl_big = (fl_f1 > fl_tb) ? fl_f1 : fl_tb;

    float* wsf = (float*)d_ws;
    size_t off = 0;
    auto alloc = [&](size_t nfloats) { float* p = wsf + off; off += (nfloats + 63) & ~(size_t)63; return p; };
    float* region1   = alloc(fl_region1);     // h1 (bf16) then h3 (bf16)
    float* regionBig = alloc(fl_big);         // f1r,f1i (f32) then tb (bf16 chunk)
    __hip_bfloat16* w1t = (__hip_bfloat16*)alloc((size_t)HID * C_ / 2);
    __hip_bfloat16* w2t = (__hip_bfloat16*)alloc((size_t)HID * C_ / 2);
    __hip_bfloat16* wbig = (__hip_bfloat16*)alloc((size_t)2 * NBK * 192 * 192 / 2);
    float* bbig = alloc(2 * NBK * 192);
    __hip_bfloat16* Tw  = (__hip_bfloat16*)alloc(192 * 96 / 2);
    __hip_bfloat16* Twf = (__hip_bfloat16*)alloc(96 * 192 / 2);
    __hip_bfloat16* Thf = (__hip_bfloat16*)alloc(192 * 192 / 2);
    __hip_bfloat16* Thi = (__hip_bfloat16*)alloc(192 * 192 / 2);

    __hip_bfloat16* h1b = (__hip_bfloat16*)region1;
    __hip_bfloat16* h3  = (__hip_bfloat16*)region1;
    float* f1r = regionBig;
    float* f1i = regionBig + (size_t)NPOS * C_;
    __hip_bfloat16* tb  = (__hip_bfloat16*)regionBig;

    init_tables_kernel<<<144, 256, 0, stream>>>(Tw, Twf, Thf, Thi);
    wprep_kernel<<<(2 * NBK * 192 * 192 + 255) / 256, 256, 0, stream>>>(w1, b1, w2, b2, wbig, bbig);
    transpose_cvt_kernel<<<dim3(HID / 32, C_ / 32), 256, 0, stream>>>(fc1w, w1t, C_, HID);
    transpose_cvt_kernel<<<dim3(C_ / 32, HID / 32), 256, 0, stream>>>(fc2w, w2t, HID, C_);

    ln_kernel<<<NTOK, 256, 0, stream>>>(x, n1w, n1b, h1b, NTOK);
    wfft_kernel<<<dim3(B_ * H_, 12), 256, 0, stream>>>(h1b, f1r, f1i, Twf);
    hdft_kernel<<<dim3(B_ * WFK, 12), 256, 0, stream>>>(f1r, f1i, Thf);
    blockmlp_mfma_kernel<<<dim3(130, NBK), 256, 0, stream>>>(f1r, f1i, wbig, bbig);
    hdft_kernel<<<dim3(B_ * WFK, 12), 256, 0, stream>>>(f1r, f1i, Thi);
    iwfft_kernel<<<dim3(B_ * H_, 12), 256, 0, stream>>>(f1r, f1i, h1b, x, out, Tw);
    // h1b, f1r/f1i dead from here; regions reused by h3 and tb
    ln_kernel<<<MPAD, 256, 0, stream>>>(out, n2w, n2b, h3, NTOK);

    int tilesArr[4], ntiles = 0;
    if (nch == 1)      { tilesArr[0] = 254; ntiles = 1; }
    else if (nch == 2) { tilesArr[0] = 127; tilesArr[1] = 127; ntiles = 2; }
    else               { tilesArr[0] = 64; tilesArr[1] = 64; tilesArr[2] = 64; tilesArr[3] = 62; ntiles = 4; }
    int baseT = 0;
    for (int c = 0; c < ntiles; ++c) {
        int tiles = tilesArr[c];
        size_t baseRow = (size_t)baseT * 128;
        gemm_kernel<0><<<tiles * (HID / 128), 256, 0, stream>>>(
            (const short*)(h3 + baseRow * C_), (const short*)w1t, fc1b,
            tb, nullptr, nullptr, HID, C_, 0, tiles, HID / 128);
        gemm_kernel<1><<<tiles * (C_ / 128), 256, 0, stream>>>(
            (const short*)tb, (const short*)w2t, fc2b,
            nullptr, out + baseRow * C_, out + baseRow * C_, C_, HID, NTOK - (int)baseRow, tiles, C_ / 128);
        baseT += tiles;
    }
}

// Round 7
// 806.834 us; speedup vs baseline: 1.7645x; 1.0042x over previous
//
#include <hip/hip_runtime.h>
#include <hip/hip_bf16.h>

#define B_    2
#define H_    90
#define W_    180
#define C_    768
#define WFK   46          // kept W-frequency modes (of 91)
#define NBK   8
#define BSK   96
#define HID   3072
#define NTOK  (B_*H_*W_)  // 32400
#define MPAD  32512       // 254*128
#define NPOS  (B_*H_*WFK) // 8280
#define LAM   0.01f

typedef __attribute__((ext_vector_type(8))) short short8;
typedef __attribute__((ext_vector_type(4))) float f32x4;

__device__ __forceinline__ float bf2f(short u) {
    union { unsigned int i; float f; } z;
    z.i = ((unsigned int)(unsigned short)u) << 16;
    return z.f;
}

__device__ __forceinline__ void gload_lds16(const void* g, void* l) {
    __builtin_amdgcn_global_load_lds((const __attribute__((address_space(1))) void*)g,
                                     (__attribute__((address_space(3))) void*)l, 16, 0, 0);
}

// ---------------- bf16 twiddle tables for all MFMA DFT stages ----------------
__global__ __launch_bounds__(256) void init_tables_kernel(__hip_bfloat16* Tw, __hip_bfloat16* Twf,
                                                          __hip_bfloat16* Thf, __hip_bfloat16* Thi) {
    int i = blockIdx.x * 256 + threadIdx.x;
    const float S = 0.00785674201318386f; // 1/sqrt(90*180)
    if (i < 192 * 96) {
        int w = i / 96, k = i % 96;
        int j = k >> 1, odd = k & 1;
        float val = 0.f;
        if (w < W_ && j < WFK) {
            float th = (float)((w * j) % W_) * (float)(6.283185307179586476925286766559 / 180.0);
            if (odd) val = (j == 0) ? 0.f : -2.f * S * sinf(th);
            else     val = (j == 0) ? S : 2.f * S * cosf(th);
        }
        Tw[i] = __float2bfloat16(val);
    }
    if (i < 96 * 192) {
        int r = i / 192, w = i % 192;
        int wf = r >> 1, odd = r & 1;
        float val = 0.f;
        if (w < W_ && wf < WFK) {
            float th = (float)((w * wf) % W_) * (float)(6.283185307179586476925286766559 / 180.0);
            val = odd ? -S * sinf(th) : S * cosf(th);
        }
        Twf[i] = __float2bfloat16(val);
    }
    if (i < 192 * 192) {
        int r = i / 192, j = i % 192;
        float vf = 0.f, vi = 0.f;
        if (r < 180 && j < 180) {
            int k = r >> 1, ro = r & 1, h = j >> 1, jo = j & 1;
            float th = (float)((k * h) % H_) * (float)(6.283185307179586476925286766559 / 90.0);
            float c = cosf(th), s = sinf(th);
            vf = ro ? (jo ? c : -s) : (jo ? s : c);   // fwd
            vi = ro ? (jo ? c : s) : (jo ? -s : c);   // inv
        }
        Thf[i] = __float2bfloat16(vf);
        Thi[i] = __float2bfloat16(vi);
    }
}

// ---------------- build expanded real weights for the block-MLP ----------------
__global__ __launch_bounds__(256) void wprep_kernel(
        const float* __restrict__ w1, const float* __restrict__ b1,
        const float* __restrict__ w2, const float* __restrict__ b2,
        __hip_bfloat16* __restrict__ wbig, float* __restrict__ bbig)
{
    int idx = blockIdx.x * 256 + threadIdx.x;
    if (idx < 2 * NBK * 192 * 192) {
        int k = idx % 192;
        int o = (idx / 192) % 192;
        int nb = (idx / (192 * 192)) % NBK;
        int L = idx / (192 * 192 * NBK);
        const float* w = L ? w2 : w1;
        const float* wr = w + (size_t)nb * BSK * BSK;
        const float* wi = w + (size_t)(NBK + nb) * BSK * BSK;
        int kk = k % BSK, oo = o % BSK;
        float val;
        if (o < BSK)  val = (k < BSK) ? wr[kk * BSK + oo] : -wi[kk * BSK + oo];
        else          val = (k < BSK) ? wi[kk * BSK + oo] :  wr[kk * BSK + oo];
        wbig[((size_t)(L * NBK + nb) * 192 + o) * 192 + k] = __float2bfloat16(val);
    }
    if (idx < 2 * NBK * 192) {
        int o = idx % 192;
        int nb = (idx / 192) % NBK;
        int L = idx / (192 * NBK);
        const float* b = L ? b2 : b1;
        bbig[idx] = (o < BSK) ? b[nb * BSK + o] : b[(NBK + nb) * BSK + (o - BSK)];
    }
}

// ---------------- LayerNorm: f32 in -> bf16 out, zero-pads rows >= ntok_valid ----------------
__global__ __launch_bounds__(256) void ln_kernel(const float* __restrict__ in,
        const float* __restrict__ w, const float* __restrict__ b,
        __hip_bfloat16* __restrict__ outb, int ntok_valid)
{
    int tok = blockIdx.x;
    int tid = threadIdx.x;
    size_t base = (size_t)tok * C_;
    if (tok >= ntok_valid) {
        __hip_bfloat16 z = __float2bfloat16(0.f);
        outb[base + tid] = z; outb[base + tid + 256] = z; outb[base + tid + 512] = z;
        return;
    }
    float x0 = in[base + tid], x1 = in[base + tid + 256], x2 = in[base + tid + 512];
    float s = x0 + x1 + x2;
    float q = x0*x0 + x1*x1 + x2*x2;
#pragma unroll
    for (int off = 32; off > 0; off >>= 1) { s += __shfl_down(s, off); q += __shfl_down(q, off); }
    __shared__ float rs[4], rq[4];
    int wid = tid >> 6, lane = tid & 63;
    if (lane == 0) { rs[wid] = s; rq[wid] = q; }
    __syncthreads();
    float ts = rs[0] + rs[1] + rs[2] + rs[3];
    float tq = rq[0] + rq[1] + rq[2] + rq[3];
    float mu = ts * (1.f / C_);
    float var = tq * (1.f / C_) - mu * mu;
    float rstd = rsqrtf(var + 1e-5f);
#pragma unroll
    for (int k = 0; k < 3; ++k) {
        int c = tid + k * 256;
        float xv = (k == 0 ? x0 : (k == 1 ? x1 : x2));
        outb[base + c] = __float2bfloat16((xv - mu) * rstd * w[c] + b[c]);
    }
}

// ---------------- forward rfft along W via MFMA: OUT[96][64] = Twf @ Xt^T ----------------
__global__ __launch_bounds__(256) void wfft_kernel(const __hip_bfloat16* __restrict__ h1,
        float* __restrict__ f1r, float* __restrict__ f1i,
        const __hip_bfloat16* __restrict__ Twf)
{
    __shared__ __hip_bfloat16 Xt[64 * 200];  // [c][w], w pad 180..191 = 0
    int slab = blockIdx.x;           // b*90+h
    int c0 = blockIdx.y * 64;
    int tid = threadIdx.x, wid = tid >> 6, lane = tid & 63;
    int lrow = lane & 15, lk8 = lane >> 4;
    const short* src = (const short*)h1 + (size_t)slab * W_ * C_ + c0;
    short* X = (short*)Xt;
    for (int i = tid; i < W_ * 8; i += 256) {
        int w = i >> 3, c8 = (i & 7) * 8;
        short8 v = *(const short8*)&src[(size_t)w * C_ + c8];
#pragma unroll
        for (int j = 0; j < 8; ++j) X[(c8 + j) * 200 + w] = v[j];
    }
    for (int z = tid; z < 64 * 12; z += 256) {
        int c = z / 12, w = 180 + z % 12;
        Xt[c * 200 + w] = __float2bfloat16(0.f);
    }
    __syncthreads();
    const short* Tp = (const short*)Twf;
    f32x4 zero = {0.f, 0.f, 0.f, 0.f};
    f32x4 acc[6];
#pragma unroll
    for (int m = 0; m < 6; ++m) acc[m] = zero;
#pragma unroll
    for (int ks = 0; ks < 6; ++ks) {
        short8 bf = *(const short8*)&X[(wid * 16 + lrow) * 200 + ks * 32 + lk8 * 8];
#pragma unroll
        for (int m = 0; m < 6; ++m) {
            short8 af = *(const short8*)&Tp[(m * 16 + lrow) * 192 + ks * 32 + lk8 * 8];
            acc[m] = __builtin_amdgcn_mfma_f32_16x16x32_bf16(af, bf, acc[m], 0, 0, 0);
        }
    }
    int crow = (lane >> 4) * 4, ccol = lane & 15;
#pragma unroll
    for (int m = 0; m < 6; ++m)
#pragma unroll
        for (int j = 0; j < 4; ++j) {
            int r = m * 16 + crow + j;
            int wf = r >> 1;
            if (wf >= WFK) continue;
            size_t o = ((size_t)slab * WFK + wf) * C_ + c0 + wid * 16 + ccol;
            if (r & 1) f1i[o] = acc[m][j];
            else       f1r[o] = acc[m][j];
        }
}

// ---------------- complex DFT along H via MFMA, IN-PLACE: OUT[192][64] = Th @ Xt^T ----------------
__global__ __launch_bounds__(256) void hdft_kernel(float* __restrict__ dr, float* __restrict__ di,
        const __hip_bfloat16* __restrict__ Th)
{
    __shared__ __hip_bfloat16 Xt[64 * 200];  // [c][j], j=2h re / 2h+1 im, pad 180..191 = 0
    int bwf = blockIdx.x;            // b*46+wf
    int b = bwf / WFK, wf = bwf % WFK;
    int c0 = blockIdx.y * 64;
    int tid = threadIdx.x, wid = tid >> 6, lane = tid & 63;
    int lrow = lane & 15, lk8 = lane >> 4;
    size_t base = ((size_t)(b * H_) * WFK + wf) * C_ + c0;
    short* X = (short*)Xt;
    for (int i = tid; i < H_ * 16; i += 256) {
        int h = i >> 4, cq = (i & 15) * 4;
        size_t a = base + (size_t)h * WFK * C_ + cq;
        float4 re = *(const float4*)&dr[a];
        float4 im = *(const float4*)&di[a];
        X[(cq + 0) * 200 + 2 * h]     = (short)__bfloat16_as_ushort(__float2bfloat16(re.x));
        X[(cq + 0) * 200 + 2 * h + 1] = (short)__bfloat16_as_ushort(__float2bfloat16(im.x));
        X[(cq + 1) * 200 + 2 * h]     = (short)__bfloat16_as_ushort(__float2bfloat16(re.y));
        X[(cq + 1) * 200 + 2 * h + 1] = (short)__bfloat16_as_ushort(__float2bfloat16(im.y));
        X[(cq + 2) * 200 + 2 * h]     = (short)__bfloat16_as_ushort(__float2bfloat16(re.z));
        X[(cq + 2) * 200 + 2 * h + 1] = (short)__bfloat16_as_ushort(__float2bfloat16(im.z));
        X[(cq + 3) * 200 + 2 * h]     = (short)__bfloat16_as_ushort(__float2bfloat16(re.w));
        X[(cq + 3) * 200 + 2 * h + 1] = (short)__bfloat16_as_ushort(__float2bfloat16(im.w));
    }
    for (int z = tid; z < 64 * 12; z += 256) {
        int c = z / 12, j = 180 + z % 12;
        Xt[c * 200 + j] = __float2bfloat16(0.f);
    }
    __syncthreads();
    const short* Tp = (const short*)Th;
    f32x4 zero = {0.f, 0.f, 0.f, 0.f};
    f32x4 acc[3][4];
#pragma unroll
    for (int m = 0; m < 3; ++m)
#pragma unroll
        for (int n = 0; n < 4; ++n) acc[m][n] = zero;
#pragma unroll
    for (int ks = 0; ks < 6; ++ks) {
        short8 af[3], bf[4];
#pragma unroll
        for (int m = 0; m < 3; ++m)
            af[m] = *(const short8*)&Tp[(wid * 48 + m * 16 + lrow) * 192 + ks * 32 + lk8 * 8];
#pragma unroll
        for (int n = 0; n < 4; ++n)
            bf[n] = *(const short8*)&X[(n * 16 + lrow) * 200 + ks * 32 + lk8 * 8];
#pragma unroll
        for (int m = 0; m < 3; ++m)
#pragma unroll
            for (int n = 0; n < 4; ++n)
                acc[m][n] = __builtin_amdgcn_mfma_f32_16x16x32_bf16(af[m], bf[n], acc[m][n], 0, 0, 0);
    }
    int crow = (lane >> 4) * 4, ccol = lane & 15;
#pragma unroll
    for (int m = 0; m < 3; ++m)
#pragma unroll
        for (int j = 0; j < 4; ++j) {
            int r = wid * 48 + m * 16 + crow + j;
            int kh = r >> 1;
            if (kh >= H_) continue;
#pragma unroll
            for (int n = 0; n < 4; ++n) {
                size_t o = base + (size_t)kh * WFK * C_ + n * 16 + ccol;
                if (r & 1) di[o] = acc[m][n][j];
                else       dr[o] = acc[m][n][j];
            }
        }
}

// ---------------- block-diagonal complex 2-layer MLP + softshrink, IN-PLACE, via MFMA ----------------
__global__ __launch_bounds__(256) void blockmlp_mfma_kernel(
        float* __restrict__ vr, float* __restrict__ vi,
        const __hip_bfloat16* __restrict__ wbig, const float* __restrict__ bbig)
{
    __shared__ __hip_bfloat16 X1[64 * 200];
    __shared__ __hip_bfloat16 X2[64 * 200];
    int chunk = blockIdx.x;          // 130 chunks of 64 positions
    int nb = blockIdx.y;
    int tid = threadIdx.x, wid = tid >> 6, lane = tid & 63;
    int p0 = chunk * 64;
    for (int i = tid; i < 64 * 48; i += 256) {
        int p = i / 48, q = i % 48;
        int pg = p0 + p;
        int c4 = (q % 24) * 4;
        bool isr = q < 24;
        float4 v = make_float4(0, 0, 0, 0);
        if (pg < NPOS) {
            const float* src = isr ? vr : vi;
            v = *(const float4*)&src[(size_t)pg * C_ + nb * BSK + c4];
        }
        __hip_bfloat16* d = &X1[p * 200 + (isr ? 0 : 96) + c4];
        d[0] = __float2bfloat16(v.x); d[1] = __float2bfloat16(v.y);
        d[2] = __float2bfloat16(v.z); d[3] = __float2bfloat16(v.w);
    }
    __syncthreads();
    int n0 = wid * 48;
    int lrow = lane & 15, lk8 = lane >> 4;
    int crow = (lane >> 4) * 4, ccol = lane & 15;
    const short* W1 = (const short*)(wbig + (size_t)nb * 192 * 192);
    const short* W2 = (const short*)(wbig + (size_t)(NBK + nb) * 192 * 192);
    const float* bb1 = bbig + nb * 192;
    const float* bb2 = bbig + (NBK + nb) * 192;
    f32x4 zero = {0.f, 0.f, 0.f, 0.f};
    {
        f32x4 acc[4][3];
#pragma unroll
        for (int m = 0; m < 4; ++m)
#pragma unroll
            for (int n = 0; n < 3; ++n) acc[m][n] = zero;
#pragma unroll
        for (int k0 = 0; k0 < 192; k0 += 32) {
            short8 af[4], bf[3];
#pragma unroll
            for (int m = 0; m < 4; ++m)
                af[m] = *(const short8*)&X1[(m * 16 + lrow) * 200 + k0 + lk8 * 8];
#pragma unroll
            for (int n = 0; n < 3; ++n)
                bf[n] = *(const short8*)&W1[(size_t)(n0 + n * 16 + lrow) * 192 + k0 + lk8 * 8];
#pragma unroll
            for (int m = 0; m < 4; ++m)
#pragma unroll
                for (int n = 0; n < 3; ++n)
                    acc[m][n] = __builtin_amdgcn_mfma_f32_16x16x32_bf16(af[m], bf[n], acc[m][n], 0, 0, 0);
        }
        __syncthreads();
#pragma unroll
        for (int m = 0; m < 4; ++m)
#pragma unroll
            for (int j = 0; j < 4; ++j) {
                int row = m * 16 + crow + j;
#pragma unroll
                for (int n = 0; n < 3; ++n) {
                    int col = n0 + n * 16 + ccol;
                    float v = acc[m][n][j] + bb1[col];
                    X2[row * 200 + col] = __float2bfloat16(fmaxf(v, 0.f));
                }
            }
    }
    __syncthreads();
    {
        f32x4 acc[4][3];
#pragma unroll
        for (int m = 0; m < 4; ++m)
#pragma unroll
            for (int n = 0; n < 3; ++n) acc[m][n] = zero;
#pragma unroll
        for (int k0 = 0; k0 < 192; k0 += 32) {
            short8 af[4], bf[3];
#pragma unroll
            for (int m = 0; m < 4; ++m)
                af[m] = *(const short8*)&X2[(m * 16 + lrow) * 200 + k0 + lk8 * 8];
#pragma unroll
            for (int n = 0; n < 3; ++n)
                bf[n] = *(const short8*)&W2[(size_t)(n0 + n * 16 + lrow) * 192 + k0 + lk8 * 8];
#pragma unroll
            for (int m = 0; m < 4; ++m)
#pragma unroll
                for (int n = 0; n < 3; ++n)
                    acc[m][n] = __builtin_amdgcn_mfma_f32_16x16x32_bf16(af[m], bf[n], acc[m][n], 0, 0, 0);
        }
#pragma unroll
        for (int m = 0; m < 4; ++m)
#pragma unroll
            for (int j = 0; j < 4; ++j) {
                int row = m * 16 + crow + j;
                int pg = p0 + row;
                if (pg >= NPOS) continue;
#pragma unroll
                for (int n = 0; n < 3; ++n) {
                    int col = n0 + n * 16 + ccol;
                    float v = acc[m][n][j] + bb2[col];
                    v = v > LAM ? v - LAM : (v < -LAM ? v + LAM : 0.f);
                    if (col < BSK) vr[(size_t)pg * C_ + nb * BSK + col] = v;
                    else           vi[(size_t)pg * C_ + nb * BSK + col - BSK] = v;
                }
            }
    }
}

// ---------------- inverse rfft along W via MFMA: OUT[180][64] = Tw[192][96] @ Yt^T, + residuals ----------------
__global__ __launch_bounds__(256) void iwfft_kernel(
        const float* __restrict__ inr, const float* __restrict__ ini,
        const __hip_bfloat16* __restrict__ h1, const float* __restrict__ x,
        float* __restrict__ out, const __hip_bfloat16* __restrict__ Tw)
{
    __shared__ __hip_bfloat16 Yt[64 * 104];   // [channel][k], k: 2j=re,2j+1=im, pad 92..95
    int slab = blockIdx.x;        // 180
    int c0 = blockIdx.y * 64;     // 12 groups
    int tid = threadIdx.x, wid = tid >> 6, lane = tid & 63;
    int lrow = lane & 15, lk8 = lane >> 4;
    size_t sb = (size_t)slab * WFK * C_ + c0;
    for (int i = tid; i < WFK * 16; i += 256) {
        int wf = i >> 4, cq = (i & 15) * 4;
        size_t a = sb + (size_t)wf * C_ + cq;
        float4 vrv = *(const float4*)&inr[a];
        float4 viv = *(const float4*)&ini[a];
        Yt[(cq + 0) * 104 + 2 * wf]     = __float2bfloat16(vrv.x);
        Yt[(cq + 0) * 104 + 2 * wf + 1] = __float2bfloat16(viv.x);
        Yt[(cq + 1) * 104 + 2 * wf]     = __float2bfloat16(vrv.y);
        Yt[(cq + 1) * 104 + 2 * wf + 1] = __float2bfloat16(viv.y);
        Yt[(cq + 2) * 104 + 2 * wf]     = __float2bfloat16(vrv.z);
        Yt[(cq + 2) * 104 + 2 * wf + 1] = __float2bfloat16(viv.z);
        Yt[(cq + 3) * 104 + 2 * wf]     = __float2bfloat16(vrv.w);
        Yt[(cq + 3) * 104 + 2 * wf + 1] = __float2bfloat16(viv.w);
    }
    {
        int c = tid >> 2, kk = 92 + (tid & 3);
        Yt[c * 104 + kk] = __float2bfloat16(0.f);
    }
    __syncthreads();
    const short* Tp = (const short*)Tw;
    f32x4 zero = {0.f, 0.f, 0.f, 0.f};
    f32x4 acc[3][4];
#pragma unroll
    for (int m = 0; m < 3; ++m)
#pragma unroll
        for (int n = 0; n < 4; ++n) acc[m][n] = zero;
#pragma unroll
    for (int ks = 0; ks < 3; ++ks) {
        short8 af[3], bf[4];
#pragma unroll
        for (int m = 0; m < 3; ++m)
            af[m] = *(const short8*)&Tp[(wid * 48 + m * 16 + lrow) * 96 + ks * 32 + lk8 * 8];
#pragma unroll
        for (int n = 0; n < 4; ++n)
            bf[n] = *(const short8*)&Yt[(n * 16 + lrow) * 104 + ks * 32 + lk8 * 8];
#pragma unroll
        for (int m = 0; m < 3; ++m)
#pragma unroll
            for (int n = 0; n < 4; ++n)
                acc[m][n] = __builtin_amdgcn_mfma_f32_16x16x32_bf16(af[m], bf[n], acc[m][n], 0, 0, 0);
    }
    int crow = (lane >> 4) * 4, ccol = lane & 15;
    const short* hp = (const short*)h1;
#pragma unroll
    for (int m = 0; m < 3; ++m)
#pragma unroll
        for (int j = 0; j < 4; ++j) {
            int w = wid * 48 + m * 16 + crow + j;
            if (w >= W_) continue;
            size_t o = ((size_t)slab * W_ + w) * C_ + c0;
#pragma unroll
            for (int n = 0; n < 4; ++n) {
                int col = n * 16 + ccol;
                out[o + col] = acc[m][n][j] + bf2f(hp[o + col]) + x[o + col];
            }
        }
}

// ---------------- transpose + f32->bf16 (weights) ----------------
__global__ __launch_bounds__(256) void transpose_cvt_kernel(const float* __restrict__ Wm,
        __hip_bfloat16* __restrict__ Wt, int R, int Ccol)
{
    __shared__ float tile[32][33];
    int c0 = blockIdx.x * 32, r0 = blockIdx.y * 32;
    int tid = threadIdx.x;
    int tc = tid & 31, tr = tid >> 5;
#pragma unroll
    for (int k = 0; k < 4; ++k)
        tile[tr + k * 8][tc] = Wm[(size_t)(r0 + tr + k * 8) * Ccol + c0 + tc];
    __syncthreads();
    int rr = tid & 31, cc = tid >> 5;
#pragma unroll
    for (int k = 0; k < 4; ++k)
        Wt[(size_t)(c0 + cc + k * 8) * R + r0 + rr] = __float2bfloat16(tile[rr][cc + k * 8]);
}

// ---------------- bf16 MFMA GEMM (m97 structure + supertile remap + T2 XOR swizzle) ----------------
// LDS[row][slot] = global[row][slot ^ s(row)], s(row)=(row>>1)&3, slot = 16B unit of the 64B row.
// Dest stays linear (global_load_lds requirement); source address carries the inverse swizzle;
// ds_read applies the same XOR -> banks spread 2-way (free) instead of 8-way.
template<int EPI>
__global__ __launch_bounds__(256) void gemm_kernel(
        const short* __restrict__ A, const short* __restrict__ Bt,
        const float* __restrict__ bias,
        __hip_bfloat16* __restrict__ obf, float* __restrict__ of32,
        const float* __restrict__ res, int N, int K, int mvalid, int MT, int NT)
{
    __shared__ short As[128 * 32];
    __shared__ short Bs[128 * 32];
    // ---- supertile remap (bijective incl. remainder supertile) ----
    int id = blockIdx.x;
    const int SUPER = 16;
    int per = SUPER * NT;
    int sidx = id / per;
    int offs = id % per;
    int rows = MT - sidx * SUPER; if (rows > SUPER) rows = SUPER;
    int mt = sidx * SUPER + offs % rows;
    int nt = offs / rows;
    size_t m0 = (size_t)mt * 128, n0 = (size_t)nt * 128;

    int tid = threadIdx.x;
    int wid = tid >> 6, lane = tid & 63;
    int wm = (wid >> 1) * 64, wn = (wid & 1) * 64;
    int lrow = lane & 15, lk8 = lane >> 4;
    f32x4 zero = {0.f, 0.f, 0.f, 0.f};
    f32x4 acc[4][4];
#pragma unroll
    for (int i = 0; i < 4; ++i)
#pragma unroll
        for (int j = 0; j < 4; ++j) acc[i][j] = zero;
    int srow = tid >> 2;                                  // 0..63 (row within half-tile)
    int scol = ((tid & 3) ^ ((srow >> 1) & 3)) * 8;       // inverse-swizzled source k-octet
    const short* Ag = A + (m0 + srow) * K + scol;
    const short* Bg = Bt + (n0 + srow) * K + scol;
    char* Asb = (char*)As + (size_t)tid * 16;
    char* Bsb = (char*)Bs + (size_t)tid * 16;
    int rswz = (lk8 ^ ((lrow >> 1) & 3)) * 8;             // swizzled read slot (s(row)=(lrow>>1)&3)
    for (int k0 = 0; k0 < K; k0 += 32) {
        __syncthreads();            // prior reads done before overwrite
        gload_lds16(Ag + k0, Asb);
        gload_lds16(Ag + k0 + (size_t)64 * K, Asb + 4096);
        gload_lds16(Bg + k0, Bsb);
        gload_lds16(Bg + k0 + (size_t)64 * K, Bsb + 4096);
        __syncthreads();            // implicit vmcnt(0) drain
        short8 af[4], bfr[4];
#pragma unroll
        for (int mf = 0; mf < 4; ++mf) af[mf] = *(const short8*)&As[(wm + mf * 16 + lrow) * 32 + rswz];
#pragma unroll
        for (int nf = 0; nf < 4; ++nf) bfr[nf] = *(const short8*)&Bs[(wn + nf * 16 + lrow) * 32 + rswz];
#pragma unroll
        for (int mf = 0; mf < 4; ++mf)
#pragma unroll
            for (int nf = 0; nf < 4; ++nf)
                acc[mf][nf] = __builtin_amdgcn_mfma_f32_16x16x32_bf16(af[mf], bfr[nf], acc[mf][nf], 0, 0, 0);
    }
    int crow = (lane >> 4) * 4;
    int ccol = lane & 15;
#pragma unroll
    for (int mf = 0; mf < 4; ++mf) {
#pragma unroll
        for (int j = 0; j < 4; ++j) {
            size_t r = m0 + wm + mf * 16 + crow + j;
            if (EPI == 1 && r >= (size_t)mvalid) continue;
#pragma unroll
            for (int nf = 0; nf < 4; ++nf) {
                size_t cidx = n0 + wn + nf * 16 + ccol;
                float v = acc[mf][nf][j] + bias[cidx];
                if (EPI == 0) {
                    float g = 0.5f * v * (1.f + erff(v * 0.70710678118654752f));
                    obf[r * N + cidx] = __float2bfloat16(g);
                } else {
                    of32[r * N + cidx] = v + res[r * N + cidx];
                }
            }
        }
    }
}

extern "C" void kernel_launch(void* const* d_in, const int* in_sizes, int n_in,
                              void* d_out, int out_size, void* d_ws, size_t ws_size,
                              hipStream_t stream) {
    (void)in_sizes; (void)n_in; (void)out_size;
    const float* x    = (const float*)d_in[0];
    const float* n1w  = (const float*)d_in[1];
    const float* n1b  = (const float*)d_in[2];
    const float* w1   = (const float*)d_in[3];
    const float* b1   = (const float*)d_in[4];
    const float* w2   = (const float*)d_in[5];
    const float* b2   = (const float*)d_in[6];
    const float* n2w  = (const float*)d_in[7];
    const float* n2b  = (const float*)d_in[8];
    const float* fc1w = (const float*)d_in[9];
    const float* fc1b = (const float*)d_in[10];
    const float* fc2w = (const float*)d_in[11];
    const float* fc2b = (const float*)d_in[12];
    float* out = (float*)d_out;

    // ---- tiered chunking: pick largest tb that fits ws_size (deterministic: ws_size fixed) ----
    const size_t fl_region1 = (size_t)MPAD * C_ / 2;            // 12,484,608
    const size_t fl_f1      = (size_t)2 * NPOS * C_;            // 12,718,080
    const size_t fl_tb1     = (size_t)MPAD * HID / 2;           // 49,938,432 (254 tiles)
    const size_t fl_tb2     = (size_t)127 * 128 * HID / 2;      // 24,969,216 (127 tiles)
    const size_t fl_wx      = 2712576 + 4096;                    // weights + tables + align slop
    const size_t need1 = (fl_region1 + fl_tb1 + fl_wx) * 4;
    const size_t need2 = (fl_region1 + ((fl_f1 > fl_tb2) ? fl_f1 : fl_tb2) + fl_wx) * 4;
    int nch = (ws_size >= need1) ? 1 : (ws_size >= need2) ? 2 : 4;
    size_t fl_tb = (nch == 1) ? fl_tb1 : (nch == 2) ? fl_tb2 : 0;
    size_t fl_big = (fl_f1 > fl_tb) ? fl_f1 : fl_tb;

    float* wsf = (float*)d_ws;
    size_t off = 0;
    auto alloc = [&](size_t nfloats) { float* p = wsf + off; off += (nfloats + 63) & ~(size_t)63; return p; };
    float* region1   = alloc(fl_region1);     // h1 (bf16) then h3 (bf16)
    float* regionBig = alloc(fl_big);         // f1r,f1i (f32) then tb (bf16 chunk)
    __hip_bfloat16* w1t = (__hip_bfloat16*)alloc((size_t)HID * C_ / 2);
    __hip_bfloat16* w2t = (__hip_bfloat16*)alloc((size_t)HID * C_ / 2);
    __hip_bfloat16* wbig = (__hip_bfloat16*)alloc((size_t)2 * NBK * 192 * 192 / 2);
    float* bbig = alloc(2 * NBK * 192);
    __hip_bfloat16* Tw  = (__hip_bfloat16*)alloc(192 * 96 / 2);
    __hip_bfloat16* Twf = (__hip_bfloat16*)alloc(96 * 192 / 2);
    __hip_bfloat16* Thf = (__hip_bfloat16*)alloc(192 * 192 / 2);
    __hip_bfloat16* Thi = (__hip_bfloat16*)alloc(192 * 192 / 2);

    __hip_bfloat16* h1b = (__hip_bfloat16*)region1;
    __hip_bfloat16* h3  = (__hip_bfloat16*)region1;
    float* f1r = regionBig;
    float* f1i = regionBig + (size_t)NPOS * C_;
    __hip_bfloat16* tb  = (__hip_bfloat16*)regionBig;

    init_tables_kernel<<<144, 256, 0, stream>>>(Tw, Twf, Thf, Thi);
    wprep_kernel<<<(2 * NBK * 192 * 192 + 255) / 256, 256, 0, stream>>>(w1, b1, w2, b2, wbig, bbig);
    transpose_cvt_kernel<<<dim3(HID / 32, C_ / 32), 256, 0, stream>>>(fc1w, w1t, C_, HID);
    transpose_cvt_kernel<<<dim3(C_ / 32, HID / 32), 256, 0, stream>>>(fc2w, w2t, HID, C_);

    ln_kernel<<<NTOK, 256, 0, stream>>>(x, n1w, n1b, h1b, NTOK);
    wfft_kernel<<<dim3(B_ * H_, 12), 256, 0, stream>>>(h1b, f1r, f1i, Twf);
    hdft_kernel<<<dim3(B_ * WFK, 12), 256, 0, stream>>>(f1r, f1i, Thf);
    blockmlp_mfma_kernel<<<dim3(130, NBK), 256, 0, stream>>>(f1r, f1i, wbig, bbig);
    hdft_kernel<<<dim3(B_ * WFK, 12), 256, 0, stream>>>(f1r, f1i, Thi);
    iwfft_kernel<<<dim3(B_ * H_, 12), 256, 0, stream>>>(f1r, f1i, h1b, x, out, Tw);
    // h1b, f1r/f1i dead from here; regions reused by h3 and tb
    ln_kernel<<<MPAD, 256, 0, stream>>>(out, n2w, n2b, h3, NTOK);

    int tilesArr[4], ntiles = 0;
    if (nch == 1)      { tilesArr[0] = 254; ntiles = 1; }
    else if (nch == 2) { tilesArr[0] = 127; tilesArr[1] = 127; ntiles = 2; }
    else               { tilesArr[0] = 64; tilesArr[1] = 64; tilesArr[2] = 64; tilesArr[3] = 62; ntiles = 4; }
    int baseT = 0;
    for (int c = 0; c < ntiles; ++c) {
        int tiles = tilesArr[c];
        size_t baseRow = (size_t)baseT * 128;
        gemm_kernel<0><<<tiles * (HID / 128), 256, 0, stream>>>(
            (const short*)(h3 + baseRow * C_), (const short*)w1t, fc1b,
            tb, nullptr, nullptr, HID, C_, 0, tiles, HID / 128);
        gemm_kernel<1><<<tiles * (C_ / 128), 256, 0, stream>>>(
            (const short*)tb, (const short*)w2t, fc2b,
            nullptr, out + baseRow * C_, out + baseRow * C_, C_, HID, NTOK - (int)baseRow, tiles, C_ / 128);
        baseT += tiles;
    }
}

// Round 8
// 773.467 us; speedup vs baseline: 1.8406x; 1.0431x over previous
//
#include <hip/hip_runtime.h>
#include <hip/hip_bf16.h>

#define B_    2
#define H_    90
#define W_    180
#define C_    768
#define WFK   46          // kept W-frequency modes (of 91)
#define NBK   8
#define BSK   96
#define HID   3072
#define NTOK  (B_*H_*W_)  // 32400
#define MPAD  32512       // 254*128
#define NPOS  (B_*H_*WFK) // 8280
#define LAM   0.01f

typedef __attribute__((ext_vector_type(8))) short short8;
typedef __attribute__((ext_vector_type(4))) float f32x4;

__device__ __forceinline__ float bf2f(short u) {
    union { unsigned int i; float f; } z;
    z.i = ((unsigned int)(unsigned short)u) << 16;
    return z.f;
}

__device__ __forceinline__ void gload_lds16(const void* g, void* l) {
    __builtin_amdgcn_global_load_lds((const __attribute__((address_space(1))) void*)g,
                                     (__attribute__((address_space(3))) void*)l, 16, 0, 0);
}

// branch-free tanh-form GELU (max abs err ~1e-3, << bf16 rounding here)
__device__ __forceinline__ float gelu_f(float v) {
    float u = v * (0.7978845608028654f + 0.03567740813636141f * v * v);
    float au = fabsf(u);
    float e = __expf(2.f * au);              // inf-safe: 2/(inf+1)=0
    float t = 1.f - 2.f / (e + 1.f);
    t = copysignf(t, u);
    return 0.5f * v * (1.f + t);
}

// ---------------- bf16 twiddle tables for all MFMA DFT stages ----------------
__global__ __launch_bounds__(256) void init_tables_kernel(__hip_bfloat16* Tw, __hip_bfloat16* Twf,
                                                          __hip_bfloat16* Thf, __hip_bfloat16* Thi) {
    int i = blockIdx.x * 256 + threadIdx.x;
    const float S = 0.00785674201318386f; // 1/sqrt(90*180)
    if (i < 192 * 96) {
        int w = i / 96, k = i % 96;
        int j = k >> 1, odd = k & 1;
        float val = 0.f;
        if (w < W_ && j < WFK) {
            float th = (float)((w * j) % W_) * (float)(6.283185307179586476925286766559 / 180.0);
            if (odd) val = (j == 0) ? 0.f : -2.f * S * sinf(th);
            else     val = (j == 0) ? S : 2.f * S * cosf(th);
        }
        Tw[i] = __float2bfloat16(val);
    }
    if (i < 96 * 192) {
        int r = i / 192, w = i % 192;
        int wf = r >> 1, odd = r & 1;
        float val = 0.f;
        if (w < W_ && wf < WFK) {
            float th = (float)((w * wf) % W_) * (float)(6.283185307179586476925286766559 / 180.0);
            val = odd ? -S * sinf(th) : S * cosf(th);
        }
        Twf[i] = __float2bfloat16(val);
    }
    if (i < 192 * 192) {
        int r = i / 192, j = i % 192;
        float vf = 0.f, vi = 0.f;
        if (r < 180 && j < 180) {
            int k = r >> 1, ro = r & 1, h = j >> 1, jo = j & 1;
            float th = (float)((k * h) % H_) * (float)(6.283185307179586476925286766559 / 90.0);
            float c = cosf(th), s = sinf(th);
            vf = ro ? (jo ? c : -s) : (jo ? s : c);   // fwd
            vi = ro ? (jo ? c : s) : (jo ? -s : c);   // inv
        }
        Thf[i] = __float2bfloat16(vf);
        Thi[i] = __float2bfloat16(vi);
    }
}

// ---------------- build expanded real weights for the block-MLP ----------------
__global__ __launch_bounds__(256) void wprep_kernel(
        const float* __restrict__ w1, const float* __restrict__ b1,
        const float* __restrict__ w2, const float* __restrict__ b2,
        __hip_bfloat16* __restrict__ wbig, float* __restrict__ bbig)
{
    int idx = blockIdx.x * 256 + threadIdx.x;
    if (idx < 2 * NBK * 192 * 192) {
        int k = idx % 192;
        int o = (idx / 192) % 192;
        int nb = (idx / (192 * 192)) % NBK;
        int L = idx / (192 * 192 * NBK);
        const float* w = L ? w2 : w1;
        const float* wr = w + (size_t)nb * BSK * BSK;
        const float* wi = w + (size_t)(NBK + nb) * BSK * BSK;
        int kk = k % BSK, oo = o % BSK;
        float val;
        if (o < BSK)  val = (k < BSK) ? wr[kk * BSK + oo] : -wi[kk * BSK + oo];
        else          val = (k < BSK) ? wi[kk * BSK + oo] :  wr[kk * BSK + oo];
        wbig[((size_t)(L * NBK + nb) * 192 + o) * 192 + k] = __float2bfloat16(val);
    }
    if (idx < 2 * NBK * 192) {
        int o = idx % 192;
        int nb = (idx / 192) % NBK;
        int L = idx / (192 * NBK);
        const float* b = L ? b2 : b1;
        bbig[idx] = (o < BSK) ? b[nb * BSK + o] : b[(NBK + nb) * BSK + (o - BSK)];
    }
}

// ---------------- LayerNorm: f32 in -> bf16 out, zero-pads rows >= ntok_valid ----------------
__global__ __launch_bounds__(256) void ln_kernel(const float* __restrict__ in,
        const float* __restrict__ w, const float* __restrict__ b,
        __hip_bfloat16* __restrict__ outb, int ntok_valid)
{
    int tok = blockIdx.x;
    int tid = threadIdx.x;
    size_t base = (size_t)tok * C_;
    if (tok >= ntok_valid) {
        __hip_bfloat16 z = __float2bfloat16(0.f);
        outb[base + tid] = z; outb[base + tid + 256] = z; outb[base + tid + 512] = z;
        return;
    }
    float x0 = in[base + tid], x1 = in[base + tid + 256], x2 = in[base + tid + 512];
    float s = x0 + x1 + x2;
    float q = x0*x0 + x1*x1 + x2*x2;
#pragma unroll
    for (int off = 32; off > 0; off >>= 1) { s += __shfl_down(s, off); q += __shfl_down(q, off); }
    __shared__ float rs[4], rq[4];
    int wid = tid >> 6, lane = tid & 63;
    if (lane == 0) { rs[wid] = s; rq[wid] = q; }
    __syncthreads();
    float ts = rs[0] + rs[1] + rs[2] + rs[3];
    float tq = rq[0] + rq[1] + rq[2] + rq[3];
    float mu = ts * (1.f / C_);
    float var = tq * (1.f / C_) - mu * mu;
    float rstd = rsqrtf(var + 1e-5f);
#pragma unroll
    for (int k = 0; k < 3; ++k) {
        int c = tid + k * 256;
        float xv = (k == 0 ? x0 : (k == 1 ? x1 : x2));
        outb[base + c] = __float2bfloat16((xv - mu) * rstd * w[c] + b[c]);
    }
}

// ---------------- forward rfft along W via MFMA: OUT[96][64] = Twf @ Xt^T ----------------
__global__ __launch_bounds__(256) void wfft_kernel(const __hip_bfloat16* __restrict__ h1,
        float* __restrict__ f1r, float* __restrict__ f1i,
        const __hip_bfloat16* __restrict__ Twf)
{
    __shared__ __hip_bfloat16 Xt[64 * 200];  // [c][w], w pad 180..191 = 0
    int slab = blockIdx.x;           // b*90+h
    int c0 = blockIdx.y * 64;
    int tid = threadIdx.x, wid = tid >> 6, lane = tid & 63;
    int lrow = lane & 15, lk8 = lane >> 4;
    const short* src = (const short*)h1 + (size_t)slab * W_ * C_ + c0;
    short* X = (short*)Xt;
    for (int i = tid; i < W_ * 8; i += 256) {
        int w = i >> 3, c8 = (i & 7) * 8;
        short8 v = *(const short8*)&src[(size_t)w * C_ + c8];
#pragma unroll
        for (int j = 0; j < 8; ++j) X[(c8 + j) * 200 + w] = v[j];
    }
    for (int z = tid; z < 64 * 12; z += 256) {
        int c = z / 12, w = 180 + z % 12;
        Xt[c * 200 + w] = __float2bfloat16(0.f);
    }
    __syncthreads();
    const short* Tp = (const short*)Twf;
    f32x4 zero = {0.f, 0.f, 0.f, 0.f};
    f32x4 acc[6];
#pragma unroll
    for (int m = 0; m < 6; ++m) acc[m] = zero;
#pragma unroll
    for (int ks = 0; ks < 6; ++ks) {
        short8 bf = *(const short8*)&X[(wid * 16 + lrow) * 200 + ks * 32 + lk8 * 8];
#pragma unroll
        for (int m = 0; m < 6; ++m) {
            short8 af = *(const short8*)&Tp[(m * 16 + lrow) * 192 + ks * 32 + lk8 * 8];
            acc[m] = __builtin_amdgcn_mfma_f32_16x16x32_bf16(af, bf, acc[m], 0, 0, 0);
        }
    }
    int crow = (lane >> 4) * 4, ccol = lane & 15;
#pragma unroll
    for (int m = 0; m < 6; ++m)
#pragma unroll
        for (int j = 0; j < 4; ++j) {
            int r = m * 16 + crow + j;
            int wf = r >> 1;
            if (wf >= WFK) continue;
            size_t o = ((size_t)slab * WFK + wf) * C_ + c0 + wid * 16 + ccol;
            if (r & 1) f1i[o] = acc[m][j];
            else       f1r[o] = acc[m][j];
        }
}

// ---------------- complex DFT along H via MFMA, IN-PLACE: OUT[192][64] = Th @ Xt^T ----------------
__global__ __launch_bounds__(256) void hdft_kernel(float* __restrict__ dr, float* __restrict__ di,
        const __hip_bfloat16* __restrict__ Th)
{
    __shared__ __hip_bfloat16 Xt[64 * 200];  // [c][j], j=2h re / 2h+1 im, pad 180..191 = 0
    int bwf = blockIdx.x;            // b*46+wf
    int b = bwf / WFK, wf = bwf % WFK;
    int c0 = blockIdx.y * 64;
    int tid = threadIdx.x, wid = tid >> 6, lane = tid & 63;
    int lrow = lane & 15, lk8 = lane >> 4;
    size_t base = ((size_t)(b * H_) * WFK + wf) * C_ + c0;
    short* X = (short*)Xt;
    for (int i = tid; i < H_ * 16; i += 256) {
        int h = i >> 4, cq = (i & 15) * 4;
        size_t a = base + (size_t)h * WFK * C_ + cq;
        float4 re = *(const float4*)&dr[a];
        float4 im = *(const float4*)&di[a];
        X[(cq + 0) * 200 + 2 * h]     = (short)__bfloat16_as_ushort(__float2bfloat16(re.x));
        X[(cq + 0) * 200 + 2 * h + 1] = (short)__bfloat16_as_ushort(__float2bfloat16(im.x));
        X[(cq + 1) * 200 + 2 * h]     = (short)__bfloat16_as_ushort(__float2bfloat16(re.y));
        X[(cq + 1) * 200 + 2 * h + 1] = (short)__bfloat16_as_ushort(__float2bfloat16(im.y));
        X[(cq + 2) * 200 + 2 * h]     = (short)__bfloat16_as_ushort(__float2bfloat16(re.z));
        X[(cq + 2) * 200 + 2 * h + 1] = (short)__bfloat16_as_ushort(__float2bfloat16(im.z));
        X[(cq + 3) * 200 + 2 * h]     = (short)__bfloat16_as_ushort(__float2bfloat16(re.w));
        X[(cq + 3) * 200 + 2 * h + 1] = (short)__bfloat16_as_ushort(__float2bfloat16(im.w));
    }
    for (int z = tid; z < 64 * 12; z += 256) {
        int c = z / 12, j = 180 + z % 12;
        Xt[c * 200 + j] = __float2bfloat16(0.f);
    }
    __syncthreads();
    const short* Tp = (const short*)Th;
    f32x4 zero = {0.f, 0.f, 0.f, 0.f};
    f32x4 acc[3][4];
#pragma unroll
    for (int m = 0; m < 3; ++m)
#pragma unroll
        for (int n = 0; n < 4; ++n) acc[m][n] = zero;
#pragma unroll
    for (int ks = 0; ks < 6; ++ks) {
        short8 af[3], bf[4];
#pragma unroll
        for (int m = 0; m < 3; ++m)
            af[m] = *(const short8*)&Tp[(wid * 48 + m * 16 + lrow) * 192 + ks * 32 + lk8 * 8];
#pragma unroll
        for (int n = 0; n < 4; ++n)
            bf[n] = *(const short8*)&X[(n * 16 + lrow) * 200 + ks * 32 + lk8 * 8];
#pragma unroll
        for (int m = 0; m < 3; ++m)
#pragma unroll
            for (int n = 0; n < 4; ++n)
                acc[m][n] = __builtin_amdgcn_mfma_f32_16x16x32_bf16(af[m], bf[n], acc[m][n], 0, 0, 0);
    }
    int crow = (lane >> 4) * 4, ccol = lane & 15;
#pragma unroll
    for (int m = 0; m < 3; ++m)
#pragma unroll
        for (int j = 0; j < 4; ++j) {
            int r = wid * 48 + m * 16 + crow + j;
            int kh = r >> 1;
            if (kh >= H_) continue;
#pragma unroll
            for (int n = 0; n < 4; ++n) {
                size_t o = base + (size_t)kh * WFK * C_ + n * 16 + ccol;
                if (r & 1) di[o] = acc[m][n][j];
                else       dr[o] = acc[m][n][j];
            }
        }
}

// ---------------- block-diagonal complex 2-layer MLP + softshrink, IN-PLACE, via MFMA ----------------
__global__ __launch_bounds__(256) void blockmlp_mfma_kernel(
        float* __restrict__ vr, float* __restrict__ vi,
        const __hip_bfloat16* __restrict__ wbig, const float* __restrict__ bbig)
{
    __shared__ __hip_bfloat16 X1[64 * 200];
    __shared__ __hip_bfloat16 X2[64 * 200];
    int chunk = blockIdx.x;          // 130 chunks of 64 positions
    int nb = blockIdx.y;
    int tid = threadIdx.x, wid = tid >> 6, lane = tid & 63;
    int p0 = chunk * 64;
    for (int i = tid; i < 64 * 48; i += 256) {
        int p = i / 48, q = i % 48;
        int pg = p0 + p;
        int c4 = (q % 24) * 4;
        bool isr = q < 24;
        float4 v = make_float4(0, 0, 0, 0);
        if (pg < NPOS) {
            const float* src = isr ? vr : vi;
            v = *(const float4*)&src[(size_t)pg * C_ + nb * BSK + c4];
        }
        __hip_bfloat16* d = &X1[p * 200 + (isr ? 0 : 96) + c4];
        d[0] = __float2bfloat16(v.x); d[1] = __float2bfloat16(v.y);
        d[2] = __float2bfloat16(v.z); d[3] = __float2bfloat16(v.w);
    }
    __syncthreads();
    int n0 = wid * 48;
    int lrow = lane & 15, lk8 = lane >> 4;
    int crow = (lane >> 4) * 4, ccol = lane & 15;
    const short* W1 = (const short*)(wbig + (size_t)nb * 192 * 192);
    const short* W2 = (const short*)(wbig + (size_t)(NBK + nb) * 192 * 192);
    const float* bb1 = bbig + nb * 192;
    const float* bb2 = bbig + (NBK + nb) * 192;
    f32x4 zero = {0.f, 0.f, 0.f, 0.f};
    {
        f32x4 acc[4][3];
#pragma unroll
        for (int m = 0; m < 4; ++m)
#pragma unroll
            for (int n = 0; n < 3; ++n) acc[m][n] = zero;
#pragma unroll
        for (int k0 = 0; k0 < 192; k0 += 32) {
            short8 af[4], bf[3];
#pragma unroll
            for (int m = 0; m < 4; ++m)
                af[m] = *(const short8*)&X1[(m * 16 + lrow) * 200 + k0 + lk8 * 8];
#pragma unroll
            for (int n = 0; n < 3; ++n)
                bf[n] = *(const short8*)&W1[(size_t)(n0 + n * 16 + lrow) * 192 + k0 + lk8 * 8];
#pragma unroll
            for (int m = 0; m < 4; ++m)
#pragma unroll
                for (int n = 0; n < 3; ++n)
                    acc[m][n] = __builtin_amdgcn_mfma_f32_16x16x32_bf16(af[m], bf[n], acc[m][n], 0, 0, 0);
        }
        __syncthreads();
#pragma unroll
        for (int m = 0; m < 4; ++m)
#pragma unroll
            for (int j = 0; j < 4; ++j) {
                int row = m * 16 + crow + j;
#pragma unroll
                for (int n = 0; n < 3; ++n) {
                    int col = n0 + n * 16 + ccol;
                    float v = acc[m][n][j] + bb1[col];
                    X2[row * 200 + col] = __float2bfloat16(fmaxf(v, 0.f));
                }
            }
    }
    __syncthreads();
    {
        f32x4 acc[4][3];
#pragma unroll
        for (int m = 0; m < 4; ++m)
#pragma unroll
            for (int n = 0; n < 3; ++n) acc[m][n] = zero;
#pragma unroll
        for (int k0 = 0; k0 < 192; k0 += 32) {
            short8 af[4], bf[3];
#pragma unroll
            for (int m = 0; m < 4; ++m)
                af[m] = *(const short8*)&X2[(m * 16 + lrow) * 200 + k0 + lk8 * 8];
#pragma unroll
            for (int n = 0; n < 3; ++n)
                bf[n] = *(const short8*)&W2[(size_t)(n0 + n * 16 + lrow) * 192 + k0 + lk8 * 8];
#pragma unroll
            for (int m = 0; m < 4; ++m)
#pragma unroll
                for (int n = 0; n < 3; ++n)
                    acc[m][n] = __builtin_amdgcn_mfma_f32_16x16x32_bf16(af[m], bf[n], acc[m][n], 0, 0, 0);
        }
#pragma unroll
        for (int m = 0; m < 4; ++m)
#pragma unroll
            for (int j = 0; j < 4; ++j) {
                int row = m * 16 + crow + j;
                int pg = p0 + row;
                if (pg >= NPOS) continue;
#pragma unroll
                for (int n = 0; n < 3; ++n) {
                    int col = n0 + n * 16 + ccol;
                    float v = acc[m][n][j] + bb2[col];
                    v = v > LAM ? v - LAM : (v < -LAM ? v + LAM : 0.f);
                    if (col < BSK) vr[(size_t)pg * C_ + nb * BSK + col] = v;
                    else           vi[(size_t)pg * C_ + nb * BSK + col - BSK] = v;
                }
            }
    }
}

// ---------------- inverse rfft along W via MFMA: OUT[180][64] = Tw[192][96] @ Yt^T, + residuals ----------------
__global__ __launch_bounds__(256) void iwfft_kernel(
        const float* __restrict__ inr, const float* __restrict__ ini,
        const __hip_bfloat16* __restrict__ h1, const float* __restrict__ x,
        float* __restrict__ out, const __hip_bfloat16* __restrict__ Tw)
{
    __shared__ __hip_bfloat16 Yt[64 * 104];   // [channel][k], k: 2j=re,2j+1=im, pad 92..95
    int slab = blockIdx.x;        // 180
    int c0 = blockIdx.y * 64;     // 12 groups
    int tid = threadIdx.x, wid = tid >> 6, lane = tid & 63;
    int lrow = lane & 15, lk8 = lane >> 4;
    size_t sb = (size_t)slab * WFK * C_ + c0;
    for (int i = tid; i < WFK * 16; i += 256) {
        int wf = i >> 4, cq = (i & 15) * 4;
        size_t a = sb + (size_t)wf * C_ + cq;
        float4 vrv = *(const float4*)&inr[a];
        float4 viv = *(const float4*)&ini[a];
        Yt[(cq + 0) * 104 + 2 * wf]     = __float2bfloat16(vrv.x);
        Yt[(cq + 0) * 104 + 2 * wf + 1] = __float2bfloat16(viv.x);
        Yt[(cq + 1) * 104 + 2 * wf]     = __float2bfloat16(vrv.y);
        Yt[(cq + 1) * 104 + 2 * wf + 1] = __float2bfloat16(viv.y);
        Yt[(cq + 2) * 104 + 2 * wf]     = __float2bfloat16(vrv.z);
        Yt[(cq + 2) * 104 + 2 * wf + 1] = __float2bfloat16(viv.z);
        Yt[(cq + 3) * 104 + 2 * wf]     = __float2bfloat16(vrv.w);
        Yt[(cq + 3) * 104 + 2 * wf + 1] = __float2bfloat16(viv.w);
    }
    {
        int c = tid >> 2, kk = 92 + (tid & 3);
        Yt[c * 104 + kk] = __float2bfloat16(0.f);
    }
    __syncthreads();
    const short* Tp = (const short*)Tw;
    f32x4 zero = {0.f, 0.f, 0.f, 0.f};
    f32x4 acc[3][4];
#pragma unroll
    for (int m = 0; m < 3; ++m)
#pragma unroll
        for (int n = 0; n < 4; ++n) acc[m][n] = zero;
#pragma unroll
    for (int ks = 0; ks < 3; ++ks) {
        short8 af[3], bf[4];
#pragma unroll
        for (int m = 0; m < 3; ++m)
            af[m] = *(const short8*)&Tp[(wid * 48 + m * 16 + lrow) * 96 + ks * 32 + lk8 * 8];
#pragma unroll
        for (int n = 0; n < 4; ++n)
            bf[n] = *(const short8*)&Yt[(n * 16 + lrow) * 104 + ks * 32 + lk8 * 8];
#pragma unroll
        for (int m = 0; m < 3; ++m)
#pragma unroll
            for (int n = 0; n < 4; ++n)
                acc[m][n] = __builtin_amdgcn_mfma_f32_16x16x32_bf16(af[m], bf[n], acc[m][n], 0, 0, 0);
    }
    int crow = (lane >> 4) * 4, ccol = lane & 15;
    const short* hp = (const short*)h1;
#pragma unroll
    for (int m = 0; m < 3; ++m)
#pragma unroll
        for (int j = 0; j < 4; ++j) {
            int w = wid * 48 + m * 16 + crow + j;
            if (w >= W_) continue;
            size_t o = ((size_t)slab * W_ + w) * C_ + c0;
#pragma unroll
            for (int n = 0; n < 4; ++n) {
                int col = n * 16 + ccol;
                out[o + col] = acc[m][n][j] + bf2f(hp[o + col]) + x[o + col];
            }
        }
}

// ---------------- transpose + f32->bf16 (weights) ----------------
__global__ __launch_bounds__(256) void transpose_cvt_kernel(const float* __restrict__ Wm,
        __hip_bfloat16* __restrict__ Wt, int R, int Ccol)
{
    __shared__ float tile[32][33];
    int c0 = blockIdx.x * 32, r0 = blockIdx.y * 32;
    int tid = threadIdx.x;
    int tc = tid & 31, tr = tid >> 5;
#pragma unroll
    for (int k = 0; k < 4; ++k)
        tile[tr + k * 8][tc] = Wm[(size_t)(r0 + tr + k * 8) * Ccol + c0 + tc];
    __syncthreads();
    int rr = tid & 31, cc = tid >> 5;
#pragma unroll
    for (int k = 0; k < 4; ++k)
        Wt[(size_t)(c0 + cc + k * 8) * R + r0 + rr] = __float2bfloat16(tile[rr][cc + k * 8]);
}

// ---------------- bf16 MFMA GEMM: dbuf single-barrier loop + supertile remap + T2 XOR swizzle ----------------
// Per K-step: STAGE(next tile -> other buffer) issued FIRST, then ds_read+MFMA on current buffer,
// then one __syncthreads (vmcnt+lgkm drain + barrier). Stage latency hides under compute.
template<int EPI>
__global__ __launch_bounds__(256) void gemm_kernel(
        const short* __restrict__ A, const short* __restrict__ Bt,
        const float* __restrict__ bias,
        __hip_bfloat16* __restrict__ obf, float* __restrict__ of32,
        const float* __restrict__ res, int N, int K, int mvalid, int MT, int NT)
{
    __shared__ short As[2][128 * 32];
    __shared__ short Bs[2][128 * 32];
    // ---- supertile remap (bijective incl. remainder supertile) ----
    int id = blockIdx.x;
    const int SUPER = 16;
    int per = SUPER * NT;
    int sidx = id / per;
    int offs = id % per;
    int rows = MT - sidx * SUPER; if (rows > SUPER) rows = SUPER;
    int mt = sidx * SUPER + offs % rows;
    int nt = offs / rows;
    size_t m0 = (size_t)mt * 128, n0 = (size_t)nt * 128;

    int tid = threadIdx.x;
    int wid = tid >> 6, lane = tid & 63;
    int wm = (wid >> 1) * 64, wn = (wid & 1) * 64;
    int lrow = lane & 15, lk8 = lane >> 4;
    f32x4 zero = {0.f, 0.f, 0.f, 0.f};
    f32x4 acc[4][4];
#pragma unroll
    for (int i = 0; i < 4; ++i)
#pragma unroll
        for (int j = 0; j < 4; ++j) acc[i][j] = zero;
    int srow = tid >> 2;                                  // 0..63 (row within half-tile)
    int scol = ((tid & 3) ^ ((srow >> 1) & 3)) * 8;       // inverse-swizzled source k-octet
    const short* Ag = A + (m0 + srow) * K + scol;
    const short* Bg = Bt + (n0 + srow) * K + scol;
    int ldsoff = tid * 16;                                // byte offset within buffer
    int rswz = (lk8 ^ ((lrow >> 1) & 3)) * 8;             // swizzled read slot

    auto stage = [&](int buf, int t) {
        const short* Ak = Ag + (size_t)t * 32;
        const short* Bk = Bg + (size_t)t * 32;
        char* ab = (char*)&As[buf][0] + ldsoff;
        char* bb = (char*)&Bs[buf][0] + ldsoff;
        gload_lds16(Ak, ab);
        gload_lds16(Ak + (size_t)64 * K, ab + 4096);
        gload_lds16(Bk, bb);
        gload_lds16(Bk + (size_t)64 * K, bb + 4096);
    };
    auto compute = [&](int buf) {
        short8 af[4], bfr[4];
#pragma unroll
        for (int mf = 0; mf < 4; ++mf) af[mf] = *(const short8*)&As[buf][(wm + mf * 16 + lrow) * 32 + rswz];
#pragma unroll
        for (int nf = 0; nf < 4; ++nf) bfr[nf] = *(const short8*)&Bs[buf][(wn + nf * 16 + lrow) * 32 + rswz];
#pragma unroll
        for (int mf = 0; mf < 4; ++mf)
#pragma unroll
            for (int nf = 0; nf < 4; ++nf)
                acc[mf][nf] = __builtin_amdgcn_mfma_f32_16x16x32_bf16(af[mf], bfr[nf], acc[mf][nf], 0, 0, 0);
    };

    int nk = K / 32;                 // even for K=768 (24) and K=3072 (96)
    stage(0, 0);
    __syncthreads();
    for (int t = 0; t < nk; t += 2) {
        if (t + 1 < nk) stage(1, t + 1);
        compute(0);
        __syncthreads();
        if (t + 2 < nk) stage(0, t + 2);
        compute(1);
        __syncthreads();
    }

    int crow = (lane >> 4) * 4;
    int ccol = lane & 15;
#pragma unroll
    for (int mf = 0; mf < 4; ++mf) {
#pragma unroll
        for (int j = 0; j < 4; ++j) {
            size_t r = m0 + wm + mf * 16 + crow + j;
            if (EPI == 1 && r >= (size_t)mvalid) continue;
#pragma unroll
            for (int nf = 0; nf < 4; ++nf) {
                size_t cidx = n0 + wn + nf * 16 + ccol;
                float v = acc[mf][nf][j] + bias[cidx];
                if (EPI == 0) {
                    obf[r * N + cidx] = __float2bfloat16(gelu_f(v));
                } else {
                    of32[r * N + cidx] = v + res[r * N + cidx];
                }
            }
        }
    }
}

extern "C" void kernel_launch(void* const* d_in, const int* in_sizes, int n_in,
                              void* d_out, int out_size, void* d_ws, size_t ws_size,
                              hipStream_t stream) {
    (void)in_sizes; (void)n_in; (void)out_size;
    const float* x    = (const float*)d_in[0];
    const float* n1w  = (const float*)d_in[1];
    const float* n1b  = (const float*)d_in[2];
    const float* w1   = (const float*)d_in[3];
    const float* b1   = (const float*)d_in[4];
    const float* w2   = (const float*)d_in[5];
    const float* b2   = (const float*)d_in[6];
    const float* n2w  = (const float*)d_in[7];
    const float* n2b  = (const float*)d_in[8];
    const float* fc1w = (const float*)d_in[9];
    const float* fc1b = (const float*)d_in[10];
    const float* fc2w = (const float*)d_in[11];
    const float* fc2b = (const float*)d_in[12];
    float* out = (float*)d_out;

    // ---- tiered chunking: pick largest tb that fits ws_size (deterministic: ws_size fixed) ----
    const size_t fl_region1 = (size_t)MPAD * C_ / 2;            // 12,484,608
    const size_t fl_f1      = (size_t)2 * NPOS * C_;            // 12,718,080
    const size_t fl_tb1     = (size_t)MPAD * HID / 2;           // 49,938,432 (254 tiles)
    const size_t fl_tb2     = (size_t)127 * 128 * HID / 2;      // 24,969,216 (127 tiles)
    const size_t fl_wx      = 2712576 + 4096;                    // weights + tables + align slop
    const size_t need1 = (fl_region1 + fl_tb1 + fl_wx) * 4;
    const size_t need2 = (fl_region1 + ((fl_f1 > fl_tb2) ? fl_f1 : fl_tb2) + fl_wx) * 4;
    int nch = (ws_size >= need1) ? 1 : (ws_size >= need2) ? 2 : 4;
    size_t fl_tb = (nch == 1) ? fl_tb1 : (nch == 2) ? fl_tb2 : 0;
    size_t fl_big = (fl_f1 > fl_tb) ? fl_f1 : fl_tb;

    float* wsf = (float*)d_ws;
    size_t off = 0;
    auto alloc = [&](size_t nfloats) { float* p = wsf + off; off += (nfloats + 63) & ~(size_t)63; return p; };
    float* region1   = alloc(fl_region1);     // h1 (bf16) then h3 (bf16)
    float* regionBig = alloc(fl_big);         // f1r,f1i (f32) then tb (bf16 chunk)
    __hip_bfloat16* w1t = (__hip_bfloat16*)alloc((size_t)HID * C_ / 2);
    __hip_bfloat16* w2t = (__hip_bfloat16*)alloc((size_t)HID * C_ / 2);
    __hip_bfloat16* wbig = (__hip_bfloat16*)alloc((size_t)2 * NBK * 192 * 192 / 2);
    float* bbig = alloc(2 * NBK * 192);
    __hip_bfloat16* Tw  = (__hip_bfloat16*)alloc(192 * 96 / 2);
    __hip_bfloat16* Twf = (__hip_bfloat16*)alloc(96 * 192 / 2);
    __hip_bfloat16* Thf = (__hip_bfloat16*)alloc(192 * 192 / 2);
    __hip_bfloat16* Thi = (__hip_bfloat16*)alloc(192 * 192 / 2);

    __hip_bfloat16* h1b = (__hip_bfloat16*)region1;
    __hip_bfloat16* h3  = (__hip_bfloat16*)region1;
    float* f1r = regionBig;
    float* f1i = regionBig + (size_t)NPOS * C_;
    __hip_bfloat16* tb  = (__hip_bfloat16*)regionBig;

    init_tables_kernel<<<144, 256, 0, stream>>>(Tw, Twf, Thf, Thi);
    wprep_kernel<<<(2 * NBK * 192 * 192 + 255) / 256, 256, 0, stream>>>(w1, b1, w2, b2, wbig, bbig);
    transpose_cvt_kernel<<<dim3(HID / 32, C_ / 32), 256, 0, stream>>>(fc1w, w1t, C_, HID);
    transpose_cvt_kernel<<<dim3(C_ / 32, HID / 32), 256, 0, stream>>>(fc2w, w2t, HID, C_);

    ln_kernel<<<NTOK, 256, 0, stream>>>(x, n1w, n1b, h1b, NTOK);
    wfft_kernel<<<dim3(B_ * H_, 12), 256, 0, stream>>>(h1b, f1r, f1i, Twf);
    hdft_kernel<<<dim3(B_ * WFK, 12), 256, 0, stream>>>(f1r, f1i, Thf);
    blockmlp_mfma_kernel<<<dim3(130, NBK), 256, 0, stream>>>(f1r, f1i, wbig, bbig);
    hdft_kernel<<<dim3(B_ * WFK, 12), 256, 0, stream>>>(f1r, f1i, Thi);
    iwfft_kernel<<<dim3(B_ * H_, 12), 256, 0, stream>>>(f1r, f1i, h1b, x, out, Tw);
    // h1b, f1r/f1i dead from here; regions reused by h3 and tb
    ln_kernel<<<MPAD, 256, 0, stream>>>(out, n2w, n2b, h3, NTOK);

    int tilesArr[4], ntiles = 0;
    if (nch == 1)      { tilesArr[0] = 254; ntiles = 1; }
    else if (nch == 2) { tilesArr[0] = 127; tilesArr[1] = 127; ntiles = 2; }
    else               { tilesArr[0] = 64; tilesArr[1] = 64; tilesArr[2] = 64; tilesArr[3] = 62; ntiles = 4; }
    int baseT = 0;
    for (int c = 0; c < ntiles; ++c) {
        int tiles = tilesArr[c];
        size_t baseRow = (size_t)baseT * 128;
        gemm_kernel<0><<<tiles * (HID / 128), 256, 0, stream>>>(
            (const short*)(h3 + baseRow * C_), (const short*)w1t, fc1b,
            tb, nullptr, nullptr, HID, C_, 0, tiles, HID / 128);
        gemm_kernel<1><<<tiles * (C_ / 128), 256, 0, stream>>>(
            (const short*)tb, (const short*)w2t, fc2b,
            nullptr, out + baseRow * C_, out + baseRow * C_, C_, HID, NTOK - (int)baseRow, tiles, C_ / 128);
        baseT += tiles;
    }
}